// Round 15
// baseline (214.319 us; speedup 1.0000x reference)
//
#include <hip/hip_runtime.h>

#define NNODE 2048
#define NBATCH 32

typedef __attribute__((ext_vector_type(4))) float f32x4;
typedef __attribute__((ext_vector_type(8))) __bf16 bf16x8;
typedef __attribute__((ext_vector_type(4))) __bf16 bf16x4;

__device__ __forceinline__ void gload16(const void* g, void* lds) {
  __builtin_amdgcn_global_load_lds(
      (const __attribute__((address_space(1))) unsigned int*)g,
      (__attribute__((address_space(3))) unsigned int*)lds, 16, 0, 0);
}

// ---------------------------------------------------------------------------
// Merged: prep_e (blocks 0..127) + prep_w (blocks 128..223)
__global__ __launch_bounds__(256) void prep_ew(const float* __restrict__ E1,
                                               const float* __restrict__ E2,
                                               const float* __restrict__ Wz,
                                               const float* __restrict__ Wr,
                                               const float* __restrict__ Wc,
                                               const float* __restrict__ wpre,
                                               const float* __restrict__ wadp,
                                               __bf16* __restrict__ E1p,
                                               __bf16* __restrict__ E2p,
                                               __bf16* __restrict__ Wzrt,
                                               __bf16* __restrict__ Wct) {
  if (blockIdx.x < 128) {
    int idx = blockIdx.x * 256 + threadIdx.x;  // 0..32767
    int cq = idx & 3;
    int n = (idx >> 2) & 2047;
    int h = idx >> 13;
    const float4 q1 = *(const float4*)(E1 + (size_t)(n * 4 + h) * 16 + cq * 4);
    const float4 q2 = *(const float4*)(E2 + (size_t)(n * 4 + h) * 16 + cq * 4);
    size_t o = ((size_t)h * NNODE + n) * 32 + cq * 4;
    E1p[o + 0] = (__bf16)q1.x; E1p[o + 1] = (__bf16)q1.y;
    E1p[o + 2] = (__bf16)q1.z; E1p[o + 3] = (__bf16)q1.w;
    E2p[o + 0] = (__bf16)q2.x; E2p[o + 1] = (__bf16)q2.y;
    E2p[o + 2] = (__bf16)q2.z; E2p[o + 3] = (__bf16)q2.w;
    size_t oz = o + 16;
    E1p[oz + 0] = (__bf16)0.f; E1p[oz + 1] = (__bf16)0.f;
    E1p[oz + 2] = (__bf16)0.f; E1p[oz + 3] = (__bf16)0.f;
    E2p[oz + 0] = (__bf16)0.f; E2p[oz + 1] = (__bf16)0.f;
    E2p[oz + 2] = (__bf16)0.f; E2p[oz + 3] = (__bf16)0.f;
  } else {
    int idx = (blockIdx.x - 128) * 256 + threadIdx.x;  // 0 .. 128*192-1
    int rr = idx / 192, k = idx % 192;
    float s = 2.f * (*wpre) + (*wadp);
    float sc = (k < 64) ? s : 1.f;
    float vz = (rr < 64) ? Wz[(size_t)k * 64 + rr] : Wr[(size_t)k * 64 + rr - 64];
    Wzrt[idx] = (__bf16)(vz * sc);
    float vc = (rr < 64) ? Wc[(size_t)k * 64 + rr] * sc : 0.f;
    Wct[idx] = (__bf16)vc;
  }
}

// ---------------------------------------------------------------------------
// SC[h][w][v] = relu(E1p_h @ E2p_h^T)/4, bf16. Single K=32 MFMA step.
__global__ __launch_bounds__(256) void score_gemm(const __bf16* __restrict__ E1p,
                                                  const __bf16* __restrict__ E2p,
                                                  __bf16* __restrict__ SC) {
  __shared__ __bf16 As[128 * 32];
  __shared__ __bf16 Bs[128 * 32];
  const int tid = threadIdx.x;
  const int wave = tid >> 6, lane = tid & 63;
  const int wr = wave >> 1, wc = wave & 1;
  const int h = blockIdx.z;
  const int m0 = blockIdx.x * 128, n0 = blockIdx.y * 128;
  const __bf16* A = E1p + (size_t)h * NNODE * 32;
  const __bf16* Bt = E2p + (size_t)h * NNODE * 32;
  const int rowA = tid >> 2;
  const int colb = (tid & 3) * 16;
  gload16((const char*)(A + (size_t)(m0 + rowA) * 32) + colb, (char*)As + wave * 1024);
  gload16((const char*)(A + (size_t)(m0 + rowA + 64) * 32) + colb, (char*)As + 4096 + wave * 1024);
  gload16((const char*)(Bt + (size_t)(n0 + rowA) * 32) + colb, (char*)Bs + wave * 1024);
  gload16((const char*)(Bt + (size_t)(n0 + rowA + 64) * 32) + colb, (char*)Bs + 4096 + wave * 1024);
  __syncthreads();

  f32x4 acc[4][4] = {};
  bf16x8 af[4], bfr[4];
#pragma unroll
  for (int mi = 0; mi < 4; ++mi)
    af[mi] = *(const bf16x8*)((const char*)As +
             ((wr * 64 + mi * 16 + (lane & 15)) * 64 + (lane >> 4) * 16));
#pragma unroll
  for (int ni = 0; ni < 4; ++ni)
    bfr[ni] = *(const bf16x8*)((const char*)Bs +
             ((wc * 64 + ni * 16 + (lane & 15)) * 64 + (lane >> 4) * 16));
#pragma unroll
  for (int mi = 0; mi < 4; ++mi)
#pragma unroll
    for (int ni = 0; ni < 4; ++ni)
      acc[mi][ni] = __builtin_amdgcn_mfma_f32_16x16x32_bf16(af[mi], bfr[ni],
                                                            acc[mi][ni], 0, 0, 0);

  const int crow = (lane >> 4) * 4;
  const int ccol = lane & 15;
#pragma unroll
  for (int mi = 0; mi < 4; ++mi)
#pragma unroll
    for (int ni = 0; ni < 4; ++ni) {
      int r0 = m0 + wr * 64 + mi * 16 + crow;
      int cc = n0 + wc * 64 + ni * 16 + ccol;
#pragma unroll
      for (int r = 0; r < 4; ++r) {
        float val = fmaxf(acc[mi][ni][r], 0.f) * 0.25f;
        SC[((size_t)h * NNODE + r0 + r) * NNODE + cc] = (__bf16)val;
      }
    }
}

// ---------------------------------------------------------------------------
// Merged: blocks 0..2047 -> row softmax (SC -> adjh); blocks 2048..3071 ->
// transpose_x: x f32 -> XT8 fp8(16x) [B*64,N] and xbf bf16 [B*N,64].
__global__ __launch_bounds__(256) void soft_tx(const __bf16* __restrict__ SC,
                                               __bf16* __restrict__ adjh,
                                               const float* __restrict__ x,
                                               unsigned char* __restrict__ XT8,
                                               __bf16* __restrict__ xbf) {
  const int tid = threadIdx.x;
  if (blockIdx.x < 2048) {
    const int wave = tid >> 6, lane = tid & 63;
    const size_t row = (size_t)blockIdx.x * 4 + wave;
    const __bf16* src = SC + row * NNODE;
    __bf16* dst = adjh + row * NNODE;
    float v[32];
    float mx = 0.f;
#pragma unroll
    for (int j = 0; j < 4; ++j) {
      bf16x8 q = *(const bf16x8*)(src + j * 512 + lane * 8);
#pragma unroll
      for (int i = 0; i < 8; ++i) {
        float f = (float)q[i];
        v[j * 8 + i] = f;
        mx = fmaxf(mx, f);
      }
    }
#pragma unroll
    for (int o = 32; o > 0; o >>= 1) mx = fmaxf(mx, __shfl_xor(mx, o));
    float s = 0.f;
#pragma unroll
    for (int i = 0; i < 32; ++i) {
      v[i] = __expf(v[i] - mx);
      s += v[i];
    }
#pragma unroll
    for (int o = 32; o > 0; o >>= 1) s += __shfl_xor(s, o);
    float inv = 1.f / s;
#pragma unroll
    for (int j = 0; j < 4; ++j) {
      bf16x8 q;
#pragma unroll
      for (int i = 0; i < 8; ++i) q[i] = (__bf16)(v[j * 8 + i] * inv);
      *(bf16x8*)(dst + j * 512 + lane * 8) = q;
    }
  } else {
    const int idx = blockIdx.x - 2048;
    const int b = idx >> 5, v0 = (idx & 31) * 64;
    __shared__ float t[64][65];
    const int vr = tid >> 2, c0 = (tid & 3) * 16;
    const float* src = x + ((size_t)b * NNODE + v0 + vr) * 64 + c0;
    __bf16* xb = xbf + ((size_t)b * NNODE + v0 + vr) * 64 + c0;
#pragma unroll
    for (int j = 0; j < 4; ++j) {
      float4 q = ((const float4*)src)[j];
      t[vr][c0 + j * 4 + 0] = q.x;
      t[vr][c0 + j * 4 + 1] = q.y;
      t[vr][c0 + j * 4 + 2] = q.z;
      t[vr][c0 + j * 4 + 3] = q.w;
      xb[j * 4 + 0] = (__bf16)q.x;
      xb[j * 4 + 1] = (__bf16)q.y;
      xb[j * 4 + 2] = (__bf16)q.z;
      xb[j * 4 + 3] = (__bf16)q.w;
    }
    __syncthreads();
    const float SX = 16.f;
#pragma unroll
    for (int jr = 0; jr < 4; ++jr) {
      int c = jr * 16 + (tid >> 4);
      int vq = (tid & 15) * 4;
      int w0 = __builtin_amdgcn_cvt_pk_fp8_f32(t[vq][c] * SX, t[vq + 1][c] * SX, 0, false);
      w0 = __builtin_amdgcn_cvt_pk_fp8_f32(t[vq + 2][c] * SX, t[vq + 3][c] * SX, w0, true);
      *(int*)(XT8 + ((size_t)(b * 64 + c)) * NNODE + v0 + vq) = w0;
    }
  }
}

// ---------------------------------------------------------------------------
// Fused adjacency prep (fp8 outputs): ADJ8 = fp8(128 A_z), ADJT8 =
// fp8(128 w_z A_z^T), M18 = fp8(128 sum_z w_z A_z).
__global__ __launch_bounds__(256) void prep_adj(const float* __restrict__ A1,
                                                const float* __restrict__ A2,
                                                const __bf16* __restrict__ ADJ,
                                                unsigned char* __restrict__ ADJ8,
                                                unsigned char* __restrict__ ADJT8,
                                                unsigned char* __restrict__ M18,
                                                const float* __restrict__ wpre,
                                                const float* __restrict__ wadp) {
  const int r0 = blockIdx.x * 64, c0 = blockIdx.y * 64;
  const int tid = threadIdx.x;
  const size_t NN2 = (size_t)NNODE * NNODE;
  const float wp = *wpre, wa = *wadp * 0.25f;
  const float SA = 128.f;
  __shared__ float t[64][65];
  const int vr = tid >> 2, cg = (tid & 3) * 16;
  float m1acc[16] = {};

  for (int z = 0; z < 6; ++z) {
    const float wz = (z < 2) ? wp : wa;
    float vv[16];
    if (z < 2) {
      const float* src = (z == 0 ? A1 : A2) + (size_t)(r0 + vr) * NNODE + c0 + cg;
#pragma unroll
      for (int j = 0; j < 4; ++j) {
        float4 q = ((const float4*)src)[j];
        vv[j * 4 + 0] = q.x; vv[j * 4 + 1] = q.y;
        vv[j * 4 + 2] = q.z; vv[j * 4 + 3] = q.w;
      }
    } else {
      const __bf16* p = ADJ + (size_t)(z - 2) * NN2 + (size_t)(r0 + vr) * NNODE + c0 + cg;
      bf16x8 q0 = ((const bf16x8*)p)[0];
      bf16x8 q1 = ((const bf16x8*)p)[1];
#pragma unroll
      for (int i = 0; i < 8; ++i) { vv[i] = (float)q0[i]; vv[8 + i] = (float)q1[i]; }
    }
#pragma unroll
    for (int i = 0; i < 16; ++i) {
      m1acc[i] += wz * vv[i];
      t[vr][cg + i] = vv[i];
    }
    {
      int4 pk;
#pragma unroll
      for (int q = 0; q < 4; ++q) {
        int w0 = __builtin_amdgcn_cvt_pk_fp8_f32(vv[4 * q] * SA, vv[4 * q + 1] * SA, 0, false);
        w0 = __builtin_amdgcn_cvt_pk_fp8_f32(vv[4 * q + 2] * SA, vv[4 * q + 3] * SA, w0, true);
        (&pk.x)[q] = w0;
      }
      *(int4*)(ADJ8 + (size_t)z * NN2 + (size_t)(r0 + vr) * NNODE + c0 + cg) = pk;
    }
    __syncthreads();
    {
      const float sb = wz * SA;
#pragma unroll
      for (int jr = 0; jr < 4; ++jr) {
        int c = jr * 16 + (tid >> 4);
        int vq = (tid & 15) * 4;
        int w0 = __builtin_amdgcn_cvt_pk_fp8_f32(t[vq][c] * sb, t[vq + 1][c] * sb, 0, false);
        w0 = __builtin_amdgcn_cvt_pk_fp8_f32(t[vq + 2][c] * sb, t[vq + 3][c] * sb, w0, true);
        *(int*)(ADJT8 + (size_t)z * NN2 + (size_t)(c0 + c) * NNODE + r0 + vq) = w0;
      }
    }
    __syncthreads();
  }
  {
    int4 pk;
#pragma unroll
    for (int q = 0; q < 4; ++q) {
      int w0 = __builtin_amdgcn_cvt_pk_fp8_f32(m1acc[4 * q] * SA, m1acc[4 * q + 1] * SA, 0, false);
      w0 = __builtin_amdgcn_cvt_pk_fp8_f32(m1acc[4 * q + 2] * SA, m1acc[4 * q + 3] * SA, w0, true);
      (&pk.x)[q] = w0;
    }
    *(int4*)(M18 + (size_t)(r0 + vr) * NNODE + c0 + cg) = pk;
  }
}

// ---------------------------------------------------------------------------
#define VMCNT0() asm volatile("s_waitcnt vmcnt(0)" ::: "memory")
#define VMCNT4() asm volatile("s_waitcnt vmcnt(4)" ::: "memory")
#define LGKMCNT0() asm volatile("s_waitcnt lgkmcnt(0)" ::: "memory")
#define BARRIER() asm volatile("s_barrier" ::: "memory")

// fp8 frag helpers
#define READFRAGS8(d, AF, BF)                                                 \
  do {                                                                        \
    _Pragma("unroll")                                                         \
    for (int mi = 0; mi < 4; ++mi) {                                          \
      AF[mi][0] = *(const long*)(AREG8(d) + aoff[mi][0]);                     \
      AF[mi][1] = *(const long*)(AREG8(d) + aoff[mi][1]);                     \
    }                                                                         \
    _Pragma("unroll")                                                         \
    for (int j = 0; j < 4; ++j) {                                             \
      BF[j][0] = *(const long*)(BREG8(d) + boff[j][0]);                       \
      BF[j][1] = *(const long*)(BREG8(d) + boff[j][1]);                       \
    }                                                                         \
  } while (0)

#define MFMA8(AF, BF)                                                         \
  do {                                                                        \
    __builtin_amdgcn_s_setprio(1);                                            \
    _Pragma("unroll")                                                         \
    for (int mi = 0; mi < 4; ++mi)                                            \
      _Pragma("unroll")                                                       \
      for (int j = 0; j < 4; ++j)                                             \
        _Pragma("unroll")                                                     \
        for (int ks = 0; ks < 2; ++ks)                                        \
          acc[mi][j] = __builtin_amdgcn_mfma_f32_16x16x32_fp8_fp8(            \
              AF[mi][ks], BF[j][ks], acc[mi][j], 0, 0, 0);                    \
    __builtin_amdgcn_s_setprio(0);                                            \
  } while (0)

// fp8 swizzle/staging geometry (R13-verified), shared by gemm_sq/gemm_hop1s8.
#define FP8_GEOM()                                                            \
  int aoff[4][2], boff[4][2];                                                 \
  _Pragma("unroll")                                                           \
  for (int mi = 0; mi < 4; ++mi)                                              \
    _Pragma("unroll")                                                         \
    for (int ks = 0; ks < 2; ++ks) {                                          \
      int rh = mi * 32 + wr * 16 + (l & 15);                                  \
      int lo = rh * 64 + ks * 32 + ((l >> 4) * 8);                            \
      aoff[mi][ks] = lo ^ ((rh & 6) << 3);                                    \
    }                                                                         \
  _Pragma("unroll")                                                           \
  for (int j = 0; j < 4; ++j)                                                 \
    _Pragma("unroll")                                                         \
    for (int ks = 0; ks < 2; ++ks) {                                          \
      int rh = j * 32 + wc * 16 + (l & 15);                                   \
      int lo = rh * 64 + ks * 32 + ((l >> 4) * 8);                            \
      boff[j][ks] = lo ^ ((rh & 6) << 3);                                     \
    }                                                                         \
  const int sg_col = (((l & 3) ^ ((l >> 3) & 3)) << 4);                       \
  unsigned aLoff[2], bLoff[2];                                                \
  _Pragma("unroll")                                                           \
  for (int p = 0; p < 2; ++p) {                                               \
    int srow = p * 64 + w * 16 + (l >> 2);                                    \
    aLoff[p] = (unsigned)((m0 + srow) * 2048 + sg_col);                       \
    bLoff[p] = (unsigned)((n0 + srow) * 2048 + sg_col);                       \
  }

// ---------------------------------------------------------------------------
// Fused-squares (fp8): M2part[zh] = (1/16384) sum_{z in third} ADJ8_z @ ADJT8_z^T.
// R15: zh split 3-way -> 768 blocks = exactly 3 blocks/CU (full machine).
// Each block: 2 z-slices x 32 = 64 K-tiles. XCD chunk = 96 blocks.
__global__ __launch_bounds__(256, 3) void gemm_sq(const unsigned char* __restrict__ ADJ8,
                                                  const unsigned char* __restrict__ ADJT8,
                                                  float* __restrict__ M2part) {
  extern __shared__ char smem[];  // 32768 B
  const int tid = threadIdx.x;
  const int w = tid >> 6, l = tid & 63;
  const int wr = w >> 1, wc = w & 1;
  const size_t NN2 = (size_t)NNODE * NNODE;
  int lin = blockIdx.x + 16 * blockIdx.y + 256 * blockIdx.z;  // [0,768)
  int nlin = (lin & 7) * 96 + (lin >> 3);
  const int m0 = (nlin & 15) * 128, n0 = ((nlin >> 4) & 15) * 128;
  const int zh = nlin >> 8;      // [0,3)
  const int zb = zh * 2;
  float* Cp = M2part + (size_t)zh * NN2;
  const int NTT = 64;            // 2 z * 32 K-tiles

#define AREG8(d) (smem + (d) * 8192)
#define BREG8(d) (smem + 16384 + (d) * 8192)

  FP8_GEOM();

#define STAGE8A(toff, region)                                                 \
  do {                                                                        \
    _Pragma("unroll")                                                         \
    for (int p = 0; p < 2; ++p)                                               \
      gload16((const char*)ADJ8 + (toff) + aLoff[p],                          \
              (region) + p * 4096 + w * 1024);                                \
  } while (0)
#define STAGE8B(toff, region)                                                 \
  do {                                                                        \
    _Pragma("unroll")                                                         \
    for (int p = 0; p < 2; ++p)                                               \
      gload16((const char*)ADJT8 + (toff) + bLoff[p],                         \
              (region) + p * 4096 + w * 1024);                                \
  } while (0)

  f32x4 acc[4][4] = {};
  long afA[4][2], bfA[4][2], afB[4][2], bfB[4][2];

  size_t tOff = (size_t)zb * NN2;
  STAGE8A(tOff, AREG8(0));
  STAGE8B(tOff, BREG8(0));
  STAGE8A(tOff + 64, AREG8(1));
  STAGE8B(tOff + 64, BREG8(1));
  tOff += 128;
  VMCNT4();
  BARRIER();
  READFRAGS8(0, afA, bfA);
  LGKMCNT0();
  BARRIER();

  for (int t = 0; t <= NTT - 4; t += 2) {
    STAGE8A(tOff, AREG8(0));
    STAGE8B(tOff, BREG8(0));
    tOff += (((t + 2) & 31) == 31) ? (NN2 - (size_t)31 * 64) : (size_t)64;
    VMCNT4();
    BARRIER();
    READFRAGS8(1, afB, bfB);
    MFMA8(afA, bfA);
    LGKMCNT0();
    BARRIER();
    STAGE8A(tOff, AREG8(1));
    STAGE8B(tOff, BREG8(1));
    tOff += (((t + 3) & 31) == 31) ? (NN2 - (size_t)31 * 64) : (size_t)64;
    VMCNT4();
    BARRIER();
    READFRAGS8(0, afA, bfA);
    MFMA8(afB, bfB);
    LGKMCNT0();
    BARRIER();
  }
  VMCNT0();
  BARRIER();
  READFRAGS8(1, afB, bfB);
  MFMA8(afA, bfA);
  LGKMCNT0();
  MFMA8(afB, bfB);

  const float DS = 1.f / 16384.f;
  const int crow = (l >> 4) * 4;
  const int ccol = l & 15;
#pragma unroll
  for (int mi = 0; mi < 4; ++mi)
#pragma unroll
    for (int j = 0; j < 4; ++j) {
      int r0 = m0 + mi * 32 + wr * 16 + crow;
      int cc = n0 + j * 32 + wc * 16 + ccol;
#pragma unroll
      for (int r = 0; r < 4; ++r)
        Cp[(size_t)(r0 + r) * NNODE + cc] = acc[mi][j][r] * DS;
    }
#undef STAGE8A
#undef STAGE8B
#undef AREG8
#undef BREG8
}

// ---------------------------------------------------------------------------
// fp8 stage GEMM with fused transposed epilogue:
//   S_z[(b,n),c] = (1/2048) sum_v XT8[(b,c)][v] * M_z8[n][v]
__global__ __launch_bounds__(256, 3) void gemm_hop1s8(const unsigned char* __restrict__ XT8,
                                                      const unsigned char* __restrict__ M18,
                                                      const unsigned char* __restrict__ M28,
                                                      __bf16* __restrict__ S1,
                                                      __bf16* __restrict__ S2) {
  extern __shared__ char smem[];  // 32768 B
  const int tid = threadIdx.x;
  const int w = tid >> 6, l = tid & 63;
  const int wr = w >> 1, wc = w & 1;
  int lin = blockIdx.x + 16 * blockIdx.y + 256 * blockIdx.z;
  int nlin = (lin & 7) * 64 + (lin >> 3);
  const int m0 = (nlin & 15) * 128, n0 = ((nlin >> 4) & 15) * 128;
  const int z = nlin >> 8;
  const unsigned char* Bbase = z ? M28 : M18;
  const int NT = NNODE / 64;  // 32

#define AREG8(d) (smem + (d) * 8192)
#define BREG8(d) (smem + 16384 + (d) * 8192)

  FP8_GEOM();

#define STAGE8A(koff, region)                                                 \
  do {                                                                        \
    _Pragma("unroll")                                                         \
    for (int p = 0; p < 2; ++p)                                               \
      gload16((const char*)XT8 + (koff) + aLoff[p],                           \
              (region) + p * 4096 + w * 1024);                                \
  } while (0)
#define STAGE8B(koff, region)                                                 \
  do {                                                                        \
    _Pragma("unroll")                                                         \
    for (int p = 0; p < 2; ++p)                                               \
      gload16((const char*)Bbase + (koff) + bLoff[p],                         \
              (region) + p * 4096 + w * 1024);                                \
  } while (0)

  f32x4 acc[4][4] = {};
  long afA[4][2], bfA[4][2], afB[4][2], bfB[4][2];

  size_t kOff = 0;
  STAGE8A(kOff, AREG8(0));
  STAGE8B(kOff, BREG8(0));
  STAGE8A(kOff + 64, AREG8(1));
  STAGE8B(kOff + 64, BREG8(1));
  kOff += 128;
  VMCNT4();
  BARRIER();
  READFRAGS8(0, afA, bfA);
  LGKMCNT0();
  BARRIER();

  for (int t = 0; t <= NT - 4; t += 2) {
    STAGE8A(kOff, AREG8(0));
    STAGE8B(kOff, BREG8(0));
    kOff += 64;
    VMCNT4();
    BARRIER();
    READFRAGS8(1, afB, bfB);
    MFMA8(afA, bfA);
    LGKMCNT0();
    BARRIER();
    STAGE8A(kOff, AREG8(1));
    STAGE8B(kOff, BREG8(1));
    kOff += 64;
    VMCNT4();
    BARRIER();
    READFRAGS8(0, afA, bfA);
    MFMA8(afB, bfB);
    LGKMCNT0();
    BARRIER();
  }
  VMCNT0();
  BARRIER();
  READFRAGS8(1, afB, bfB);
  MFMA8(afA, bfA);
  LGKMCNT0();
  MFMA8(afB, bfB);

  // ---- epilogue: descale, LDS transpose T[n][m] (slot-XOR), coalesced write
  {
    __syncthreads();
    const float DS = 1.f / 2048.f;  // 1/(16*128)
    const int crow = (l >> 4) * 4;
    const int ccol = l & 15;
    char* T = smem;  // 128 x 256 B = 32768
#pragma unroll
    for (int mi = 0; mi < 4; ++mi)
#pragma unroll
      for (int j = 0; j < 4; ++j) {
        int ml = mi * 32 + wr * 16 + crow;
        int nl = j * 32 + wc * 16 + ccol;
        bf16x4 v;
#pragma unroll
        for (int r = 0; r < 4; ++r) v[r] = (__bf16)(acc[mi][j][r] * DS);
        *(bf16x4*)(T + nl * 256 + ((ml * 2) ^ ((nl & 7) << 4))) = v;
      }
    __syncthreads();
    __bf16* dst = z ? S2 : S1;
    const int bA = m0 >> 6;
#pragma unroll
    for (int it = 0; it < 4; ++it) {
      int nl = (tid >> 3) + it * 32;
      int seg = tid & 7;
      int xorv = (nl & 7) << 4;
      const char* src = T + nl * 256;
      bf16x8 v0 = *(const bf16x8*)(src + ((seg * 32) ^ xorv));
      bf16x8 v1 = *(const bf16x8*)(src + ((seg * 32 + 16) ^ xorv));
      int b = bA + (seg >> 2);
      size_t o = ((size_t)b * NNODE + n0 + nl) * 64 + (seg & 3) * 16;
      *(bf16x8*)(dst + o) = v0;
      *(bf16x8*)(dst + o + 8) = v1;
    }
  }
#undef STAGE8A
#undef STAGE8B
#undef AREG8
#undef BREG8
}

// ---------------------------------------------------------------------------
// M28[i] = fp8(128 * (M2a[i] + M2b[i] + M2c[i]))
__global__ __launch_bounds__(256) void combine_m2(const float* __restrict__ M2p,
                                                  unsigned char* __restrict__ M28) {
  const size_t NN2 = (size_t)NNODE * NNODE;
  size_t i = ((size_t)blockIdx.x * 256 + threadIdx.x) * 4;
  float4 a = *(const float4*)(M2p + i);
  float4 b = *(const float4*)(M2p + NN2 + i);
  float4 c = *(const float4*)(M2p + 2 * NN2 + i);
  const float SA = 128.f;
  int w0 = __builtin_amdgcn_cvt_pk_fp8_f32((a.x + b.x + c.x) * SA,
                                           (a.y + b.y + c.y) * SA, 0, false);
  w0 = __builtin_amdgcn_cvt_pk_fp8_f32((a.z + b.z + c.z) * SA,
                                       (a.w + b.w + c.w) * SA, w0, true);
  *(int*)(M28 + i) = w0;
}

// ---------------------------------------------------------------------------
// Gate linear GEMM: [65536 x 192] @ Wt^T, K=192, N=128, fused epilogues.
// MODE 0: cols 0-63 -> z=sigmoid -> zbuf(f32); cols 64-127 -> r ->
//         rx=(bf16)(r*hid) row-major AND fp8(16*rx)^T -> XT8out.
// MODE 1: cols 0-63 -> c=tanh -> out=(1-z)*hid+z*c (f32)
template <int MODE>
__global__ __launch_bounds__(256) void gemm_lin(const __bf16* __restrict__ Xp,
                                                const __bf16* __restrict__ S1,
                                                const __bf16* __restrict__ S2,
                                                const __bf16* __restrict__ Wt,
                                                const float* __restrict__ b0,
                                                const float* __restrict__ b1,
                                                const float* __restrict__ wpre,
                                                const float* __restrict__ wadp,
                                                const float* __restrict__ hid,
                                                float* __restrict__ zbuf,
                                                __bf16* __restrict__ rxout,
                                                unsigned char* __restrict__ XT8out,
                                                float* __restrict__ outp) {
  __shared__ __bf16 As[128 * 32];
  __shared__ __bf16 Bs[128 * 32];
  __shared__ char T[64 * 256];  // rx transpose staging (MODE 0)
  const int tid = threadIdx.x;
  const int wave = tid >> 6, lane = tid & 63;
  const int wr = wave >> 1, wc = wave & 1;
  const int m0 = blockIdx.x * 128;
  const int rowA = tid >> 2;
  const int colb = (tid & 3) * 16;
  const __bf16* srcs[3] = {Xp, S1, S2};
  char* asD0 = (char*)As + wave * 1024;
  char* asD1 = (char*)As + 4096 + wave * 1024;
  char* bsD0 = (char*)Bs + wave * 1024;
  char* bsD1 = (char*)Bs + 4096 + wave * 1024;

  f32x4 acc[4][4] = {};

#pragma unroll
  for (int kt = 0; kt < 6; ++kt) {
    const __bf16* Ab = srcs[kt >> 1];
    const char* aS0 = (const char*)(Ab + (size_t)(m0 + rowA) * 64) + (kt & 1) * 64 + colb;
    const char* aS1 = (const char*)(Ab + (size_t)(m0 + rowA + 64) * 64) + (kt & 1) * 64 + colb;
    const char* bS0 = (const char*)(Wt + (size_t)rowA * 192) + kt * 64 + colb;
    const char* bS1 = (const char*)(Wt + (size_t)(rowA + 64) * 192) + kt * 64 + colb;
    gload16(aS0, asD0);
    gload16(aS1, asD1);
    gload16(bS0, bsD0);
    gload16(bS1, bsD1);
    __syncthreads();
    bf16x8 af[4], bfr[4];
#pragma unroll
    for (int mi = 0; mi < 4; ++mi)
      af[mi] = *(const bf16x8*)((const char*)As +
               ((wr * 64 + mi * 16 + (lane & 15)) * 64 + (lane >> 4) * 16));
#pragma unroll
    for (int ni = 0; ni < 4; ++ni)
      bfr[ni] = *(const bf16x8*)((const char*)Bs +
               ((wc * 64 + ni * 16 + (lane & 15)) * 64 + (lane >> 4) * 16));
#pragma unroll
    for (int mi = 0; mi < 4; ++mi)
#pragma unroll
      for (int ni = 0; ni < 4; ++ni)
        acc[mi][ni] = __builtin_amdgcn_mfma_f32_16x16x32_bf16(af[mi], bfr[ni],
                                                              acc[mi][ni], 0, 0, 0);
    __syncthreads();
  }

  const float wp = *wpre, wa = *wadp;
  const float s = 2.f * wp + wa;
  const int crow = (lane >> 4) * 4;
  const int ccol = lane & 15;
#pragma unroll
  for (int mi = 0; mi < 4; ++mi)
#pragma unroll
    for (int ni = 0; ni < 4; ++ni) {
      int r0 = m0 + wr * 64 + mi * 16 + crow;
      int col = wc * 64 + ni * 16 + ccol;
      int cf = col & 63;
      if (MODE == 0) {
        if (col < 64) {
#pragma unroll
          for (int r = 0; r < 4; ++r) {
            int row = r0 + r;
            float g = acc[mi][ni][r] + s * b0[cf];
            zbuf[(size_t)row * 64 + cf] = 1.f / (1.f + __expf(-g));
          }
        } else {
          bf16x4 tv;
#pragma unroll
          for (int r = 0; r < 4; ++r) {
            int row = r0 + r;
            float g = acc[mi][ni][r] + s * b1[cf];
            float rv = 1.f / (1.f + __expf(-g));
            __bf16 rxv = (__bf16)(rv * hid[(size_t)row * 64 + cf]);
            rxout[(size_t)row * 64 + cf] = rxv;
            tv[r] = rxv;
          }
          int vl0 = wr * 64 + mi * 16 + crow;
          *(bf16x4*)(T + cf * 256 + ((vl0 * 2) ^ ((cf & 7) << 4))) = tv;
        }
      } else {
        if (col < 64) {
#pragma unroll
          for (int r = 0; r < 4; ++r) {
            int row = r0 + r;
            float g = acc[mi][ni][r] + s * b0[cf];
            float cv = 1.f - 2.f / (1.f + __expf(2.f * g));
            float zv = zbuf[(size_t)row * 64 + cf];
            float hv = hid[(size_t)row * 64 + cf];
            outp[(size_t)row * 64 + cf] = (1.f - zv) * hv + zv * cv;
          }
        }
      }
    }

  if (MODE == 0) {
    __syncthreads();
    const int b = m0 >> 11;
    const int v0 = m0 & 2047;
    const float SX = 16.f;
#pragma unroll
    for (int it = 0; it < 4; ++it) {
      int rr = it * 16 + (tid >> 4);
      int seg = tid & 15;
      bf16x8 v = *(const bf16x8*)(T + rr * 256 + ((seg * 16) ^ ((rr & 7) << 4)));
      int w0 = __builtin_amdgcn_cvt_pk_fp8_f32((float)v[0] * SX, (float)v[1] * SX, 0, false);
      w0 = __builtin_amdgcn_cvt_pk_fp8_f32((float)v[2] * SX, (float)v[3] * SX, w0, true);
      int w1 = __builtin_amdgcn_cvt_pk_fp8_f32((float)v[4] * SX, (float)v[5] * SX, 0, false);
      w1 = __builtin_amdgcn_cvt_pk_fp8_f32((float)v[6] * SX, (float)v[7] * SX, w1, true);
      int2 pk; pk.x = w0; pk.y = w1;
      *(int2*)(XT8out + ((size_t)(b * 64 + rr)) * NNODE + v0 + seg * 8) = pk;
    }
  }
}

// ---------------------------------------------------------------------------
extern "C" void kernel_launch(void* const* d_in, const int* in_sizes, int n_in,
                              void* d_out, int out_size, void* d_ws, size_t ws_size,
                              hipStream_t stream) {
  (void)in_sizes; (void)n_in; (void)out_size;
  const float* x    = (const float*)d_in[0];
  const float* A1   = (const float*)d_in[1];
  const float* A2   = (const float*)d_in[2];
  const float* E1   = (const float*)d_in[3];
  const float* E2   = (const float*)d_in[4];
  const float* Wz   = (const float*)d_in[5];
  const float* bz   = (const float*)d_in[6];
  const float* Wr   = (const float*)d_in[7];
  const float* br   = (const float*)d_in[8];
  const float* Wc   = (const float*)d_in[9];
  const float* bc   = (const float*)d_in[10];
  const float* wpre = (const float*)d_in[11];
  const float* wadp = (const float*)d_in[12];
  float* out = (float*)d_out;

  char* ws = (char*)d_ws;
  const size_t NN2 = (size_t)NNODE * NNODE;  // 4,194,304
  const size_t NN2B = NN2 * 2;               // bytes per bf16 slice
  __bf16* ADJ  = (__bf16*)(ws);                 // softmax out @ bf16 slices 0..3
  unsigned char* ADJ8  = (unsigned char*)(ws + 6 * NN2B);           // 6 fp8
  unsigned char* ADJT8 = (unsigned char*)(ws + 6 * NN2B + 6 * NN2); // 6 fp8
  __bf16* SC   = (__bf16*)(ws + 12 * NN2B);     // scores (4 slices), then:
  float*  M2p  = (float*)(ws + 12 * NN2B);      // f32 partials x3 = [12,18)
  unsigned char* M18 = (unsigned char*)(ws + 18 * NN2B);        // fp8
  unsigned char* M28 = (unsigned char*)(ws + 18 * NN2B + NN2);  // fp8
  unsigned char* XT8 = (unsigned char*)(ws + 20 * NN2B);        // fp8
  __bf16* xbf  = (__bf16*)(ws + 21 * NN2B);
  __bf16* rx   = (__bf16*)(ws + 22 * NN2B);
  __bf16* S1   = (__bf16*)(ws + 2 * NN2B);      // over ADJ slice 2 (dead post-prep)
  __bf16* S2   = (__bf16*)(ws + 3 * NN2B);      // over ADJ slice 3
  float*  zbuf = (float*)(ws + 4 * NN2B);       // over ADJ slices 4..5
  __bf16* E1p  = (__bf16*)(ws + 23 * NN2B);
  __bf16* E2p  = E1p + 4 * NNODE * 32;
  __bf16* Wzrt = E2p + 4 * NNODE * 32;
  __bf16* Wct  = Wzrt + 128 * 192;
  if (ws_size < 23 * NN2B + 2 * 4 * NNODE * 32 * 2 + 2 * 128 * 192 * 2) return;

  // --- adjacency construction (fused)
  prep_ew<<<224, 256, 0, stream>>>(E1, E2, Wz, Wr, Wc, wpre, wadp,
                                   E1p, E2p, Wzrt, Wct);
  score_gemm<<<dim3(16, 16, 4), 256, 0, stream>>>(E1p, E2p, SC);
  soft_tx<<<3072, 256, 0, stream>>>(SC, ADJ, x, XT8, xbf);
  prep_adj<<<dim3(32, 32), 256, 0, stream>>>(A1, A2, ADJ, ADJ8, ADJT8, M18,
                                             wpre, wadp);

  // --- M2 = sum_z w_z A_z^2 (fp8; 768 blocks = 3/CU full machine)
  gemm_sq<<<dim3(16, 16, 3), 256, 32768, stream>>>(ADJ8, ADJT8, M2p);
  combine_m2<<<4096, 256, 0, stream>>>(M2p, M28);

  // --- stage 1: S1 = M1 x, S2 = M2 x (fp8, fused transposed epilogue)
  gemm_hop1s8<<<dim3(16, 16, 2), 256, 32768, stream>>>(XT8, M18, M28, S1, S2);
  gemm_lin<0><<<512, 256, 0, stream>>>(xbf, S1, S2, Wzrt, bz, br, wpre, wadp,
                                       x, zbuf, rx, XT8, nullptr);

  // --- stage 2: hops on r*x (XT8 holds fp8(16*rx)^T from gemm_lin<0>)
  gemm_hop1s8<<<dim3(16, 16, 2), 256, 32768, stream>>>(XT8, M18, M28, S1, S2);
  gemm_lin<1><<<512, 256, 0, stream>>>(rx, S1, S2, Wct, bc, nullptr, wpre, wadp,
                                       x, zbuf, nullptr, nullptr, out);
}

// Round 16
// 199.908 us; speedup vs baseline: 1.0721x; 1.0721x over previous
//
#include <hip/hip_runtime.h>

#define NNODE 2048
#define NBATCH 32

typedef __attribute__((ext_vector_type(4))) float f32x4;
typedef __attribute__((ext_vector_type(8))) __bf16 bf16x8;
typedef __attribute__((ext_vector_type(4))) __bf16 bf16x4;

__device__ __forceinline__ void gload16(const void* g, void* lds) {
  __builtin_amdgcn_global_load_lds(
      (const __attribute__((address_space(1))) unsigned int*)g,
      (__attribute__((address_space(3))) unsigned int*)lds, 16, 0, 0);
}

// ---------------------------------------------------------------------------
// Merged: prep_e (blocks 0..127) + prep_w (blocks 128..223)
__global__ __launch_bounds__(256) void prep_ew(const float* __restrict__ E1,
                                               const float* __restrict__ E2,
                                               const float* __restrict__ Wz,
                                               const float* __restrict__ Wr,
                                               const float* __restrict__ Wc,
                                               const float* __restrict__ wpre,
                                               const float* __restrict__ wadp,
                                               __bf16* __restrict__ E1p,
                                               __bf16* __restrict__ E2p,
                                               __bf16* __restrict__ Wzrt,
                                               __bf16* __restrict__ Wct) {
  if (blockIdx.x < 128) {
    int idx = blockIdx.x * 256 + threadIdx.x;  // 0..32767
    int cq = idx & 3;
    int n = (idx >> 2) & 2047;
    int h = idx >> 13;
    const float4 q1 = *(const float4*)(E1 + (size_t)(n * 4 + h) * 16 + cq * 4);
    const float4 q2 = *(const float4*)(E2 + (size_t)(n * 4 + h) * 16 + cq * 4);
    size_t o = ((size_t)h * NNODE + n) * 32 + cq * 4;
    E1p[o + 0] = (__bf16)q1.x; E1p[o + 1] = (__bf16)q1.y;
    E1p[o + 2] = (__bf16)q1.z; E1p[o + 3] = (__bf16)q1.w;
    E2p[o + 0] = (__bf16)q2.x; E2p[o + 1] = (__bf16)q2.y;
    E2p[o + 2] = (__bf16)q2.z; E2p[o + 3] = (__bf16)q2.w;
    size_t oz = o + 16;
    E1p[oz + 0] = (__bf16)0.f; E1p[oz + 1] = (__bf16)0.f;
    E1p[oz + 2] = (__bf16)0.f; E1p[oz + 3] = (__bf16)0.f;
    E2p[oz + 0] = (__bf16)0.f; E2p[oz + 1] = (__bf16)0.f;
    E2p[oz + 2] = (__bf16)0.f; E2p[oz + 3] = (__bf16)0.f;
  } else {
    int idx = (blockIdx.x - 128) * 256 + threadIdx.x;  // 0 .. 128*192-1
    int rr = idx / 192, k = idx % 192;
    float s = 2.f * (*wpre) + (*wadp);
    float sc = (k < 64) ? s : 1.f;
    float vz = (rr < 64) ? Wz[(size_t)k * 64 + rr] : Wr[(size_t)k * 64 + rr - 64];
    Wzrt[idx] = (__bf16)(vz * sc);
    float vc = (rr < 64) ? Wc[(size_t)k * 64 + rr] * sc : 0.f;
    Wct[idx] = (__bf16)vc;
  }
}

// ---------------------------------------------------------------------------
// SC[h][w][v] = relu(E1p_h @ E2p_h^T)/4, bf16. Single K=32 MFMA step.
__global__ __launch_bounds__(256) void score_gemm(const __bf16* __restrict__ E1p,
                                                  const __bf16* __restrict__ E2p,
                                                  __bf16* __restrict__ SC) {
  __shared__ __bf16 As[128 * 32];
  __shared__ __bf16 Bs[128 * 32];
  const int tid = threadIdx.x;
  const int wave = tid >> 6, lane = tid & 63;
  const int wr = wave >> 1, wc = wave & 1;
  const int h = blockIdx.z;
  const int m0 = blockIdx.x * 128, n0 = blockIdx.y * 128;
  const __bf16* A = E1p + (size_t)h * NNODE * 32;
  const __bf16* Bt = E2p + (size_t)h * NNODE * 32;
  const int rowA = tid >> 2;
  const int colb = (tid & 3) * 16;
  gload16((const char*)(A + (size_t)(m0 + rowA) * 32) + colb, (char*)As + wave * 1024);
  gload16((const char*)(A + (size_t)(m0 + rowA + 64) * 32) + colb, (char*)As + 4096 + wave * 1024);
  gload16((const char*)(Bt + (size_t)(n0 + rowA) * 32) + colb, (char*)Bs + wave * 1024);
  gload16((const char*)(Bt + (size_t)(n0 + rowA + 64) * 32) + colb, (char*)Bs + 4096 + wave * 1024);
  __syncthreads();

  f32x4 acc[4][4] = {};
  bf16x8 af[4], bfr[4];
#pragma unroll
  for (int mi = 0; mi < 4; ++mi)
    af[mi] = *(const bf16x8*)((const char*)As +
             ((wr * 64 + mi * 16 + (lane & 15)) * 64 + (lane >> 4) * 16));
#pragma unroll
  for (int ni = 0; ni < 4; ++ni)
    bfr[ni] = *(const bf16x8*)((const char*)Bs +
             ((wc * 64 + ni * 16 + (lane & 15)) * 64 + (lane >> 4) * 16));
#pragma unroll
  for (int mi = 0; mi < 4; ++mi)
#pragma unroll
    for (int ni = 0; ni < 4; ++ni)
      acc[mi][ni] = __builtin_amdgcn_mfma_f32_16x16x32_bf16(af[mi], bfr[ni],
                                                            acc[mi][ni], 0, 0, 0);

  const int crow = (lane >> 4) * 4;
  const int ccol = lane & 15;
#pragma unroll
  for (int mi = 0; mi < 4; ++mi)
#pragma unroll
    for (int ni = 0; ni < 4; ++ni) {
      int r0 = m0 + wr * 64 + mi * 16 + crow;
      int cc = n0 + wc * 64 + ni * 16 + ccol;
#pragma unroll
      for (int r = 0; r < 4; ++r) {
        float val = fmaxf(acc[mi][ni][r], 0.f) * 0.25f;
        SC[((size_t)h * NNODE + r0 + r) * NNODE + cc] = (__bf16)val;
      }
    }
}

// ---------------------------------------------------------------------------
// Merged: blocks 0..2047 -> row softmax (SC -> fp8 ADJ8 slices 2..5 directly,
// scaled x128); blocks 2048..3071 -> transpose_x: x f32 -> XT8 fp8(16x) and
// xbf bf16 [B*N,64].
__global__ __launch_bounds__(256) void soft_tx(const __bf16* __restrict__ SC,
                                               unsigned char* __restrict__ ADJ8,
                                               const float* __restrict__ x,
                                               unsigned char* __restrict__ XT8,
                                               __bf16* __restrict__ xbf) {
  const int tid = threadIdx.x;
  const size_t NN2 = (size_t)NNODE * NNODE;
  if (blockIdx.x < 2048) {
    const int wave = tid >> 6, lane = tid & 63;
    const size_t row = (size_t)blockIdx.x * 4 + wave;
    const __bf16* src = SC + row * NNODE;
    unsigned char* dst = ADJ8 + 2 * NN2 + row * NNODE;  // slices 2..5
    float v[32];
    float mx = 0.f;
#pragma unroll
    for (int j = 0; j < 4; ++j) {
      bf16x8 q = *(const bf16x8*)(src + j * 512 + lane * 8);
#pragma unroll
      for (int i = 0; i < 8; ++i) {
        float f = (float)q[i];
        v[j * 8 + i] = f;
        mx = fmaxf(mx, f);
      }
    }
#pragma unroll
    for (int o = 32; o > 0; o >>= 1) mx = fmaxf(mx, __shfl_xor(mx, o));
    float s = 0.f;
#pragma unroll
    for (int i = 0; i < 32; ++i) {
      v[i] = __expf(v[i] - mx);
      s += v[i];
    }
#pragma unroll
    for (int o = 32; o > 0; o >>= 1) s += __shfl_xor(s, o);
    float inv = 128.f / s;  // x128 fp8 scale folded in
#pragma unroll
    for (int j = 0; j < 4; ++j) {
      int w0 = __builtin_amdgcn_cvt_pk_fp8_f32(v[j * 8 + 0] * inv, v[j * 8 + 1] * inv, 0, false);
      w0 = __builtin_amdgcn_cvt_pk_fp8_f32(v[j * 8 + 2] * inv, v[j * 8 + 3] * inv, w0, true);
      int w1 = __builtin_amdgcn_cvt_pk_fp8_f32(v[j * 8 + 4] * inv, v[j * 8 + 5] * inv, 0, false);
      w1 = __builtin_amdgcn_cvt_pk_fp8_f32(v[j * 8 + 6] * inv, v[j * 8 + 7] * inv, w1, true);
      int2 pk; pk.x = w0; pk.y = w1;
      *(int2*)(dst + j * 512 + lane * 8) = pk;
    }
  } else {
    const int idx = blockIdx.x - 2048;
    const int b = idx >> 5, v0 = (idx & 31) * 64;
    __shared__ float t[64][65];
    const int vr = tid >> 2, c0 = (tid & 3) * 16;
    const float* src = x + ((size_t)b * NNODE + v0 + vr) * 64 + c0;
    __bf16* xb = xbf + ((size_t)b * NNODE + v0 + vr) * 64 + c0;
#pragma unroll
    for (int j = 0; j < 4; ++j) {
      float4 q = ((const float4*)src)[j];
      t[vr][c0 + j * 4 + 0] = q.x;
      t[vr][c0 + j * 4 + 1] = q.y;
      t[vr][c0 + j * 4 + 2] = q.z;
      t[vr][c0 + j * 4 + 3] = q.w;
      xb[j * 4 + 0] = (__bf16)q.x;
      xb[j * 4 + 1] = (__bf16)q.y;
      xb[j * 4 + 2] = (__bf16)q.z;
      xb[j * 4 + 3] = (__bf16)q.w;
    }
    __syncthreads();
    const float SX = 16.f;
#pragma unroll
    for (int jr = 0; jr < 4; ++jr) {
      int c = jr * 16 + (tid >> 4);
      int vq = (tid & 15) * 4;
      int w0 = __builtin_amdgcn_cvt_pk_fp8_f32(t[vq][c] * SX, t[vq + 1][c] * SX, 0, false);
      w0 = __builtin_amdgcn_cvt_pk_fp8_f32(t[vq + 2][c] * SX, t[vq + 3][c] * SX, w0, true);
      *(int*)(XT8 + ((size_t)(b * 64 + c)) * NNODE + v0 + vq) = w0;
    }
  }
}

// ---------------------------------------------------------------------------
// Fused adjacency prep (x128 domain): z<2 reads A1/A2 f32, writes ADJ8;
// z>=2 reads fp8 ADJ8 (written by soft_tx). All z: ADJT8 = fp8(wz * v128),
// M18 = fp8(sum wz * v128).
__global__ __launch_bounds__(256) void prep_adj(const float* __restrict__ A1,
                                                const float* __restrict__ A2,
                                                unsigned char* __restrict__ ADJ8,
                                                unsigned char* __restrict__ ADJT8,
                                                unsigned char* __restrict__ M18,
                                                const float* __restrict__ wpre,
                                                const float* __restrict__ wadp) {
  const int r0 = blockIdx.x * 64, c0 = blockIdx.y * 64;
  const int tid = threadIdx.x;
  const size_t NN2 = (size_t)NNODE * NNODE;
  const float wp = *wpre, wa = *wadp * 0.25f;
  const float SA = 128.f;
  __shared__ float t[64][65];
  const int vr = tid >> 2, cg = (tid & 3) * 16;
  float m1acc[16] = {};

  for (int z = 0; z < 6; ++z) {
    const float wz = (z < 2) ? wp : wa;
    float vv[16];  // values in x128 domain
    if (z < 2) {
      const float* src = (z == 0 ? A1 : A2) + (size_t)(r0 + vr) * NNODE + c0 + cg;
#pragma unroll
      for (int j = 0; j < 4; ++j) {
        float4 q = ((const float4*)src)[j];
        vv[j * 4 + 0] = q.x * SA; vv[j * 4 + 1] = q.y * SA;
        vv[j * 4 + 2] = q.z * SA; vv[j * 4 + 3] = q.w * SA;
      }
      int4 pk;
#pragma unroll
      for (int q = 0; q < 4; ++q) {
        int w0 = __builtin_amdgcn_cvt_pk_fp8_f32(vv[4 * q], vv[4 * q + 1], 0, false);
        w0 = __builtin_amdgcn_cvt_pk_fp8_f32(vv[4 * q + 2], vv[4 * q + 3], w0, true);
        (&pk.x)[q] = w0;
      }
      *(int4*)(ADJ8 + (size_t)z * NN2 + (size_t)(r0 + vr) * NNODE + c0 + cg) = pk;
    } else {
      int4 pk = *(const int4*)(ADJ8 + (size_t)z * NN2 + (size_t)(r0 + vr) * NNODE + c0 + cg);
#pragma unroll
      for (int q = 0; q < 4; ++q) {
        int w0 = (&pk.x)[q];
        vv[4 * q + 0] = __builtin_amdgcn_cvt_f32_fp8(w0, 0);
        vv[4 * q + 1] = __builtin_amdgcn_cvt_f32_fp8(w0, 1);
        vv[4 * q + 2] = __builtin_amdgcn_cvt_f32_fp8(w0, 2);
        vv[4 * q + 3] = __builtin_amdgcn_cvt_f32_fp8(w0, 3);
      }
    }
#pragma unroll
    for (int i = 0; i < 16; ++i) {
      m1acc[i] += wz * vv[i];
      t[vr][cg + i] = vv[i];
    }
    __syncthreads();
    {
#pragma unroll
      for (int jr = 0; jr < 4; ++jr) {
        int c = jr * 16 + (tid >> 4);
        int vq = (tid & 15) * 4;
        int w0 = __builtin_amdgcn_cvt_pk_fp8_f32(t[vq][c] * wz, t[vq + 1][c] * wz, 0, false);
        w0 = __builtin_amdgcn_cvt_pk_fp8_f32(t[vq + 2][c] * wz, t[vq + 3][c] * wz, w0, true);
        *(int*)(ADJT8 + (size_t)z * NN2 + (size_t)(c0 + c) * NNODE + r0 + vq) = w0;
      }
    }
    __syncthreads();
  }
  {
    int4 pk;
#pragma unroll
    for (int q = 0; q < 4; ++q) {
      int w0 = __builtin_amdgcn_cvt_pk_fp8_f32(m1acc[4 * q], m1acc[4 * q + 1], 0, false);
      w0 = __builtin_amdgcn_cvt_pk_fp8_f32(m1acc[4 * q + 2], m1acc[4 * q + 3], w0, true);
      (&pk.x)[q] = w0;
    }
    *(int4*)(M18 + (size_t)(r0 + vr) * NNODE + c0 + cg) = pk;
  }
}

// ---------------------------------------------------------------------------
#define VMCNT0() asm volatile("s_waitcnt vmcnt(0)" ::: "memory")
#define VMCNT4() asm volatile("s_waitcnt vmcnt(4)" ::: "memory")
#define LGKMCNT0() asm volatile("s_waitcnt lgkmcnt(0)" ::: "memory")
#define BARRIER() asm volatile("s_barrier" ::: "memory")

// fp8 frag helpers
#define READFRAGS8(d, AF, BF)                                                 \
  do {                                                                        \
    _Pragma("unroll")                                                         \
    for (int mi = 0; mi < 4; ++mi) {                                          \
      AF[mi][0] = *(const long*)(AREG8(d) + aoff[mi][0]);                     \
      AF[mi][1] = *(const long*)(AREG8(d) + aoff[mi][1]);                     \
    }                                                                         \
    _Pragma("unroll")                                                         \
    for (int j = 0; j < 4; ++j) {                                             \
      BF[j][0] = *(const long*)(BREG8(d) + boff[j][0]);                       \
      BF[j][1] = *(const long*)(BREG8(d) + boff[j][1]);                       \
    }                                                                         \
  } while (0)

#define MFMA8(AF, BF)                                                         \
  do {                                                                        \
    __builtin_amdgcn_s_setprio(1);                                            \
    _Pragma("unroll")                                                         \
    for (int mi = 0; mi < 4; ++mi)                                            \
      _Pragma("unroll")                                                       \
      for (int j = 0; j < 4; ++j)                                             \
        _Pragma("unroll")                                                     \
        for (int ks = 0; ks < 2; ++ks)                                        \
          acc[mi][j] = __builtin_amdgcn_mfma_f32_16x16x32_fp8_fp8(            \
              AF[mi][ks], BF[j][ks], acc[mi][j], 0, 0, 0);                    \
    __builtin_amdgcn_s_setprio(0);                                            \
  } while (0)

// fp8 swizzle/staging geometry (R13-verified), shared by gemm_sq/gemm_hop1s8.
#define FP8_GEOM()                                                            \
  int aoff[4][2], boff[4][2];                                                 \
  _Pragma("unroll")                                                           \
  for (int mi = 0; mi < 4; ++mi)                                              \
    _Pragma("unroll")                                                         \
    for (int ks = 0; ks < 2; ++ks) {                                          \
      int rh = mi * 32 + wr * 16 + (l & 15);                                  \
      int lo = rh * 64 + ks * 32 + ((l >> 4) * 8);                            \
      aoff[mi][ks] = lo ^ ((rh & 6) << 3);                                    \
    }                                                                         \
  _Pragma("unroll")                                                           \
  for (int j = 0; j < 4; ++j)                                                 \
    _Pragma("unroll")                                                         \
    for (int ks = 0; ks < 2; ++ks) {                                          \
      int rh = j * 32 + wc * 16 + (l & 15);                                   \
      int lo = rh * 64 + ks * 32 + ((l >> 4) * 8);                            \
      boff[j][ks] = lo ^ ((rh & 6) << 3);                                     \
    }                                                                         \
  const int sg_col = (((l & 3) ^ ((l >> 3) & 3)) << 4);                       \
  unsigned aLoff[2], bLoff[2];                                                \
  _Pragma("unroll")                                                           \
  for (int p = 0; p < 2; ++p) {                                               \
    int srow = p * 64 + w * 16 + (l >> 2);                                    \
    aLoff[p] = (unsigned)((m0 + srow) * 2048 + sg_col);                       \
    bLoff[p] = (unsigned)((n0 + srow) * 2048 + sg_col);                       \
  }

// ---------------------------------------------------------------------------
// Fused-squares (fp8): M2part[zh] = (1/16384) sum_{z in third} ADJ8_z @ ADJT8_z^T.
// 768 blocks = 3 blocks/CU full machine; bf16 partials (R16).
__global__ __launch_bounds__(256, 3) void gemm_sq(const unsigned char* __restrict__ ADJ8,
                                                  const unsigned char* __restrict__ ADJT8,
                                                  __bf16* __restrict__ M2part) {
  extern __shared__ char smem[];  // 32768 B
  const int tid = threadIdx.x;
  const int w = tid >> 6, l = tid & 63;
  const int wr = w >> 1, wc = w & 1;
  const size_t NN2 = (size_t)NNODE * NNODE;
  int lin = blockIdx.x + 16 * blockIdx.y + 256 * blockIdx.z;  // [0,768)
  int nlin = (lin & 7) * 96 + (lin >> 3);
  const int m0 = (nlin & 15) * 128, n0 = ((nlin >> 4) & 15) * 128;
  const int zh = nlin >> 8;      // [0,3)
  const int zb = zh * 2;
  __bf16* Cp = M2part + (size_t)zh * NN2;
  const int NTT = 64;            // 2 z * 32 K-tiles

#define AREG8(d) (smem + (d) * 8192)
#define BREG8(d) (smem + 16384 + (d) * 8192)

  FP8_GEOM();

#define STAGE8A(toff, region)                                                 \
  do {                                                                        \
    _Pragma("unroll")                                                         \
    for (int p = 0; p < 2; ++p)                                               \
      gload16((const char*)ADJ8 + (toff) + aLoff[p],                          \
              (region) + p * 4096 + w * 1024);                                \
  } while (0)
#define STAGE8B(toff, region)                                                 \
  do {                                                                        \
    _Pragma("unroll")                                                         \
    for (int p = 0; p < 2; ++p)                                               \
      gload16((const char*)ADJT8 + (toff) + bLoff[p],                         \
              (region) + p * 4096 + w * 1024);                                \
  } while (0)

  f32x4 acc[4][4] = {};
  long afA[4][2], bfA[4][2], afB[4][2], bfB[4][2];

  size_t tOff = (size_t)zb * NN2;
  STAGE8A(tOff, AREG8(0));
  STAGE8B(tOff, BREG8(0));
  STAGE8A(tOff + 64, AREG8(1));
  STAGE8B(tOff + 64, BREG8(1));
  tOff += 128;
  VMCNT4();
  BARRIER();
  READFRAGS8(0, afA, bfA);
  LGKMCNT0();
  BARRIER();

  for (int t = 0; t <= NTT - 4; t += 2) {
    STAGE8A(tOff, AREG8(0));
    STAGE8B(tOff, BREG8(0));
    tOff += (((t + 2) & 31) == 31) ? (NN2 - (size_t)31 * 64) : (size_t)64;
    VMCNT4();
    BARRIER();
    READFRAGS8(1, afB, bfB);
    MFMA8(afA, bfA);
    LGKMCNT0();
    BARRIER();
    STAGE8A(tOff, AREG8(1));
    STAGE8B(tOff, BREG8(1));
    tOff += (((t + 3) & 31) == 31) ? (NN2 - (size_t)31 * 64) : (size_t)64;
    VMCNT4();
    BARRIER();
    READFRAGS8(0, afA, bfA);
    MFMA8(afB, bfB);
    LGKMCNT0();
    BARRIER();
  }
  VMCNT0();
  BARRIER();
  READFRAGS8(1, afB, bfB);
  MFMA8(afA, bfA);
  LGKMCNT0();
  MFMA8(afB, bfB);

  const float DS = 1.f / 16384.f;
  const int crow = (l >> 4) * 4;
  const int ccol = l & 15;
#pragma unroll
  for (int mi = 0; mi < 4; ++mi)
#pragma unroll
    for (int j = 0; j < 4; ++j) {
      int r0 = m0 + mi * 32 + wr * 16 + crow;
      int cc = n0 + j * 32 + wc * 16 + ccol;
#pragma unroll
      for (int r = 0; r < 4; ++r)
        Cp[(size_t)(r0 + r) * NNODE + cc] = (__bf16)(acc[mi][j][r] * DS);
    }
#undef STAGE8A
#undef STAGE8B
#undef AREG8
#undef BREG8
}

// ---------------------------------------------------------------------------
// fp8 stage GEMM with fused transposed epilogue:
//   S_z[(b,n),c] = (1/2048) sum_v XT8[(b,c)][v] * M_z8[n][v]
__global__ __launch_bounds__(256, 3) void gemm_hop1s8(const unsigned char* __restrict__ XT8,
                                                      const unsigned char* __restrict__ M18,
                                                      const unsigned char* __restrict__ M28,
                                                      __bf16* __restrict__ S1,
                                                      __bf16* __restrict__ S2) {
  extern __shared__ char smem[];  // 32768 B
  const int tid = threadIdx.x;
  const int w = tid >> 6, l = tid & 63;
  const int wr = w >> 1, wc = w & 1;
  int lin = blockIdx.x + 16 * blockIdx.y + 256 * blockIdx.z;
  int nlin = (lin & 7) * 64 + (lin >> 3);
  const int m0 = (nlin & 15) * 128, n0 = ((nlin >> 4) & 15) * 128;
  const int z = nlin >> 8;
  const unsigned char* Bbase = z ? M28 : M18;
  const int NT = NNODE / 64;  // 32

#define AREG8(d) (smem + (d) * 8192)
#define BREG8(d) (smem + 16384 + (d) * 8192)

  FP8_GEOM();

#define STAGE8A(koff, region)                                                 \
  do {                                                                        \
    _Pragma("unroll")                                                         \
    for (int p = 0; p < 2; ++p)                                               \
      gload16((const char*)XT8 + (koff) + aLoff[p],                           \
              (region) + p * 4096 + w * 1024);                                \
  } while (0)
#define STAGE8B(koff, region)                                                 \
  do {                                                                        \
    _Pragma("unroll")                                                         \
    for (int p = 0; p < 2; ++p)                                               \
      gload16((const char*)Bbase + (koff) + bLoff[p],                         \
              (region) + p * 4096 + w * 1024);                                \
  } while (0)

  f32x4 acc[4][4] = {};
  long afA[4][2], bfA[4][2], afB[4][2], bfB[4][2];

  size_t kOff = 0;
  STAGE8A(kOff, AREG8(0));
  STAGE8B(kOff, BREG8(0));
  STAGE8A(kOff + 64, AREG8(1));
  STAGE8B(kOff + 64, BREG8(1));
  kOff += 128;
  VMCNT4();
  BARRIER();
  READFRAGS8(0, afA, bfA);
  LGKMCNT0();
  BARRIER();

  for (int t = 0; t <= NT - 4; t += 2) {
    STAGE8A(kOff, AREG8(0));
    STAGE8B(kOff, BREG8(0));
    kOff += 64;
    VMCNT4();
    BARRIER();
    READFRAGS8(1, afB, bfB);
    MFMA8(afA, bfA);
    LGKMCNT0();
    BARRIER();
    STAGE8A(kOff, AREG8(1));
    STAGE8B(kOff, BREG8(1));
    kOff += 64;
    VMCNT4();
    BARRIER();
    READFRAGS8(0, afA, bfA);
    MFMA8(afB, bfB);
    LGKMCNT0();
    BARRIER();
  }
  VMCNT0();
  BARRIER();
  READFRAGS8(1, afB, bfB);
  MFMA8(afA, bfA);
  LGKMCNT0();
  MFMA8(afB, bfB);

  // ---- epilogue: descale, LDS transpose T[n][m] (slot-XOR), coalesced write
  {
    __syncthreads();
    const float DS = 1.f / 2048.f;  // 1/(16*128)
    const int crow = (l >> 4) * 4;
    const int ccol = l & 15;
    char* T = smem;  // 128 x 256 B = 32768
#pragma unroll
    for (int mi = 0; mi < 4; ++mi)
#pragma unroll
      for (int j = 0; j < 4; ++j) {
        int ml = mi * 32 + wr * 16 + crow;
        int nl = j * 32 + wc * 16 + ccol;
        bf16x4 v;
#pragma unroll
        for (int r = 0; r < 4; ++r) v[r] = (__bf16)(acc[mi][j][r] * DS);
        *(bf16x4*)(T + nl * 256 + ((ml * 2) ^ ((nl & 7) << 4))) = v;
      }
    __syncthreads();
    __bf16* dst = z ? S2 : S1;
    const int bA = m0 >> 6;
#pragma unroll
    for (int it = 0; it < 4; ++it) {
      int nl = (tid >> 3) + it * 32;
      int seg = tid & 7;
      int xorv = (nl & 7) << 4;
      const char* src = T + nl * 256;
      bf16x8 v0 = *(const bf16x8*)(src + ((seg * 32) ^ xorv));
      bf16x8 v1 = *(const bf16x8*)(src + ((seg * 32 + 16) ^ xorv));
      int b = bA + (seg >> 2);
      size_t o = ((size_t)b * NNODE + n0 + nl) * 64 + (seg & 3) * 16;
      *(bf16x8*)(dst + o) = v0;
      *(bf16x8*)(dst + o + 8) = v1;
    }
  }
#undef STAGE8A
#undef STAGE8B
#undef AREG8
#undef BREG8
}

// ---------------------------------------------------------------------------
// M28[i] = fp8(128 * (M2a[i] + M2b[i] + M2c[i])), bf16 partials in
__global__ __launch_bounds__(256) void combine_m2(const __bf16* __restrict__ M2p,
                                                  unsigned char* __restrict__ M28) {
  const size_t NN2 = (size_t)NNODE * NNODE;
  size_t i = ((size_t)blockIdx.x * 256 + threadIdx.x) * 8;
  bf16x8 a = *(const bf16x8*)(M2p + i);
  bf16x8 b = *(const bf16x8*)(M2p + NN2 + i);
  bf16x8 c = *(const bf16x8*)(M2p + 2 * NN2 + i);
  const float SA = 128.f;
  float sv[8];
#pragma unroll
  for (int k = 0; k < 8; ++k)
    sv[k] = ((float)a[k] + (float)b[k] + (float)c[k]) * SA;
  int w0 = __builtin_amdgcn_cvt_pk_fp8_f32(sv[0], sv[1], 0, false);
  w0 = __builtin_amdgcn_cvt_pk_fp8_f32(sv[2], sv[3], w0, true);
  int w1 = __builtin_amdgcn_cvt_pk_fp8_f32(sv[4], sv[5], 0, false);
  w1 = __builtin_amdgcn_cvt_pk_fp8_f32(sv[6], sv[7], w1, true);
  int2 pk; pk.x = w0; pk.y = w1;
  *(int2*)(M28 + i) = pk;
}

// ---------------------------------------------------------------------------
// Gate linear GEMM: [65536 x 192] @ Wt^T, K=192, N=128, fused epilogues.
// MODE 0: cols 0-63 -> z=sigmoid -> zbuf(f32); cols 64-127 -> r ->
//         rx=(bf16)(r*hid) row-major AND fp8(16*rx)^T -> XT8out.
// MODE 1: cols 0-63 -> c=tanh -> out=(1-z)*hid+z*c (f32)
template <int MODE>
__global__ __launch_bounds__(256) void gemm_lin(const __bf16* __restrict__ Xp,
                                                const __bf16* __restrict__ S1,
                                                const __bf16* __restrict__ S2,
                                                const __bf16* __restrict__ Wt,
                                                const float* __restrict__ b0,
                                                const float* __restrict__ b1,
                                                const float* __restrict__ wpre,
                                                const float* __restrict__ wadp,
                                                const float* __restrict__ hid,
                                                float* __restrict__ zbuf,
                                                __bf16* __restrict__ rxout,
                                                unsigned char* __restrict__ XT8out,
                                                float* __restrict__ outp) {
  __shared__ __bf16 As[128 * 32];
  __shared__ __bf16 Bs[128 * 32];
  __shared__ char T[64 * 256];  // rx transpose staging (MODE 0)
  const int tid = threadIdx.x;
  const int wave = tid >> 6, lane = tid & 63;
  const int wr = wave >> 1, wc = wave & 1;
  const int m0 = blockIdx.x * 128;
  const int rowA = tid >> 2;
  const int colb = (tid & 3) * 16;
  const __bf16* srcs[3] = {Xp, S1, S2};
  char* asD0 = (char*)As + wave * 1024;
  char* asD1 = (char*)As + 4096 + wave * 1024;
  char* bsD0 = (char*)Bs + wave * 1024;
  char* bsD1 = (char*)Bs + 4096 + wave * 1024;

  f32x4 acc[4][4] = {};

#pragma unroll
  for (int kt = 0; kt < 6; ++kt) {
    const __bf16* Ab = srcs[kt >> 1];
    const char* aS0 = (const char*)(Ab + (size_t)(m0 + rowA) * 64) + (kt & 1) * 64 + colb;
    const char* aS1 = (const char*)(Ab + (size_t)(m0 + rowA + 64) * 64) + (kt & 1) * 64 + colb;
    const char* bS0 = (const char*)(Wt + (size_t)rowA * 192) + kt * 64 + colb;
    const char* bS1 = (const char*)(Wt + (size_t)(rowA + 64) * 192) + kt * 64 + colb;
    gload16(aS0, asD0);
    gload16(aS1, asD1);
    gload16(bS0, bsD0);
    gload16(bS1, bsD1);
    __syncthreads();
    bf16x8 af[4], bfr[4];
#pragma unroll
    for (int mi = 0; mi < 4; ++mi)
      af[mi] = *(const bf16x8*)((const char*)As +
               ((wr * 64 + mi * 16 + (lane & 15)) * 64 + (lane >> 4) * 16));
#pragma unroll
    for (int ni = 0; ni < 4; ++ni)
      bfr[ni] = *(const bf16x8*)((const char*)Bs +
               ((wc * 64 + ni * 16 + (lane & 15)) * 64 + (lane >> 4) * 16));
#pragma unroll
    for (int mi = 0; mi < 4; ++mi)
#pragma unroll
      for (int ni = 0; ni < 4; ++ni)
        acc[mi][ni] = __builtin_amdgcn_mfma_f32_16x16x32_bf16(af[mi], bfr[ni],
                                                              acc[mi][ni], 0, 0, 0);
    __syncthreads();
  }

  const float wp = *wpre, wa = *wadp;
  const float s = 2.f * wp + wa;
  const int crow = (lane >> 4) * 4;
  const int ccol = lane & 15;
#pragma unroll
  for (int mi = 0; mi < 4; ++mi)
#pragma unroll
    for (int ni = 0; ni < 4; ++ni) {
      int r0 = m0 + wr * 64 + mi * 16 + crow;
      int col = wc * 64 + ni * 16 + ccol;
      int cf = col & 63;
      if (MODE == 0) {
        if (col < 64) {
#pragma unroll
          for (int r = 0; r < 4; ++r) {
            int row = r0 + r;
            float g = acc[mi][ni][r] + s * b0[cf];
            zbuf[(size_t)row * 64 + cf] = 1.f / (1.f + __expf(-g));
          }
        } else {
          bf16x4 tv;
#pragma unroll
          for (int r = 0; r < 4; ++r) {
            int row = r0 + r;
            float g = acc[mi][ni][r] + s * b1[cf];
            float rv = 1.f / (1.f + __expf(-g));
            __bf16 rxv = (__bf16)(rv * hid[(size_t)row * 64 + cf]);
            rxout[(size_t)row * 64 + cf] = rxv;
            tv[r] = rxv;
          }
          int vl0 = wr * 64 + mi * 16 + crow;
          *(bf16x4*)(T + cf * 256 + ((vl0 * 2) ^ ((cf & 7) << 4))) = tv;
        }
      } else {
        if (col < 64) {
#pragma unroll
          for (int r = 0; r < 4; ++r) {
            int row = r0 + r;
            float g = acc[mi][ni][r] + s * b0[cf];
            float cv = 1.f - 2.f / (1.f + __expf(2.f * g));
            float zv = zbuf[(size_t)row * 64 + cf];
            float hv = hid[(size_t)row * 64 + cf];
            outp[(size_t)row * 64 + cf] = (1.f - zv) * hv + zv * cv;
          }
        }
      }
    }

  if (MODE == 0) {
    __syncthreads();
    const int b = m0 >> 11;
    const int v0 = m0 & 2047;
    const float SX = 16.f;
#pragma unroll
    for (int it = 0; it < 4; ++it) {
      int rr = it * 16 + (tid >> 4);
      int seg = tid & 15;
      bf16x8 v = *(const bf16x8*)(T + rr * 256 + ((seg * 16) ^ ((rr & 7) << 4)));
      int w0 = __builtin_amdgcn_cvt_pk_fp8_f32((float)v[0] * SX, (float)v[1] * SX, 0, false);
      w0 = __builtin_amdgcn_cvt_pk_fp8_f32((float)v[2] * SX, (float)v[3] * SX, w0, true);
      int w1 = __builtin_amdgcn_cvt_pk_fp8_f32((float)v[4] * SX, (float)v[5] * SX, 0, false);
      w1 = __builtin_amdgcn_cvt_pk_fp8_f32((float)v[6] * SX, (float)v[7] * SX, w1, true);
      int2 pk; pk.x = w0; pk.y = w1;
      *(int2*)(XT8out + ((size_t)(b * 64 + rr)) * NNODE + v0 + seg * 8) = pk;
    }
  }
}

// ---------------------------------------------------------------------------
extern "C" void kernel_launch(void* const* d_in, const int* in_sizes, int n_in,
                              void* d_out, int out_size, void* d_ws, size_t ws_size,
                              hipStream_t stream) {
  (void)in_sizes; (void)n_in; (void)out_size;
  const float* x    = (const float*)d_in[0];
  const float* A1   = (const float*)d_in[1];
  const float* A2   = (const float*)d_in[2];
  const float* E1   = (const float*)d_in[3];
  const float* E2   = (const float*)d_in[4];
  const float* Wz   = (const float*)d_in[5];
  const float* bz   = (const float*)d_in[6];
  const float* Wr   = (const float*)d_in[7];
  const float* br   = (const float*)d_in[8];
  const float* Wc   = (const float*)d_in[9];
  const float* bc   = (const float*)d_in[10];
  const float* wpre = (const float*)d_in[11];
  const float* wadp = (const float*)d_in[12];
  float* out = (float*)d_out;

  char* ws = (char*)d_ws;
  const size_t NN2 = (size_t)NNODE * NNODE;  // 4,194,304
  const size_t NN2B = NN2 * 2;               // bytes per bf16 slice
  unsigned char* ADJ8  = (unsigned char*)(ws + 6 * NN2B);           // 6 fp8
  unsigned char* ADJT8 = (unsigned char*)(ws + 6 * NN2B + 6 * NN2); // 6 fp8
  __bf16* SC   = (__bf16*)(ws + 12 * NN2B);     // scores (4 slices), then:
  __bf16* M2p  = (__bf16*)(ws + 12 * NN2B);     // bf16 partials x3 = [12,15)
  unsigned char* M18 = (unsigned char*)(ws + 18 * NN2B);        // fp8
  unsigned char* M28 = (unsigned char*)(ws + 18 * NN2B + NN2);  // fp8
  unsigned char* XT8 = (unsigned char*)(ws + 20 * NN2B);        // fp8
  __bf16* xbf  = (__bf16*)(ws + 21 * NN2B);
  __bf16* rx   = (__bf16*)(ws + 22 * NN2B);
  __bf16* S1   = (__bf16*)(ws + 2 * NN2B);      // old ADJ region (free)
  __bf16* S2   = (__bf16*)(ws + 3 * NN2B);
  float*  zbuf = (float*)(ws + 4 * NN2B);
  __bf16* E1p  = (__bf16*)(ws + 23 * NN2B);
  __bf16* E2p  = E1p + 4 * NNODE * 32;
  __bf16* Wzrt = E2p + 4 * NNODE * 32;
  __bf16* Wct  = Wzrt + 128 * 192;
  if (ws_size < 23 * NN2B + 2 * 4 * NNODE * 32 * 2 + 2 * 128 * 192 * 2) return;

  // --- adjacency construction (fused)
  prep_ew<<<224, 256, 0, stream>>>(E1, E2, Wz, Wr, Wc, wpre, wadp,
                                   E1p, E2p, Wzrt, Wct);
  score_gemm<<<dim3(16, 16, 4), 256, 0, stream>>>(E1p, E2p, SC);
  soft_tx<<<3072, 256, 0, stream>>>(SC, ADJ8, x, XT8, xbf);
  prep_adj<<<dim3(32, 32), 256, 0, stream>>>(A1, A2, ADJ8, ADJT8, M18,
                                             wpre, wadp);

  // --- M2 = sum_z w_z A_z^2 (fp8; 768 blocks = 3/CU, bf16 partials)
  gemm_sq<<<dim3(16, 16, 3), 256, 32768, stream>>>(ADJ8, ADJT8, M2p);
  combine_m2<<<2048, 256, 0, stream>>>(M2p, M28);

  // --- stage 1: S1 = M1 x, S2 = M2 x (fp8, fused transposed epilogue)
  gemm_hop1s8<<<dim3(16, 16, 2), 256, 32768, stream>>>(XT8, M18, M28, S1, S2);
  gemm_lin<0><<<512, 256, 0, stream>>>(xbf, S1, S2, Wzrt, bz, br, wpre, wadp,
                                       x, zbuf, rx, XT8, nullptr);

  // --- stage 2: hops on r*x (XT8 holds fp8(16*rx)^T from gemm_lin<0>)
  gemm_hop1s8<<<dim3(16, 16, 2), 256, 32768, stream>>>(XT8, M18, M28, S1, S2);
  gemm_lin<1><<<512, 256, 0, stream>>>(rx, S1, S2, Wct, bc, nullptr, wpre, wadp,
                                       x, zbuf, nullptr, nullptr, out);
}

// Round 17
// 177.355 us; speedup vs baseline: 1.2084x; 1.1272x over previous
//
#include <hip/hip_runtime.h>

#define NNODE 2048
#define NBATCH 32

typedef __attribute__((ext_vector_type(4))) float f32x4;
typedef __attribute__((ext_vector_type(8))) __bf16 bf16x8;
typedef __attribute__((ext_vector_type(4))) __bf16 bf16x4;
typedef __attribute__((ext_vector_type(4))) int i32x4;
typedef __attribute__((ext_vector_type(8))) int i32x8;

__device__ __forceinline__ void gload16(const void* g, void* lds) {
  __builtin_amdgcn_global_load_lds(
      (const __attribute__((address_space(1))) unsigned int*)g,
      (__attribute__((address_space(3))) unsigned int*)lds, 16, 0, 0);
}

// ---------------------------------------------------------------------------
// Merged: prep_e (blocks 0..127) + prep_w (blocks 128..223)
__global__ __launch_bounds__(256) void prep_ew(const float* __restrict__ E1,
                                               const float* __restrict__ E2,
                                               const float* __restrict__ Wz,
                                               const float* __restrict__ Wr,
                                               const float* __restrict__ Wc,
                                               const float* __restrict__ wpre,
                                               const float* __restrict__ wadp,
                                               __bf16* __restrict__ E1p,
                                               __bf16* __restrict__ E2p,
                                               __bf16* __restrict__ Wzrt,
                                               __bf16* __restrict__ Wct) {
  if (blockIdx.x < 128) {
    int idx = blockIdx.x * 256 + threadIdx.x;  // 0..32767
    int cq = idx & 3;
    int n = (idx >> 2) & 2047;
    int h = idx >> 13;
    const float4 q1 = *(const float4*)(E1 + (size_t)(n * 4 + h) * 16 + cq * 4);
    const float4 q2 = *(const float4*)(E2 + (size_t)(n * 4 + h) * 16 + cq * 4);
    size_t o = ((size_t)h * NNODE + n) * 32 + cq * 4;
    E1p[o + 0] = (__bf16)q1.x; E1p[o + 1] = (__bf16)q1.y;
    E1p[o + 2] = (__bf16)q1.z; E1p[o + 3] = (__bf16)q1.w;
    E2p[o + 0] = (__bf16)q2.x; E2p[o + 1] = (__bf16)q2.y;
    E2p[o + 2] = (__bf16)q2.z; E2p[o + 3] = (__bf16)q2.w;
    size_t oz = o + 16;
    E1p[oz + 0] = (__bf16)0.f; E1p[oz + 1] = (__bf16)0.f;
    E1p[oz + 2] = (__bf16)0.f; E1p[oz + 3] = (__bf16)0.f;
    E2p[oz + 0] = (__bf16)0.f; E2p[oz + 1] = (__bf16)0.f;
    E2p[oz + 2] = (__bf16)0.f; E2p[oz + 3] = (__bf16)0.f;
  } else {
    int idx = (blockIdx.x - 128) * 256 + threadIdx.x;  // 0 .. 128*192-1
    int rr = idx / 192, k = idx % 192;
    float s = 2.f * (*wpre) + (*wadp);
    float sc = (k < 64) ? s : 1.f;
    float vz = (rr < 64) ? Wz[(size_t)k * 64 + rr] : Wr[(size_t)k * 64 + rr - 64];
    Wzrt[idx] = (__bf16)(vz * sc);
    float vc = (rr < 64) ? Wc[(size_t)k * 64 + rr] * sc : 0.f;
    Wct[idx] = (__bf16)vc;
  }
}

// ---------------------------------------------------------------------------
// SC[h][w][v] = relu(E1p_h @ E2p_h^T)/4, bf16. Single K=32 MFMA step.
__global__ __launch_bounds__(256) void score_gemm(const __bf16* __restrict__ E1p,
                                                  const __bf16* __restrict__ E2p,
                                                  __bf16* __restrict__ SC) {
  __shared__ __bf16 As[128 * 32];
  __shared__ __bf16 Bs[128 * 32];
  const int tid = threadIdx.x;
  const int wave = tid >> 6, lane = tid & 63;
  const int wr = wave >> 1, wc = wave & 1;
  const int h = blockIdx.z;
  const int m0 = blockIdx.x * 128, n0 = blockIdx.y * 128;
  const __bf16* A = E1p + (size_t)h * NNODE * 32;
  const __bf16* Bt = E2p + (size_t)h * NNODE * 32;
  const int rowA = tid >> 2;
  const int colb = (tid & 3) * 16;
  gload16((const char*)(A + (size_t)(m0 + rowA) * 32) + colb, (char*)As + wave * 1024);
  gload16((const char*)(A + (size_t)(m0 + rowA + 64) * 32) + colb, (char*)As + 4096 + wave * 1024);
  gload16((const char*)(Bt + (size_t)(n0 + rowA) * 32) + colb, (char*)Bs + wave * 1024);
  gload16((const char*)(Bt + (size_t)(n0 + rowA + 64) * 32) + colb, (char*)Bs + 4096 + wave * 1024);
  __syncthreads();

  f32x4 acc[4][4] = {};
  bf16x8 af[4], bfr[4];
#pragma unroll
  for (int mi = 0; mi < 4; ++mi)
    af[mi] = *(const bf16x8*)((const char*)As +
             ((wr * 64 + mi * 16 + (lane & 15)) * 64 + (lane >> 4) * 16));
#pragma unroll
  for (int ni = 0; ni < 4; ++ni)
    bfr[ni] = *(const bf16x8*)((const char*)Bs +
             ((wc * 64 + ni * 16 + (lane & 15)) * 64 + (lane >> 4) * 16));
#pragma unroll
  for (int mi = 0; mi < 4; ++mi)
#pragma unroll
    for (int ni = 0; ni < 4; ++ni)
      acc[mi][ni] = __builtin_amdgcn_mfma_f32_16x16x32_bf16(af[mi], bfr[ni],
                                                            acc[mi][ni], 0, 0, 0);

  const int crow = (lane >> 4) * 4;
  const int ccol = lane & 15;
#pragma unroll
  for (int mi = 0; mi < 4; ++mi)
#pragma unroll
    for (int ni = 0; ni < 4; ++ni) {
      int r0 = m0 + wr * 64 + mi * 16 + crow;
      int cc = n0 + wc * 64 + ni * 16 + ccol;
#pragma unroll
      for (int r = 0; r < 4; ++r) {
        float val = fmaxf(acc[mi][ni][r], 0.f) * 0.25f;
        SC[((size_t)h * NNODE + r0 + r) * NNODE + cc] = (__bf16)val;
      }
    }
}

// ---------------------------------------------------------------------------
// Merged: blocks 0..2047 -> row softmax (SC -> fp8 ADJ8 slices 2..5 directly,
// scaled x128); blocks 2048..3071 -> transpose_x: x f32 -> XT8 fp8(16x) and
// xbf bf16 [B*N,64].
__global__ __launch_bounds__(256) void soft_tx(const __bf16* __restrict__ SC,
                                               unsigned char* __restrict__ ADJ8,
                                               const float* __restrict__ x,
                                               unsigned char* __restrict__ XT8,
                                               __bf16* __restrict__ xbf) {
  const int tid = threadIdx.x;
  const size_t NN2 = (size_t)NNODE * NNODE;
  if (blockIdx.x < 2048) {
    const int wave = tid >> 6, lane = tid & 63;
    const size_t row = (size_t)blockIdx.x * 4 + wave;
    const __bf16* src = SC + row * NNODE;
    unsigned char* dst = ADJ8 + 2 * NN2 + row * NNODE;  // slices 2..5
    float v[32];
    float mx = 0.f;
#pragma unroll
    for (int j = 0; j < 4; ++j) {
      bf16x8 q = *(const bf16x8*)(src + j * 512 + lane * 8);
#pragma unroll
      for (int i = 0; i < 8; ++i) {
        float f = (float)q[i];
        v[j * 8 + i] = f;
        mx = fmaxf(mx, f);
      }
    }
#pragma unroll
    for (int o = 32; o > 0; o >>= 1) mx = fmaxf(mx, __shfl_xor(mx, o));
    float s = 0.f;
#pragma unroll
    for (int i = 0; i < 32; ++i) {
      v[i] = __expf(v[i] - mx);
      s += v[i];
    }
#pragma unroll
    for (int o = 32; o > 0; o >>= 1) s += __shfl_xor(s, o);
    float inv = 128.f / s;  // x128 fp8 scale folded in
#pragma unroll
    for (int j = 0; j < 4; ++j) {
      int w0 = __builtin_amdgcn_cvt_pk_fp8_f32(v[j * 8 + 0] * inv, v[j * 8 + 1] * inv, 0, false);
      w0 = __builtin_amdgcn_cvt_pk_fp8_f32(v[j * 8 + 2] * inv, v[j * 8 + 3] * inv, w0, true);
      int w1 = __builtin_amdgcn_cvt_pk_fp8_f32(v[j * 8 + 4] * inv, v[j * 8 + 5] * inv, 0, false);
      w1 = __builtin_amdgcn_cvt_pk_fp8_f32(v[j * 8 + 6] * inv, v[j * 8 + 7] * inv, w1, true);
      int2 pk; pk.x = w0; pk.y = w1;
      *(int2*)(dst + j * 512 + lane * 8) = pk;
    }
  } else {
    const int idx = blockIdx.x - 2048;
    const int b = idx >> 5, v0 = (idx & 31) * 64;
    __shared__ float t[64][65];
    const int vr = tid >> 2, c0 = (tid & 3) * 16;
    const float* src = x + ((size_t)b * NNODE + v0 + vr) * 64 + c0;
    __bf16* xb = xbf + ((size_t)b * NNODE + v0 + vr) * 64 + c0;
#pragma unroll
    for (int j = 0; j < 4; ++j) {
      float4 q = ((const float4*)src)[j];
      t[vr][c0 + j * 4 + 0] = q.x;
      t[vr][c0 + j * 4 + 1] = q.y;
      t[vr][c0 + j * 4 + 2] = q.z;
      t[vr][c0 + j * 4 + 3] = q.w;
      xb[j * 4 + 0] = (__bf16)q.x;
      xb[j * 4 + 1] = (__bf16)q.y;
      xb[j * 4 + 2] = (__bf16)q.z;
      xb[j * 4 + 3] = (__bf16)q.w;
    }
    __syncthreads();
    const float SX = 16.f;
#pragma unroll
    for (int jr = 0; jr < 4; ++jr) {
      int c = jr * 16 + (tid >> 4);
      int vq = (tid & 15) * 4;
      int w0 = __builtin_amdgcn_cvt_pk_fp8_f32(t[vq][c] * SX, t[vq + 1][c] * SX, 0, false);
      w0 = __builtin_amdgcn_cvt_pk_fp8_f32(t[vq + 2][c] * SX, t[vq + 3][c] * SX, w0, true);
      *(int*)(XT8 + ((size_t)(b * 64 + c)) * NNODE + v0 + vq) = w0;
    }
  }
}

// ---------------------------------------------------------------------------
// Fused adjacency prep (x128 domain): z<2 reads A1/A2 f32, writes ADJ8;
// z>=2 reads fp8 ADJ8 (written by soft_tx). All z: ADJT8 = fp8(wz * v128),
// M18 = fp8(sum wz * v128).
__global__ __launch_bounds__(256) void prep_adj(const float* __restrict__ A1,
                                                const float* __restrict__ A2,
                                                unsigned char* __restrict__ ADJ8,
                                                unsigned char* __restrict__ ADJT8,
                                                unsigned char* __restrict__ M18,
                                                const float* __restrict__ wpre,
                                                const float* __restrict__ wadp) {
  const int r0 = blockIdx.x * 64, c0 = blockIdx.y * 64;
  const int tid = threadIdx.x;
  const size_t NN2 = (size_t)NNODE * NNODE;
  const float wp = *wpre, wa = *wadp * 0.25f;
  const float SA = 128.f;
  __shared__ float t[64][65];
  const int vr = tid >> 2, cg = (tid & 3) * 16;
  float m1acc[16] = {};

  for (int z = 0; z < 6; ++z) {
    const float wz = (z < 2) ? wp : wa;
    float vv[16];  // values in x128 domain
    if (z < 2) {
      const float* src = (z == 0 ? A1 : A2) + (size_t)(r0 + vr) * NNODE + c0 + cg;
#pragma unroll
      for (int j = 0; j < 4; ++j) {
        float4 q = ((const float4*)src)[j];
        vv[j * 4 + 0] = q.x * SA; vv[j * 4 + 1] = q.y * SA;
        vv[j * 4 + 2] = q.z * SA; vv[j * 4 + 3] = q.w * SA;
      }
      int4 pk;
#pragma unroll
      for (int q = 0; q < 4; ++q) {
        int w0 = __builtin_amdgcn_cvt_pk_fp8_f32(vv[4 * q], vv[4 * q + 1], 0, false);
        w0 = __builtin_amdgcn_cvt_pk_fp8_f32(vv[4 * q + 2], vv[4 * q + 3], w0, true);
        (&pk.x)[q] = w0;
      }
      *(int4*)(ADJ8 + (size_t)z * NN2 + (size_t)(r0 + vr) * NNODE + c0 + cg) = pk;
    } else {
      int4 pk = *(const int4*)(ADJ8 + (size_t)z * NN2 + (size_t)(r0 + vr) * NNODE + c0 + cg);
#pragma unroll
      for (int q = 0; q < 4; ++q) {
        int w0 = (&pk.x)[q];
        vv[4 * q + 0] = __builtin_amdgcn_cvt_f32_fp8(w0, 0);
        vv[4 * q + 1] = __builtin_amdgcn_cvt_f32_fp8(w0, 1);
        vv[4 * q + 2] = __builtin_amdgcn_cvt_f32_fp8(w0, 2);
        vv[4 * q + 3] = __builtin_amdgcn_cvt_f32_fp8(w0, 3);
      }
    }
#pragma unroll
    for (int i = 0; i < 16; ++i) {
      m1acc[i] += wz * vv[i];
      t[vr][cg + i] = vv[i];
    }
    __syncthreads();
    {
#pragma unroll
      for (int jr = 0; jr < 4; ++jr) {
        int c = jr * 16 + (tid >> 4);
        int vq = (tid & 15) * 4;
        int w0 = __builtin_amdgcn_cvt_pk_fp8_f32(t[vq][c] * wz, t[vq + 1][c] * wz, 0, false);
        w0 = __builtin_amdgcn_cvt_pk_fp8_f32(t[vq + 2][c] * wz, t[vq + 3][c] * wz, w0, true);
        *(int*)(ADJT8 + (size_t)z * NN2 + (size_t)(c0 + c) * NNODE + r0 + vq) = w0;
      }
    }
    __syncthreads();
  }
  {
    int4 pk;
#pragma unroll
    for (int q = 0; q < 4; ++q) {
      int w0 = __builtin_amdgcn_cvt_pk_fp8_f32(m1acc[4 * q], m1acc[4 * q + 1], 0, false);
      w0 = __builtin_amdgcn_cvt_pk_fp8_f32(m1acc[4 * q + 2], m1acc[4 * q + 3], w0, true);
      (&pk.x)[q] = w0;
    }
    *(int4*)(M18 + (size_t)(r0 + vr) * NNODE + c0 + cg) = pk;
  }
}

// ---------------------------------------------------------------------------
#define VMCNT0() asm volatile("s_waitcnt vmcnt(0)" ::: "memory")
#define VMCNT4() asm volatile("s_waitcnt vmcnt(4)" ::: "memory")
#define VMCNT8() asm volatile("s_waitcnt vmcnt(8)" ::: "memory")
#define LGKMCNT0() asm volatile("s_waitcnt lgkmcnt(0)" ::: "memory")
#define BARRIER() asm volatile("s_barrier" ::: "memory")

// fp8 frag helpers (K=32 path, hop1s8)
#define READFRAGS8(d, AF, BF)                                                 \
  do {                                                                        \
    _Pragma("unroll")                                                         \
    for (int mi = 0; mi < 4; ++mi) {                                          \
      AF[mi][0] = *(const long*)(AREG8(d) + aoff[mi][0]);                     \
      AF[mi][1] = *(const long*)(AREG8(d) + aoff[mi][1]);                     \
    }                                                                         \
    _Pragma("unroll")                                                         \
    for (int j = 0; j < 4; ++j) {                                             \
      BF[j][0] = *(const long*)(BREG8(d) + boff[j][0]);                       \
      BF[j][1] = *(const long*)(BREG8(d) + boff[j][1]);                       \
    }                                                                         \
  } while (0)

#define MFMA8(AF, BF)                                                         \
  do {                                                                        \
    __builtin_amdgcn_s_setprio(1);                                            \
    _Pragma("unroll")                                                         \
    for (int mi = 0; mi < 4; ++mi)                                            \
      _Pragma("unroll")                                                       \
      for (int j = 0; j < 4; ++j)                                             \
        _Pragma("unroll")                                                     \
        for (int ks = 0; ks < 2; ++ks)                                        \
          acc[mi][j] = __builtin_amdgcn_mfma_f32_16x16x32_fp8_fp8(            \
              AF[mi][ks], BF[j][ks], acc[mi][j], 0, 0, 0);                    \
    __builtin_amdgcn_s_setprio(0);                                            \
  } while (0)

// fp8 K=32 swizzle/staging geometry (R13-verified), used by gemm_hop1s8.
#define FP8_GEOM()                                                            \
  int aoff[4][2], boff[4][2];                                                 \
  _Pragma("unroll")                                                           \
  for (int mi = 0; mi < 4; ++mi)                                              \
    _Pragma("unroll")                                                         \
    for (int ks = 0; ks < 2; ++ks) {                                          \
      int rh = mi * 32 + wr * 16 + (l & 15);                                  \
      int lo = rh * 64 + ks * 32 + ((l >> 4) * 8);                            \
      aoff[mi][ks] = lo ^ ((rh & 6) << 3);                                    \
    }                                                                         \
  _Pragma("unroll")                                                           \
  for (int j = 0; j < 4; ++j)                                                 \
    _Pragma("unroll")                                                         \
    for (int ks = 0; ks < 2; ++ks) {                                          \
      int rh = j * 32 + wc * 16 + (l & 15);                                   \
      int lo = rh * 64 + ks * 32 + ((l >> 4) * 8);                            \
      boff[j][ks] = lo ^ ((rh & 6) << 3);                                     \
    }                                                                         \
  const int sg_col = (((l & 3) ^ ((l >> 3) & 3)) << 4);                       \
  unsigned aLoff[2], bLoff[2];                                                \
  _Pragma("unroll")                                                           \
  for (int p = 0; p < 2; ++p) {                                               \
    int srow = p * 64 + w * 16 + (l >> 2);                                    \
    aLoff[p] = (unsigned)((m0 + srow) * 2048 + sg_col);                       \
    bLoff[p] = (unsigned)((n0 + srow) * 2048 + sg_col);                       \
  }

// ---------------------------------------------------------------------------
// Fused-squares (MX-scaled fp8, K=128): M2part[zh] = (1/16384) *
//   sum_{z in half} ADJ8_z @ ADJT8_z^T, scales fixed at 1.0 (0x7F e8m0).
// BK=128, regions 16 KiB ([128 rows][128 B] — the R4-verified swizzle
// geometry), LDS 64 KiB -> 2 blocks/CU, grid 512 = exactly full. R11
// pipeline, vmcnt(8) (8 loads/tile). bf16 partials x2.
__global__ __launch_bounds__(256, 2) void gemm_sq(const unsigned char* __restrict__ ADJ8,
                                                  const unsigned char* __restrict__ ADJT8,
                                                  __bf16* __restrict__ M2part) {
  extern __shared__ char smem[];  // 65536 B
  const int tid = threadIdx.x;
  const int w = tid >> 6, l = tid & 63;
  const int wr = w >> 1, wc = w & 1;
  const size_t NN2 = (size_t)NNODE * NNODE;
  int lin = blockIdx.x + 16 * blockIdx.y + 256 * blockIdx.z;  // [0,512)
  int nlin = (lin & 7) * 64 + (lin >> 3);
  const int m0 = (nlin & 15) * 128, n0 = ((nlin >> 4) & 15) * 128;
  const int zh = nlin >> 8;      // [0,2)
  const int zb = zh * 3;
  __bf16* Cp = M2part + (size_t)zh * NN2;
  const int NTT = 48;            // 3 z * 16 K-tiles (BK=128)

#define AREG(d) (smem + (d) * 16384)
#define BREG(d) (smem + 32768 + (d) * 16384)

  // frag = 32 B/lane = two 16B units at row (l&15), units (l>>4)*2 + {0,1};
  // 3-bit XOR swizzle on 16B units (R4-verified geometry).
  int aoff[4][2], boff[4][2];
#pragma unroll
  for (int mi = 0; mi < 4; ++mi)
#pragma unroll
    for (int part = 0; part < 2; ++part) {
      int rh = mi * 32 + wr * 16 + (l & 15);
      int lo = rh * 128 + (l >> 4) * 32 + part * 16;
      aoff[mi][part] = lo ^ ((rh & 7) << 4);
    }
#pragma unroll
  for (int j = 0; j < 4; ++j)
#pragma unroll
    for (int part = 0; part < 2; ++part) {
      int rh = j * 32 + wc * 16 + (l & 15);
      int lo = rh * 128 + (l >> 4) * 32 + part * 16;
      boff[j][part] = lo ^ ((rh & 7) << 4);
    }

  // staging: LDS dest linear; inverse-swizzled global source column
  const int sg_row = w * 8 + (l >> 3);
  const int sg_col = (((l & 7) ^ ((l >> 3) & 7)) << 4);
  unsigned aLoff[4], bLoff[4];
#pragma unroll
  for (int p = 0; p < 4; ++p) {
    aLoff[p] = (unsigned)((m0 + p * 32 + sg_row) * 2048 + sg_col);
    bLoff[p] = (unsigned)((n0 + p * 32 + sg_row) * 2048 + sg_col);
  }

#define STAGEXA(toff, region)                                                 \
  do {                                                                        \
    _Pragma("unroll")                                                         \
    for (int p = 0; p < 4; ++p)                                               \
      gload16((const char*)ADJ8 + (toff) + aLoff[p],                          \
              (region) + p * 4096 + w * 1024);                                \
  } while (0)
#define STAGEXB(toff, region)                                                 \
  do {                                                                        \
    _Pragma("unroll")                                                         \
    for (int p = 0; p < 4; ++p)                                               \
      gload16((const char*)ADJT8 + (toff) + bLoff[p],                         \
              (region) + p * 4096 + w * 1024);                                \
  } while (0)

#define RDFRAG(region, o0, o1)                                                \
  __builtin_shufflevector(*(const i32x4*)((region) + (o0)),                   \
                          *(const i32x4*)((region) + (o1)),                   \
                          0, 1, 2, 3, 4, 5, 6, 7)

#define READFRAGSX(d, AF, BF)                                                 \
  do {                                                                        \
    _Pragma("unroll")                                                         \
    for (int mi = 0; mi < 4; ++mi)                                            \
      AF[mi] = RDFRAG(AREG(d), aoff[mi][0], aoff[mi][1]);                     \
    _Pragma("unroll")                                                         \
    for (int j = 0; j < 4; ++j)                                               \
      BF[j] = RDFRAG(BREG(d), boff[j][0], boff[j][1]);                        \
  } while (0)

  const int SC1 = 0x7F7F7F7F;  // e8m0 scales = 1.0 everywhere
#define MFMAX(AF, BF)                                                         \
  do {                                                                        \
    __builtin_amdgcn_s_setprio(1);                                            \
    _Pragma("unroll")                                                         \
    for (int mi = 0; mi < 4; ++mi)                                            \
      _Pragma("unroll")                                                       \
      for (int j = 0; j < 4; ++j)                                             \
        acc[mi][j] = __builtin_amdgcn_mfma_scale_f32_16x16x128_f8f6f4(        \
            AF[mi], BF[j], acc[mi][j], 0, 0, 0, SC1, 0, SC1);                 \
    __builtin_amdgcn_s_setprio(0);                                            \
  } while (0)

  f32x4 acc[4][4] = {};
  i32x8 afA[4], bfA[4], afB[4], bfB[4];

  size_t tOff = (size_t)zb * NN2;
  STAGEXA(tOff, AREG(0));
  STAGEXB(tOff, BREG(0));
  STAGEXA(tOff + 128, AREG(1));
  STAGEXB(tOff + 128, BREG(1));
  tOff += 256;
  VMCNT8();   // tile0 landed (tile1's 8 in flight)
  BARRIER();
  READFRAGSX(0, afA, bfA);
  LGKMCNT0();
  BARRIER();

  for (int t = 0; t <= NTT - 4; t += 2) {
    STAGEXA(tOff, AREG(0));
    STAGEXB(tOff, BREG(0));
    tOff += (((t + 2) & 15) == 15) ? (NN2 - (size_t)15 * 128) : (size_t)128;
    VMCNT8();
    BARRIER();
    READFRAGSX(1, afB, bfB);
    MFMAX(afA, bfA);
    LGKMCNT0();
    BARRIER();
    STAGEXA(tOff, AREG(1));
    STAGEXB(tOff, BREG(1));
    tOff += (((t + 3) & 15) == 15) ? (NN2 - (size_t)15 * 128) : (size_t)128;
    VMCNT8();
    BARRIER();
    READFRAGSX(0, afA, bfA);
    MFMAX(afB, bfB);
    LGKMCNT0();
    BARRIER();
  }
  VMCNT0();
  BARRIER();
  READFRAGSX(1, afB, bfB);
  MFMAX(afA, bfA);
  LGKMCNT0();
  MFMAX(afB, bfB);

  const float DS = 1.f / 16384.f;
  const int crow = (l >> 4) * 4;
  const int ccol = l & 15;
#pragma unroll
  for (int mi = 0; mi < 4; ++mi)
#pragma unroll
    for (int j = 0; j < 4; ++j) {
      int r0 = m0 + mi * 32 + wr * 16 + crow;
      int cc = n0 + j * 32 + wc * 16 + ccol;
#pragma unroll
      for (int r = 0; r < 4; ++r)
        Cp[(size_t)(r0 + r) * NNODE + cc] = (__bf16)(acc[mi][j][r] * DS);
    }
#undef STAGEXA
#undef STAGEXB
#undef RDFRAG
#undef READFRAGSX
#undef MFMAX
#undef AREG
#undef BREG
}

// ---------------------------------------------------------------------------
// fp8 stage GEMM (K=32 path, R14-verified) with fused transposed epilogue:
//   S_z[(b,n),c] = (1/2048) sum_v XT8[(b,c)][v] * M_z8[n][v]
__global__ __launch_bounds__(256, 3) void gemm_hop1s8(const unsigned char* __restrict__ XT8,
                                                      const unsigned char* __restrict__ M18,
                                                      const unsigned char* __restrict__ M28,
                                                      __bf16* __restrict__ S1,
                                                      __bf16* __restrict__ S2) {
  extern __shared__ char smem[];  // 32768 B
  const int tid = threadIdx.x;
  const int w = tid >> 6, l = tid & 63;
  const int wr = w >> 1, wc = w & 1;
  int lin = blockIdx.x + 16 * blockIdx.y + 256 * blockIdx.z;
  int nlin = (lin & 7) * 64 + (lin >> 3);
  const int m0 = (nlin & 15) * 128, n0 = ((nlin >> 4) & 15) * 128;
  const int z = nlin >> 8;
  const unsigned char* Bbase = z ? M28 : M18;
  const int NT = NNODE / 64;  // 32

#define AREG8(d) (smem + (d) * 8192)
#define BREG8(d) (smem + 16384 + (d) * 8192)

  FP8_GEOM();

#define STAGE8A(koff, region)                                                 \
  do {                                                                        \
    _Pragma("unroll")                                                         \
    for (int p = 0; p < 2; ++p)                                               \
      gload16((const char*)XT8 + (koff) + aLoff[p],                           \
              (region) + p * 4096 + w * 1024);                                \
  } while (0)
#define STAGE8B(koff, region)                                                 \
  do {                                                                        \
    _Pragma("unroll")                                                         \
    for (int p = 0; p < 2; ++p)                                               \
      gload16((const char*)Bbase + (koff) + bLoff[p],                         \
              (region) + p * 4096 + w * 1024);                                \
  } while (0)

  f32x4 acc[4][4] = {};
  long afA[4][2], bfA[4][2], afB[4][2], bfB[4][2];

  size_t kOff = 0;
  STAGE8A(kOff, AREG8(0));
  STAGE8B(kOff, BREG8(0));
  STAGE8A(kOff + 64, AREG8(1));
  STAGE8B(kOff + 64, BREG8(1));
  kOff += 128;
  VMCNT4();
  BARRIER();
  READFRAGS8(0, afA, bfA);
  LGKMCNT0();
  BARRIER();

  for (int t = 0; t <= NT - 4; t += 2) {
    STAGE8A(kOff, AREG8(0));
    STAGE8B(kOff, BREG8(0));
    kOff += 64;
    VMCNT4();
    BARRIER();
    READFRAGS8(1, afB, bfB);
    MFMA8(afA, bfA);
    LGKMCNT0();
    BARRIER();
    STAGE8A(kOff, AREG8(1));
    STAGE8B(kOff, BREG8(1));
    kOff += 64;
    VMCNT4();
    BARRIER();
    READFRAGS8(0, afA, bfA);
    MFMA8(afB, bfB);
    LGKMCNT0();
    BARRIER();
  }
  VMCNT0();
  BARRIER();
  READFRAGS8(1, afB, bfB);
  MFMA8(afA, bfA);
  LGKMCNT0();
  MFMA8(afB, bfB);

  // ---- epilogue: descale, LDS transpose T[n][m] (slot-XOR), coalesced write
  {
    __syncthreads();
    const float DS = 1.f / 2048.f;  // 1/(16*128)
    const int crow = (l >> 4) * 4;
    const int ccol = l & 15;
    char* T = smem;  // 128 x 256 B = 32768
#pragma unroll
    for (int mi = 0; mi < 4; ++mi)
#pragma unroll
      for (int j = 0; j < 4; ++j) {
        int ml = mi * 32 + wr * 16 + crow;
        int nl = j * 32 + wc * 16 + ccol;
        bf16x4 v;
#pragma unroll
        for (int r = 0; r < 4; ++r) v[r] = (__bf16)(acc[mi][j][r] * DS);
        *(bf16x4*)(T + nl * 256 + ((ml * 2) ^ ((nl & 7) << 4))) = v;
      }
    __syncthreads();
    __bf16* dst = z ? S2 : S1;
    const int bA = m0 >> 6;
#pragma unroll
    for (int it = 0; it < 4; ++it) {
      int nl = (tid >> 3) + it * 32;
      int seg = tid & 7;
      int xorv = (nl & 7) << 4;
      const char* src = T + nl * 256;
      bf16x8 v0 = *(const bf16x8*)(src + ((seg * 32) ^ xorv));
      bf16x8 v1 = *(const bf16x8*)(src + ((seg * 32 + 16) ^ xorv));
      int b = bA + (seg >> 2);
      size_t o = ((size_t)b * NNODE + n0 + nl) * 64 + (seg & 3) * 16;
      *(bf16x8*)(dst + o) = v0;
      *(bf16x8*)(dst + o + 8) = v1;
    }
  }
#undef STAGE8A
#undef STAGE8B
#undef AREG8
#undef BREG8
}

// ---------------------------------------------------------------------------
// M28[i] = fp8(128 * (M2a[i] + M2b[i])), bf16 partials in
__global__ __launch_bounds__(256) void combine_m2(const __bf16* __restrict__ M2p,
                                                  unsigned char* __restrict__ M28) {
  const size_t NN2 = (size_t)NNODE * NNODE;
  size_t i = ((size_t)blockIdx.x * 256 + threadIdx.x) * 8;
  bf16x8 a = *(const bf16x8*)(M2p + i);
  bf16x8 b = *(const bf16x8*)(M2p + NN2 + i);
  const float SA = 128.f;
  float sv[8];
#pragma unroll
  for (int k = 0; k < 8; ++k)
    sv[k] = ((float)a[k] + (float)b[k]) * SA;
  int w0 = __builtin_amdgcn_cvt_pk_fp8_f32(sv[0], sv[1], 0, false);
  w0 = __builtin_amdgcn_cvt_pk_fp8_f32(sv[2], sv[3], w0, true);
  int w1 = __builtin_amdgcn_cvt_pk_fp8_f32(sv[4], sv[5], 0, false);
  w1 = __builtin_amdgcn_cvt_pk_fp8_f32(sv[6], sv[7], w1, true);
  int2 pk; pk.x = w0; pk.y = w1;
  *(int2*)(M28 + i) = pk;
}

// ---------------------------------------------------------------------------
// Gate linear GEMM: [65536 x 192] @ Wt^T, K=192, N=128, fused epilogues.
// MODE 0: cols 0-63 -> z=sigmoid -> zbuf(f32); cols 64-127 -> r ->
//         rx=(bf16)(r*hid) row-major AND fp8(16*rx)^T -> XT8out.
// MODE 1: cols 0-63 -> c=tanh -> out=(1-z)*hid+z*c (f32)
template <int MODE>
__global__ __launch_bounds__(256) void gemm_lin(const __bf16* __restrict__ Xp,
                                                const __bf16* __restrict__ S1,
                                                const __bf16* __restrict__ S2,
                                                const __bf16* __restrict__ Wt,
                                                const float* __restrict__ b0,
                                                const float* __restrict__ b1,
                                                const float* __restrict__ wpre,
                                                const float* __restrict__ wadp,
                                                const float* __restrict__ hid,
                                                float* __restrict__ zbuf,
                                                __bf16* __restrict__ rxout,
                                                unsigned char* __restrict__ XT8out,
                                                float* __restrict__ outp) {
  __shared__ __bf16 As[128 * 32];
  __shared__ __bf16 Bs[128 * 32];
  __shared__ char T[64 * 256];  // rx transpose staging (MODE 0)
  const int tid = threadIdx.x;
  const int wave = tid >> 6, lane = tid & 63;
  const int wr = wave >> 1, wc = wave & 1;
  const int m0 = blockIdx.x * 128;
  const int rowA = tid >> 2;
  const int colb = (tid & 3) * 16;
  const __bf16* srcs[3] = {Xp, S1, S2};
  char* asD0 = (char*)As + wave * 1024;
  char* asD1 = (char*)As + 4096 + wave * 1024;
  char* bsD0 = (char*)Bs + wave * 1024;
  char* bsD1 = (char*)Bs + 4096 + wave * 1024;

  f32x4 acc[4][4] = {};

#pragma unroll
  for (int kt = 0; kt < 6; ++kt) {
    const __bf16* Ab = srcs[kt >> 1];
    const char* aS0 = (const char*)(Ab + (size_t)(m0 + rowA) * 64) + (kt & 1) * 64 + colb;
    const char* aS1 = (const char*)(Ab + (size_t)(m0 + rowA + 64) * 64) + (kt & 1) * 64 + colb;
    const char* bS0 = (const char*)(Wt + (size_t)rowA * 192) + kt * 64 + colb;
    const char* bS1 = (const char*)(Wt + (size_t)(rowA + 64) * 192) + kt * 64 + colb;
    gload16(aS0, asD0);
    gload16(aS1, asD1);
    gload16(bS0, bsD0);
    gload16(bS1, bsD1);
    __syncthreads();
    bf16x8 af[4], bfr[4];
#pragma unroll
    for (int mi = 0; mi < 4; ++mi)
      af[mi] = *(const bf16x8*)((const char*)As +
               ((wr * 64 + mi * 16 + (lane & 15)) * 64 + (lane >> 4) * 16));
#pragma unroll
    for (int ni = 0; ni < 4; ++ni)
      bfr[ni] = *(const bf16x8*)((const char*)Bs +
               ((wc * 64 + ni * 16 + (lane & 15)) * 64 + (lane >> 4) * 16));
#pragma unroll
    for (int mi = 0; mi < 4; ++mi)
#pragma unroll
      for (int ni = 0; ni < 4; ++ni)
        acc[mi][ni] = __builtin_amdgcn_mfma_f32_16x16x32_bf16(af[mi], bfr[ni],
                                                              acc[mi][ni], 0, 0, 0);
    __syncthreads();
  }

  const float wp = *wpre, wa = *wadp;
  const float s = 2.f * wp + wa;
  const int crow = (lane >> 4) * 4;
  const int ccol = lane & 15;
#pragma unroll
  for (int mi = 0; mi < 4; ++mi)
#pragma unroll
    for (int ni = 0; ni < 4; ++ni) {
      int r0 = m0 + wr * 64 + mi * 16 + crow;
      int col = wc * 64 + ni * 16 + ccol;
      int cf = col & 63;
      if (MODE == 0) {
        if (col < 64) {
#pragma unroll
          for (int r = 0; r < 4; ++r) {
            int row = r0 + r;
            float g = acc[mi][ni][r] + s * b0[cf];
            zbuf[(size_t)row * 64 + cf] = 1.f / (1.f + __expf(-g));
          }
        } else {
          bf16x4 tv;
#pragma unroll
          for (int r = 0; r < 4; ++r) {
            int row = r0 + r;
            float g = acc[mi][ni][r] + s * b1[cf];
            float rv = 1.f / (1.f + __expf(-g));
            __bf16 rxv = (__bf16)(rv * hid[(size_t)row * 64 + cf]);
            rxout[(size_t)row * 64 + cf] = rxv;
            tv[r] = rxv;
          }
          int vl0 = wr * 64 + mi * 16 + crow;
          *(bf16x4*)(T + cf * 256 + ((vl0 * 2) ^ ((cf & 7) << 4))) = tv;
        }
      } else {
        if (col < 64) {
#pragma unroll
          for (int r = 0; r < 4; ++r) {
            int row = r0 + r;
            float g = acc[mi][ni][r] + s * b0[cf];
            float cv = 1.f - 2.f / (1.f + __expf(2.f * g));
            float zv = zbuf[(size_t)row * 64 + cf];
            float hv = hid[(size_t)row * 64 + cf];
            outp[(size_t)row * 64 + cf] = (1.f - zv) * hv + zv * cv;
          }
        }
      }
    }

  if (MODE == 0) {
    __syncthreads();
    const int b = m0 >> 11;
    const int v0 = m0 & 2047;
    const float SX = 16.f;
#pragma unroll
    for (int it = 0; it < 4; ++it) {
      int rr = it * 16 + (tid >> 4);
      int seg = tid & 15;
      bf16x8 v = *(const bf16x8*)(T + rr * 256 + ((seg * 16) ^ ((rr & 7) << 4)));
      int w0 = __builtin_amdgcn_cvt_pk_fp8_f32((float)v[0] * SX, (float)v[1] * SX, 0, false);
      w0 = __builtin_amdgcn_cvt_pk_fp8_f32((float)v[2] * SX, (float)v[3] * SX, w0, true);
      int w1 = __builtin_amdgcn_cvt_pk_fp8_f32((float)v[4] * SX, (float)v[5] * SX, 0, false);
      w1 = __builtin_amdgcn_cvt_pk_fp8_f32((float)v[6] * SX, (float)v[7] * SX, w1, true);
      int2 pk; pk.x = w0; pk.y = w1;
      *(int2*)(XT8out + ((size_t)(b * 64 + rr)) * NNODE + v0 + seg * 8) = pk;
    }
  }
}

// ---------------------------------------------------------------------------
extern "C" void kernel_launch(void* const* d_in, const int* in_sizes, int n_in,
                              void* d_out, int out_size, void* d_ws, size_t ws_size,
                              hipStream_t stream) {
  (void)in_sizes; (void)n_in; (void)out_size;
  const float* x    = (const float*)d_in[0];
  const float* A1   = (const float*)d_in[1];
  const float* A2   = (const float*)d_in[2];
  const float* E1   = (const float*)d_in[3];
  const float* E2   = (const float*)d_in[4];
  const float* Wz   = (const float*)d_in[5];
  const float* bz   = (const float*)d_in[6];
  const float* Wr   = (const float*)d_in[7];
  const float* br   = (const float*)d_in[8];
  const float* Wc   = (const float*)d_in[9];
  const float* bc   = (const float*)d_in[10];
  const float* wpre = (const float*)d_in[11];
  const float* wadp = (const float*)d_in[12];
  float* out = (float*)d_out;

  char* ws = (char*)d_ws;
  const size_t NN2 = (size_t)NNODE * NNODE;  // 4,194,304
  const size_t NN2B = NN2 * 2;               // bytes per bf16 slice
  unsigned char* ADJ8  = (unsigned char*)(ws + 6 * NN2B);           // 6 fp8
  unsigned char* ADJT8 = (unsigned char*)(ws + 6 * NN2B + 6 * NN2); // 6 fp8
  __bf16* SC   = (__bf16*)(ws + 12 * NN2B);     // scores (4 slices), then:
  __bf16* M2p  = (__bf16*)(ws + 12 * NN2B);     // bf16 partials x2 = [12,14)
  unsigned char* M18 = (unsigned char*)(ws + 18 * NN2B);        // fp8
  unsigned char* M28 = (unsigned char*)(ws + 18 * NN2B + NN2);  // fp8
  unsigned char* XT8 = (unsigned char*)(ws + 20 * NN2B);        // fp8
  __bf16* xbf  = (__bf16*)(ws + 21 * NN2B);
  __bf16* rx   = (__bf16*)(ws + 22 * NN2B);
  __bf16* S1   = (__bf16*)(ws + 2 * NN2B);
  __bf16* S2   = (__bf16*)(ws + 3 * NN2B);
  float*  zbuf = (float*)(ws + 4 * NN2B);
  __bf16* E1p  = (__bf16*)(ws + 23 * NN2B);
  __bf16* E2p  = E1p + 4 * NNODE * 32;
  __bf16* Wzrt = E2p + 4 * NNODE * 32;
  __bf16* Wct  = Wzrt + 128 * 192;
  if (ws_size < 23 * NN2B + 2 * 4 * NNODE * 32 * 2 + 2 * 128 * 192 * 2) return;

  // --- adjacency construction (fused)
  prep_ew<<<224, 256, 0, stream>>>(E1, E2, Wz, Wr, Wc, wpre, wadp,
                                   E1p, E2p, Wzrt, Wct);
  score_gemm<<<dim3(16, 16, 4), 256, 0, stream>>>(E1p, E2p, SC);
  soft_tx<<<3072, 256, 0, stream>>>(SC, ADJ8, x, XT8, xbf);
  prep_adj<<<dim3(32, 32), 256, 0, stream>>>(A1, A2, ADJ8, ADJT8, M18,
                                             wpre, wadp);

  // --- M2 = sum_z w_z A_z^2 (MX fp8 K=128; 512 blocks = 2/CU full machine)
  gemm_sq<<<dim3(16, 16, 2), 256, 65536, stream>>>(ADJ8, ADJT8, M2p);
  combine_m2<<<2048, 256, 0, stream>>>(M2p, M28);

  // --- stage 1: S1 = M1 x, S2 = M2 x (fp8, fused transposed epilogue)
  gemm_hop1s8<<<dim3(16, 16, 2), 256, 32768, stream>>>(XT8, M18, M28, S1, S2);
  gemm_lin<0><<<512, 256, 0, stream>>>(xbf, S1, S2, Wzrt, bz, br, wpre, wadp,
                                       x, zbuf, rx, XT8, nullptr);

  // --- stage 2: hops on r*x (XT8 holds fp8(16*rx)^T from gemm_lin<0>)
  gemm_hop1s8<<<dim3(16, 16, 2), 256, 32768, stream>>>(XT8, M18, M28, S1, S2);
  gemm_lin<1><<<512, 256, 0, stream>>>(rx, S1, S2, Wct, bc, nullptr, wpre, wadp,
                                       x, zbuf, nullptr, nullptr, out);
}

// Round 18
// 163.657 us; speedup vs baseline: 1.3096x; 1.0837x over previous
//
#include <hip/hip_runtime.h>

#define NNODE 2048
#define NBATCH 32

typedef __attribute__((ext_vector_type(4))) float f32x4;
typedef __attribute__((ext_vector_type(8))) __bf16 bf16x8;
typedef __attribute__((ext_vector_type(4))) __bf16 bf16x4;
typedef __attribute__((ext_vector_type(4))) int i32x4;
typedef __attribute__((ext_vector_type(8))) int i32x8;

__device__ __forceinline__ void gload16(const void* g, void* lds) {
  __builtin_amdgcn_global_load_lds(
      (const __attribute__((address_space(1))) unsigned int*)g,
      (__attribute__((address_space(3))) unsigned int*)lds, 16, 0, 0);
}

// ---------------------------------------------------------------------------
// Merged: prep_e (blocks 0..127) + prep_w (blocks 128..223)
__global__ __launch_bounds__(256) void prep_ew(const float* __restrict__ E1,
                                               const float* __restrict__ E2,
                                               const float* __restrict__ Wz,
                                               const float* __restrict__ Wr,
                                               const float* __restrict__ Wc,
                                               const float* __restrict__ wpre,
                                               const float* __restrict__ wadp,
                                               __bf16* __restrict__ E1p,
                                               __bf16* __restrict__ E2p,
                                               __bf16* __restrict__ Wzrt,
                                               __bf16* __restrict__ Wct) {
  if (blockIdx.x < 128) {
    int idx = blockIdx.x * 256 + threadIdx.x;  // 0..32767
    int cq = idx & 3;
    int n = (idx >> 2) & 2047;
    int h = idx >> 13;
    const float4 q1 = *(const float4*)(E1 + (size_t)(n * 4 + h) * 16 + cq * 4);
    const float4 q2 = *(const float4*)(E2 + (size_t)(n * 4 + h) * 16 + cq * 4);
    size_t o = ((size_t)h * NNODE + n) * 32 + cq * 4;
    E1p[o + 0] = (__bf16)q1.x; E1p[o + 1] = (__bf16)q1.y;
    E1p[o + 2] = (__bf16)q1.z; E1p[o + 3] = (__bf16)q1.w;
    E2p[o + 0] = (__bf16)q2.x; E2p[o + 1] = (__bf16)q2.y;
    E2p[o + 2] = (__bf16)q2.z; E2p[o + 3] = (__bf16)q2.w;
    size_t oz = o + 16;
    E1p[oz + 0] = (__bf16)0.f; E1p[oz + 1] = (__bf16)0.f;
    E1p[oz + 2] = (__bf16)0.f; E1p[oz + 3] = (__bf16)0.f;
    E2p[oz + 0] = (__bf16)0.f; E2p[oz + 1] = (__bf16)0.f;
    E2p[oz + 2] = (__bf16)0.f; E2p[oz + 3] = (__bf16)0.f;
  } else {
    int idx = (blockIdx.x - 128) * 256 + threadIdx.x;  // 0 .. 128*192-1
    int rr = idx / 192, k = idx % 192;
    float s = 2.f * (*wpre) + (*wadp);
    float sc = (k < 64) ? s : 1.f;
    float vz = (rr < 64) ? Wz[(size_t)k * 64 + rr] : Wr[(size_t)k * 64 + rr - 64];
    Wzrt[idx] = (__bf16)(vz * sc);
    float vc = (rr < 64) ? Wc[(size_t)k * 64 + rr] * sc : 0.f;
    Wct[idx] = (__bf16)vc;
  }
}

// ---------------------------------------------------------------------------
// SC[h][w][v] = relu(E1p_h @ E2p_h^T)/4, bf16. Single K=32 MFMA step.
__global__ __launch_bounds__(256) void score_gemm(const __bf16* __restrict__ E1p,
                                                  const __bf16* __restrict__ E2p,
                                                  __bf16* __restrict__ SC) {
  __shared__ __bf16 As[128 * 32];
  __shared__ __bf16 Bs[128 * 32];
  const int tid = threadIdx.x;
  const int wave = tid >> 6, lane = tid & 63;
  const int wr = wave >> 1, wc = wave & 1;
  const int h = blockIdx.z;
  const int m0 = blockIdx.x * 128, n0 = blockIdx.y * 128;
  const __bf16* A = E1p + (size_t)h * NNODE * 32;
  const __bf16* Bt = E2p + (size_t)h * NNODE * 32;
  const int rowA = tid >> 2;
  const int colb = (tid & 3) * 16;
  gload16((const char*)(A + (size_t)(m0 + rowA) * 32) + colb, (char*)As + wave * 1024);
  gload16((const char*)(A + (size_t)(m0 + rowA + 64) * 32) + colb, (char*)As + 4096 + wave * 1024);
  gload16((const char*)(Bt + (size_t)(n0 + rowA) * 32) + colb, (char*)Bs + wave * 1024);
  gload16((const char*)(Bt + (size_t)(n0 + rowA + 64) * 32) + colb, (char*)Bs + 4096 + wave * 1024);
  __syncthreads();

  f32x4 acc[4][4] = {};
  bf16x8 af[4], bfr[4];
#pragma unroll
  for (int mi = 0; mi < 4; ++mi)
    af[mi] = *(const bf16x8*)((const char*)As +
             ((wr * 64 + mi * 16 + (lane & 15)) * 64 + (lane >> 4) * 16));
#pragma unroll
  for (int ni = 0; ni < 4; ++ni)
    bfr[ni] = *(const bf16x8*)((const char*)Bs +
             ((wc * 64 + ni * 16 + (lane & 15)) * 64 + (lane >> 4) * 16));
#pragma unroll
  for (int mi = 0; mi < 4; ++mi)
#pragma unroll
    for (int ni = 0; ni < 4; ++ni)
      acc[mi][ni] = __builtin_amdgcn_mfma_f32_16x16x32_bf16(af[mi], bfr[ni],
                                                            acc[mi][ni], 0, 0, 0);

  const int crow = (lane >> 4) * 4;
  const int ccol = lane & 15;
#pragma unroll
  for (int mi = 0; mi < 4; ++mi)
#pragma unroll
    for (int ni = 0; ni < 4; ++ni) {
      int r0 = m0 + wr * 64 + mi * 16 + crow;
      int cc = n0 + wc * 64 + ni * 16 + ccol;
#pragma unroll
      for (int r = 0; r < 4; ++r) {
        float val = fmaxf(acc[mi][ni][r], 0.f) * 0.25f;
        SC[((size_t)h * NNODE + r0 + r) * NNODE + cc] = (__bf16)val;
      }
    }
}

// ---------------------------------------------------------------------------
// Merged: blocks 0..2047 -> row softmax (SC -> fp8 ADJ8 slices 2..5 directly,
// scaled x128); blocks 2048..3071 -> transpose_x: x f32 -> XT8 fp8(16x) and
// xbf bf16 [B*N,64].
__global__ __launch_bounds__(256) void soft_tx(const __bf16* __restrict__ SC,
                                               unsigned char* __restrict__ ADJ8,
                                               const float* __restrict__ x,
                                               unsigned char* __restrict__ XT8,
                                               __bf16* __restrict__ xbf) {
  const int tid = threadIdx.x;
  const size_t NN2 = (size_t)NNODE * NNODE;
  if (blockIdx.x < 2048) {
    const int wave = tid >> 6, lane = tid & 63;
    const size_t row = (size_t)blockIdx.x * 4 + wave;
    const __bf16* src = SC + row * NNODE;
    unsigned char* dst = ADJ8 + 2 * NN2 + row * NNODE;  // slices 2..5
    float v[32];
    float mx = 0.f;
#pragma unroll
    for (int j = 0; j < 4; ++j) {
      bf16x8 q = *(const bf16x8*)(src + j * 512 + lane * 8);
#pragma unroll
      for (int i = 0; i < 8; ++i) {
        float f = (float)q[i];
        v[j * 8 + i] = f;
        mx = fmaxf(mx, f);
      }
    }
#pragma unroll
    for (int o = 32; o > 0; o >>= 1) mx = fmaxf(mx, __shfl_xor(mx, o));
    float s = 0.f;
#pragma unroll
    for (int i = 0; i < 32; ++i) {
      v[i] = __expf(v[i] - mx);
      s += v[i];
    }
#pragma unroll
    for (int o = 32; o > 0; o >>= 1) s += __shfl_xor(s, o);
    float inv = 128.f / s;  // x128 fp8 scale folded in
#pragma unroll
    for (int j = 0; j < 4; ++j) {
      int w0 = __builtin_amdgcn_cvt_pk_fp8_f32(v[j * 8 + 0] * inv, v[j * 8 + 1] * inv, 0, false);
      w0 = __builtin_amdgcn_cvt_pk_fp8_f32(v[j * 8 + 2] * inv, v[j * 8 + 3] * inv, w0, true);
      int w1 = __builtin_amdgcn_cvt_pk_fp8_f32(v[j * 8 + 4] * inv, v[j * 8 + 5] * inv, 0, false);
      w1 = __builtin_amdgcn_cvt_pk_fp8_f32(v[j * 8 + 6] * inv, v[j * 8 + 7] * inv, w1, true);
      int2 pk; pk.x = w0; pk.y = w1;
      *(int2*)(dst + j * 512 + lane * 8) = pk;
    }
  } else {
    const int idx = blockIdx.x - 2048;
    const int b = idx >> 5, v0 = (idx & 31) * 64;
    __shared__ float t[64][65];
    const int vr = tid >> 2, c0 = (tid & 3) * 16;
    const float* src = x + ((size_t)b * NNODE + v0 + vr) * 64 + c0;
    __bf16* xb = xbf + ((size_t)b * NNODE + v0 + vr) * 64 + c0;
#pragma unroll
    for (int j = 0; j < 4; ++j) {
      float4 q = ((const float4*)src)[j];
      t[vr][c0 + j * 4 + 0] = q.x;
      t[vr][c0 + j * 4 + 1] = q.y;
      t[vr][c0 + j * 4 + 2] = q.z;
      t[vr][c0 + j * 4 + 3] = q.w;
      xb[j * 4 + 0] = (__bf16)q.x;
      xb[j * 4 + 1] = (__bf16)q.y;
      xb[j * 4 + 2] = (__bf16)q.z;
      xb[j * 4 + 3] = (__bf16)q.w;
    }
    __syncthreads();
    const float SX = 16.f;
#pragma unroll
    for (int jr = 0; jr < 4; ++jr) {
      int c = jr * 16 + (tid >> 4);
      int vq = (tid & 15) * 4;
      int w0 = __builtin_amdgcn_cvt_pk_fp8_f32(t[vq][c] * SX, t[vq + 1][c] * SX, 0, false);
      w0 = __builtin_amdgcn_cvt_pk_fp8_f32(t[vq + 2][c] * SX, t[vq + 3][c] * SX, w0, true);
      *(int*)(XT8 + ((size_t)(b * 64 + c)) * NNODE + v0 + vq) = w0;
    }
  }
}

// ---------------------------------------------------------------------------
// Fused adjacency prep (x128 domain): z<2 reads A1/A2 f32, writes ADJ8;
// z>=2 reads fp8 ADJ8 (written by soft_tx). All z: ADJT8 = fp8(wz * v128),
// M18 = fp8(sum wz * v128).
__global__ __launch_bounds__(256) void prep_adj(const float* __restrict__ A1,
                                                const float* __restrict__ A2,
                                                unsigned char* __restrict__ ADJ8,
                                                unsigned char* __restrict__ ADJT8,
                                                unsigned char* __restrict__ M18,
                                                const float* __restrict__ wpre,
                                                const float* __restrict__ wadp) {
  const int r0 = blockIdx.x * 64, c0 = blockIdx.y * 64;
  const int tid = threadIdx.x;
  const size_t NN2 = (size_t)NNODE * NNODE;
  const float wp = *wpre, wa = *wadp * 0.25f;
  const float SA = 128.f;
  __shared__ float t[64][65];
  const int vr = tid >> 2, cg = (tid & 3) * 16;
  float m1acc[16] = {};

  for (int z = 0; z < 6; ++z) {
    const float wz = (z < 2) ? wp : wa;
    float vv[16];  // values in x128 domain
    if (z < 2) {
      const float* src = (z == 0 ? A1 : A2) + (size_t)(r0 + vr) * NNODE + c0 + cg;
#pragma unroll
      for (int j = 0; j < 4; ++j) {
        float4 q = ((const float4*)src)[j];
        vv[j * 4 + 0] = q.x * SA; vv[j * 4 + 1] = q.y * SA;
        vv[j * 4 + 2] = q.z * SA; vv[j * 4 + 3] = q.w * SA;
      }
      int4 pk;
#pragma unroll
      for (int q = 0; q < 4; ++q) {
        int w0 = __builtin_amdgcn_cvt_pk_fp8_f32(vv[4 * q], vv[4 * q + 1], 0, false);
        w0 = __builtin_amdgcn_cvt_pk_fp8_f32(vv[4 * q + 2], vv[4 * q + 3], w0, true);
        (&pk.x)[q] = w0;
      }
      *(int4*)(ADJ8 + (size_t)z * NN2 + (size_t)(r0 + vr) * NNODE + c0 + cg) = pk;
    } else {
      int4 pk = *(const int4*)(ADJ8 + (size_t)z * NN2 + (size_t)(r0 + vr) * NNODE + c0 + cg);
#pragma unroll
      for (int q = 0; q < 4; ++q) {
        int w0 = (&pk.x)[q];
        vv[4 * q + 0] = __builtin_amdgcn_cvt_f32_fp8(w0, 0);
        vv[4 * q + 1] = __builtin_amdgcn_cvt_f32_fp8(w0, 1);
        vv[4 * q + 2] = __builtin_amdgcn_cvt_f32_fp8(w0, 2);
        vv[4 * q + 3] = __builtin_amdgcn_cvt_f32_fp8(w0, 3);
      }
    }
#pragma unroll
    for (int i = 0; i < 16; ++i) {
      m1acc[i] += wz * vv[i];
      t[vr][cg + i] = vv[i];
    }
    __syncthreads();
    {
#pragma unroll
      for (int jr = 0; jr < 4; ++jr) {
        int c = jr * 16 + (tid >> 4);
        int vq = (tid & 15) * 4;
        int w0 = __builtin_amdgcn_cvt_pk_fp8_f32(t[vq][c] * wz, t[vq + 1][c] * wz, 0, false);
        w0 = __builtin_amdgcn_cvt_pk_fp8_f32(t[vq + 2][c] * wz, t[vq + 3][c] * wz, w0, true);
        *(int*)(ADJT8 + (size_t)z * NN2 + (size_t)(c0 + c) * NNODE + r0 + vq) = w0;
      }
    }
    __syncthreads();
  }
  {
    int4 pk;
#pragma unroll
    for (int q = 0; q < 4; ++q) {
      int w0 = __builtin_amdgcn_cvt_pk_fp8_f32(m1acc[4 * q], m1acc[4 * q + 1], 0, false);
      w0 = __builtin_amdgcn_cvt_pk_fp8_f32(m1acc[4 * q + 2], m1acc[4 * q + 3], w0, true);
      (&pk.x)[q] = w0;
    }
    *(int4*)(M18 + (size_t)(r0 + vr) * NNODE + c0 + cg) = pk;
  }
}

// ---------------------------------------------------------------------------
#define VMCNT0() asm volatile("s_waitcnt vmcnt(0)" ::: "memory")
#define VMCNT8() asm volatile("s_waitcnt vmcnt(8)" ::: "memory")
#define LGKMCNT0() asm volatile("s_waitcnt lgkmcnt(0)" ::: "memory")
#define BARRIER() asm volatile("s_barrier" ::: "memory")

// ---------------------------------------------------------------------------
// Shared MX K=128 fp8 GEMM machinery (R17-verified): 128x128 tile, BK=128,
// 16 KiB regions ([128 rows][128 B], 3-bit XOR swizzle), LDS 64 KiB ->
// 2 blocks/CU, R11 register-pipelined schedule with vmcnt(8), scales = 1.0.
#define MX_GEOM()                                                             \
  int aoff[4][2], boff[4][2];                                                 \
  _Pragma("unroll")                                                           \
  for (int mi = 0; mi < 4; ++mi)                                              \
    _Pragma("unroll")                                                         \
    for (int part = 0; part < 2; ++part) {                                    \
      int rh = mi * 32 + wr * 16 + (l & 15);                                  \
      int lo = rh * 128 + (l >> 4) * 32 + part * 16;                          \
      aoff[mi][part] = lo ^ ((rh & 7) << 4);                                  \
    }                                                                         \
  _Pragma("unroll")                                                           \
  for (int j = 0; j < 4; ++j)                                                 \
    _Pragma("unroll")                                                         \
    for (int part = 0; part < 2; ++part) {                                    \
      int rh = j * 32 + wc * 16 + (l & 15);                                   \
      int lo = rh * 128 + (l >> 4) * 32 + part * 16;                          \
      boff[j][part] = lo ^ ((rh & 7) << 4);                                   \
    }                                                                         \
  const int sg_row = w * 8 + (l >> 3);                                        \
  const int sg_col = (((l & 7) ^ ((l >> 3) & 7)) << 4);                       \
  unsigned aLoff[4], bLoff[4];                                                \
  _Pragma("unroll")                                                           \
  for (int p = 0; p < 4; ++p) {                                               \
    aLoff[p] = (unsigned)((m0 + p * 32 + sg_row) * 2048 + sg_col);            \
    bLoff[p] = (unsigned)((n0 + p * 32 + sg_row) * 2048 + sg_col);            \
  }

#define RDFRAG(region, o0, o1)                                                \
  __builtin_shufflevector(*(const i32x4*)((region) + (o0)),                   \
                          *(const i32x4*)((region) + (o1)),                   \
                          0, 1, 2, 3, 4, 5, 6, 7)

#define READFRAGSX(d, AF, BF)                                                 \
  do {                                                                        \
    _Pragma("unroll")                                                         \
    for (int mi = 0; mi < 4; ++mi)                                            \
      AF[mi] = RDFRAG(AREG(d), aoff[mi][0], aoff[mi][1]);                     \
    _Pragma("unroll")                                                         \
    for (int j = 0; j < 4; ++j)                                               \
      BF[j] = RDFRAG(BREG(d), boff[j][0], boff[j][1]);                        \
  } while (0)

#define MFMAX(AF, BF)                                                         \
  do {                                                                        \
    __builtin_amdgcn_s_setprio(1);                                            \
    _Pragma("unroll")                                                         \
    for (int mi = 0; mi < 4; ++mi)                                            \
      _Pragma("unroll")                                                       \
      for (int j = 0; j < 4; ++j)                                             \
        acc[mi][j] = __builtin_amdgcn_mfma_scale_f32_16x16x128_f8f6f4(        \
            AF[mi], BF[j], acc[mi][j], 0, 0, 0, 0x7F7F7F7F, 0, 0x7F7F7F7F);   \
    __builtin_amdgcn_s_setprio(0);                                            \
  } while (0)

// ---------------------------------------------------------------------------
// Fused-squares (MX K=128): M2part[zh] = (1/16384) sum_{z in half} ADJ8_z @
// ADJT8_z^T. 512 blocks = 2/CU; bf16 partials x2.
__global__ __launch_bounds__(256, 2) void gemm_sq(const unsigned char* __restrict__ ADJ8,
                                                  const unsigned char* __restrict__ ADJT8,
                                                  __bf16* __restrict__ M2part) {
  extern __shared__ char smem[];  // 65536 B
  const int tid = threadIdx.x;
  const int w = tid >> 6, l = tid & 63;
  const int wr = w >> 1, wc = w & 1;
  const size_t NN2 = (size_t)NNODE * NNODE;
  int lin = blockIdx.x + 16 * blockIdx.y + 256 * blockIdx.z;  // [0,512)
  int nlin = (lin & 7) * 64 + (lin >> 3);
  const int m0 = (nlin & 15) * 128, n0 = ((nlin >> 4) & 15) * 128;
  const int zh = nlin >> 8;      // [0,2)
  const int zb = zh * 3;
  __bf16* Cp = M2part + (size_t)zh * NN2;
  const int NTT = 48;            // 3 z * 16 K-tiles (BK=128)

#define AREG(d) (smem + (d) * 16384)
#define BREG(d) (smem + 32768 + (d) * 16384)

  MX_GEOM();

#define STAGEXA(toff, region)                                                 \
  do {                                                                        \
    _Pragma("unroll")                                                         \
    for (int p = 0; p < 4; ++p)                                               \
      gload16((const char*)ADJ8 + (toff) + aLoff[p],                          \
              (region) + p * 4096 + w * 1024);                                \
  } while (0)
#define STAGEXB(toff, region)                                                 \
  do {                                                                        \
    _Pragma("unroll")                                                         \
    for (int p = 0; p < 4; ++p)                                               \
      gload16((const char*)ADJT8 + (toff) + bLoff[p],                         \
              (region) + p * 4096 + w * 1024);                                \
  } while (0)

  f32x4 acc[4][4] = {};
  i32x8 afA[4], bfA[4], afB[4], bfB[4];

  size_t tOff = (size_t)zb * NN2;
  STAGEXA(tOff, AREG(0));
  STAGEXB(tOff, BREG(0));
  STAGEXA(tOff + 128, AREG(1));
  STAGEXB(tOff + 128, BREG(1));
  tOff += 256;
  VMCNT8();   // tile0 landed (tile1's 8 in flight)
  BARRIER();
  READFRAGSX(0, afA, bfA);
  LGKMCNT0();
  BARRIER();

  for (int t = 0; t <= NTT - 4; t += 2) {
    STAGEXA(tOff, AREG(0));
    STAGEXB(tOff, BREG(0));
    tOff += (((t + 2) & 15) == 15) ? (NN2 - (size_t)15 * 128) : (size_t)128;
    VMCNT8();
    BARRIER();
    READFRAGSX(1, afB, bfB);
    MFMAX(afA, bfA);
    LGKMCNT0();
    BARRIER();
    STAGEXA(tOff, AREG(1));
    STAGEXB(tOff, BREG(1));
    tOff += (((t + 3) & 15) == 15) ? (NN2 - (size_t)15 * 128) : (size_t)128;
    VMCNT8();
    BARRIER();
    READFRAGSX(0, afA, bfA);
    MFMAX(afB, bfB);
    LGKMCNT0();
    BARRIER();
  }
  VMCNT0();
  BARRIER();
  READFRAGSX(1, afB, bfB);
  MFMAX(afA, bfA);
  LGKMCNT0();
  MFMAX(afB, bfB);

  const float DS = 1.f / 16384.f;
  const int crow = (l >> 4) * 4;
  const int ccol = l & 15;
#pragma unroll
  for (int mi = 0; mi < 4; ++mi)
#pragma unroll
    for (int j = 0; j < 4; ++j) {
      int r0 = m0 + mi * 32 + wr * 16 + crow;
      int cc = n0 + j * 32 + wc * 16 + ccol;
#pragma unroll
      for (int r = 0; r < 4; ++r)
        Cp[(size_t)(r0 + r) * NNODE + cc] = (__bf16)(acc[mi][j][r] * DS);
    }
#undef STAGEXA
#undef STAGEXB
#undef AREG
#undef BREG
}

// ---------------------------------------------------------------------------
// Stage GEMM (MX K=128, R17-verified machinery) with fused transposed
// epilogue: S_z[(b,n),c] = (1/2048) sum_v XT8[(b,c)][v] * M_z8[n][v].
__global__ __launch_bounds__(256, 2) void gemm_hop1sx(const unsigned char* __restrict__ XT8,
                                                      const unsigned char* __restrict__ M18,
                                                      const unsigned char* __restrict__ M28,
                                                      __bf16* __restrict__ S1,
                                                      __bf16* __restrict__ S2) {
  extern __shared__ char smem[];  // 65536 B
  const int tid = threadIdx.x;
  const int w = tid >> 6, l = tid & 63;
  const int wr = w >> 1, wc = w & 1;
  int lin = blockIdx.x + 16 * blockIdx.y + 256 * blockIdx.z;  // [0,512)
  int nlin = (lin & 7) * 64 + (lin >> 3);
  const int m0 = (nlin & 15) * 128, n0 = ((nlin >> 4) & 15) * 128;
  const int z = nlin >> 8;
  const unsigned char* Bbase = z ? M28 : M18;
  const int NT = NNODE / 128;  // 16 K-tiles

#define AREG(d) (smem + (d) * 16384)
#define BREG(d) (smem + 32768 + (d) * 16384)

  MX_GEOM();

#define STAGEXA(koff, region)                                                 \
  do {                                                                        \
    _Pragma("unroll")                                                         \
    for (int p = 0; p < 4; ++p)                                               \
      gload16((const char*)XT8 + (koff) + aLoff[p],                           \
              (region) + p * 4096 + w * 1024);                                \
  } while (0)
#define STAGEXB(koff, region)                                                 \
  do {                                                                        \
    _Pragma("unroll")                                                         \
    for (int p = 0; p < 4; ++p)                                               \
      gload16((const char*)Bbase + (koff) + bLoff[p],                         \
              (region) + p * 4096 + w * 1024);                                \
  } while (0)

  f32x4 acc[4][4] = {};
  i32x8 afA[4], bfA[4], afB[4], bfB[4];

  size_t kOff = 0;
  STAGEXA(kOff, AREG(0));
  STAGEXB(kOff, BREG(0));
  STAGEXA(kOff + 128, AREG(1));
  STAGEXB(kOff + 128, BREG(1));
  kOff += 256;
  VMCNT8();
  BARRIER();
  READFRAGSX(0, afA, bfA);
  LGKMCNT0();
  BARRIER();

  for (int t = 0; t <= NT - 4; t += 2) {
    STAGEXA(kOff, AREG(0));
    STAGEXB(kOff, BREG(0));
    kOff += 128;
    VMCNT8();
    BARRIER();
    READFRAGSX(1, afB, bfB);
    MFMAX(afA, bfA);
    LGKMCNT0();
    BARRIER();
    STAGEXA(kOff, AREG(1));
    STAGEXB(kOff, BREG(1));
    kOff += 128;
    VMCNT8();
    BARRIER();
    READFRAGSX(0, afA, bfA);
    MFMAX(afB, bfB);
    LGKMCNT0();
    BARRIER();
  }
  VMCNT0();
  BARRIER();
  READFRAGSX(1, afB, bfB);
  MFMAX(afA, bfA);
  LGKMCNT0();
  MFMAX(afB, bfB);

  // ---- epilogue (R14-verified): descale, LDS transpose T[n][m] (slot-XOR),
  // coalesced write S_z[(b, n0+n)*64 + c].
  {
    __syncthreads();
    const float DS = 1.f / 2048.f;  // 1/(16*128)
    const int crow = (l >> 4) * 4;
    const int ccol = l & 15;
    char* T = smem;  // 128 x 256 B = 32768
#pragma unroll
    for (int mi = 0; mi < 4; ++mi)
#pragma unroll
      for (int j = 0; j < 4; ++j) {
        int ml = mi * 32 + wr * 16 + crow;
        int nl = j * 32 + wc * 16 + ccol;
        bf16x4 v;
#pragma unroll
        for (int r = 0; r < 4; ++r) v[r] = (__bf16)(acc[mi][j][r] * DS);
        *(bf16x4*)(T + nl * 256 + ((ml * 2) ^ ((nl & 7) << 4))) = v;
      }
    __syncthreads();
    __bf16* dst = z ? S2 : S1;
    const int bA = m0 >> 6;
#pragma unroll
    for (int it = 0; it < 4; ++it) {
      int nl = (tid >> 3) + it * 32;
      int seg = tid & 7;
      int xorv = (nl & 7) << 4;
      const char* src = T + nl * 256;
      bf16x8 v0 = *(const bf16x8*)(src + ((seg * 32) ^ xorv));
      bf16x8 v1 = *(const bf16x8*)(src + ((seg * 32 + 16) ^ xorv));
      int b = bA + (seg >> 2);
      size_t o = ((size_t)b * NNODE + n0 + nl) * 64 + (seg & 3) * 16;
      *(bf16x8*)(dst + o) = v0;
      *(bf16x8*)(dst + o + 8) = v1;
    }
  }
#undef STAGEXA
#undef STAGEXB
#undef AREG
#undef BREG
}

// ---------------------------------------------------------------------------
// M28[i] = fp8(128 * (M2a[i] + M2b[i])), bf16 partials in
__global__ __launch_bounds__(256) void combine_m2(const __bf16* __restrict__ M2p,
                                                  unsigned char* __restrict__ M28) {
  const size_t NN2 = (size_t)NNODE * NNODE;
  size_t i = ((size_t)blockIdx.x * 256 + threadIdx.x) * 8;
  bf16x8 a = *(const bf16x8*)(M2p + i);
  bf16x8 b = *(const bf16x8*)(M2p + NN2 + i);
  const float SA = 128.f;
  float sv[8];
#pragma unroll
  for (int k = 0; k < 8; ++k)
    sv[k] = ((float)a[k] + (float)b[k]) * SA;
  int w0 = __builtin_amdgcn_cvt_pk_fp8_f32(sv[0], sv[1], 0, false);
  w0 = __builtin_amdgcn_cvt_pk_fp8_f32(sv[2], sv[3], w0, true);
  int w1 = __builtin_amdgcn_cvt_pk_fp8_f32(sv[4], sv[5], 0, false);
  w1 = __builtin_amdgcn_cvt_pk_fp8_f32(sv[6], sv[7], w1, true);
  int2 pk; pk.x = w0; pk.y = w1;
  *(int2*)(M28 + i) = pk;
}

// ---------------------------------------------------------------------------
// Gate linear GEMM: [65536 x 192] @ Wt^T, K=192, N=128, fused epilogues.
// MODE 0: cols 0-63 -> z=sigmoid -> zbuf(f32); cols 64-127 -> r ->
//         rx=(bf16)(r*hid) row-major AND fp8(16*rx)^T -> XT8out.
// MODE 1: cols 0-63 -> c=tanh -> out=(1-z)*hid+z*c (f32)
template <int MODE>
__global__ __launch_bounds__(256) void gemm_lin(const __bf16* __restrict__ Xp,
                                                const __bf16* __restrict__ S1,
                                                const __bf16* __restrict__ S2,
                                                const __bf16* __restrict__ Wt,
                                                const float* __restrict__ b0,
                                                const float* __restrict__ b1,
                                                const float* __restrict__ wpre,
                                                const float* __restrict__ wadp,
                                                const float* __restrict__ hid,
                                                float* __restrict__ zbuf,
                                                __bf16* __restrict__ rxout,
                                                unsigned char* __restrict__ XT8out,
                                                float* __restrict__ outp) {
  __shared__ __bf16 As[128 * 32];
  __shared__ __bf16 Bs[128 * 32];
  __shared__ char T[64 * 256];  // rx transpose staging (MODE 0)
  const int tid = threadIdx.x;
  const int wave = tid >> 6, lane = tid & 63;
  const int wr = wave >> 1, wc = wave & 1;
  const int m0 = blockIdx.x * 128;
  const int rowA = tid >> 2;
  const int colb = (tid & 3) * 16;
  const __bf16* srcs[3] = {Xp, S1, S2};
  char* asD0 = (char*)As + wave * 1024;
  char* asD1 = (char*)As + 4096 + wave * 1024;
  char* bsD0 = (char*)Bs + wave * 1024;
  char* bsD1 = (char*)Bs + 4096 + wave * 1024;

  f32x4 acc[4][4] = {};

#pragma unroll
  for (int kt = 0; kt < 6; ++kt) {
    const __bf16* Ab = srcs[kt >> 1];
    const char* aS0 = (const char*)(Ab + (size_t)(m0 + rowA) * 64) + (kt & 1) * 64 + colb;
    const char* aS1 = (const char*)(Ab + (size_t)(m0 + rowA + 64) * 64) + (kt & 1) * 64 + colb;
    const char* bS0 = (const char*)(Wt + (size_t)rowA * 192) + kt * 64 + colb;
    const char* bS1 = (const char*)(Wt + (size_t)(rowA + 64) * 192) + kt * 64 + colb;
    gload16(aS0, asD0);
    gload16(aS1, asD1);
    gload16(bS0, bsD0);
    gload16(bS1, bsD1);
    __syncthreads();
    bf16x8 af[4], bfr[4];
#pragma unroll
    for (int mi = 0; mi < 4; ++mi)
      af[mi] = *(const bf16x8*)((const char*)As +
               ((wr * 64 + mi * 16 + (lane & 15)) * 64 + (lane >> 4) * 16));
#pragma unroll
    for (int ni = 0; ni < 4; ++ni)
      bfr[ni] = *(const bf16x8*)((const char*)Bs +
               ((wc * 64 + ni * 16 + (lane & 15)) * 64 + (lane >> 4) * 16));
#pragma unroll
    for (int mi = 0; mi < 4; ++mi)
#pragma unroll
      for (int ni = 0; ni < 4; ++ni)
        acc[mi][ni] = __builtin_amdgcn_mfma_f32_16x16x32_bf16(af[mi], bfr[ni],
                                                              acc[mi][ni], 0, 0, 0);
    __syncthreads();
  }

  const float wp = *wpre, wa = *wadp;
  const float s = 2.f * wp + wa;
  const int crow = (lane >> 4) * 4;
  const int ccol = lane & 15;
#pragma unroll
  for (int mi = 0; mi < 4; ++mi)
#pragma unroll
    for (int ni = 0; ni < 4; ++ni) {
      int r0 = m0 + wr * 64 + mi * 16 + crow;
      int col = wc * 64 + ni * 16 + ccol;
      int cf = col & 63;
      if (MODE == 0) {
        if (col < 64) {
#pragma unroll
          for (int r = 0; r < 4; ++r) {
            int row = r0 + r;
            float g = acc[mi][ni][r] + s * b0[cf];
            zbuf[(size_t)row * 64 + cf] = 1.f / (1.f + __expf(-g));
          }
        } else {
          bf16x4 tv;
#pragma unroll
          for (int r = 0; r < 4; ++r) {
            int row = r0 + r;
            float g = acc[mi][ni][r] + s * b1[cf];
            float rv = 1.f / (1.f + __expf(-g));
            __bf16 rxv = (__bf16)(rv * hid[(size_t)row * 64 + cf]);
            rxout[(size_t)row * 64 + cf] = rxv;
            tv[r] = rxv;
          }
          int vl0 = wr * 64 + mi * 16 + crow;
          *(bf16x4*)(T + cf * 256 + ((vl0 * 2) ^ ((cf & 7) << 4))) = tv;
        }
      } else {
        if (col < 64) {
#pragma unroll
          for (int r = 0; r < 4; ++r) {
            int row = r0 + r;
            float g = acc[mi][ni][r] + s * b0[cf];
            float cv = 1.f - 2.f / (1.f + __expf(2.f * g));
            float zv = zbuf[(size_t)row * 64 + cf];
            float hv = hid[(size_t)row * 64 + cf];
            outp[(size_t)row * 64 + cf] = (1.f - zv) * hv + zv * cv;
          }
        }
      }
    }

  if (MODE == 0) {
    __syncthreads();
    const int b = m0 >> 11;
    const int v0 = m0 & 2047;
    const float SX = 16.f;
#pragma unroll
    for (int it = 0; it < 4; ++it) {
      int rr = it * 16 + (tid >> 4);
      int seg = tid & 15;
      bf16x8 v = *(const bf16x8*)(T + rr * 256 + ((seg * 16) ^ ((rr & 7) << 4)));
      int w0 = __builtin_amdgcn_cvt_pk_fp8_f32((float)v[0] * SX, (float)v[1] * SX, 0, false);
      w0 = __builtin_amdgcn_cvt_pk_fp8_f32((float)v[2] * SX, (float)v[3] * SX, w0, true);
      int w1 = __builtin_amdgcn_cvt_pk_fp8_f32((float)v[4] * SX, (float)v[5] * SX, 0, false);
      w1 = __builtin_amdgcn_cvt_pk_fp8_f32((float)v[6] * SX, (float)v[7] * SX, w1, true);
      int2 pk; pk.x = w0; pk.y = w1;
      *(int2*)(XT8out + ((size_t)(b * 64 + rr)) * NNODE + v0 + seg * 8) = pk;
    }
  }
}

// ---------------------------------------------------------------------------
extern "C" void kernel_launch(void* const* d_in, const int* in_sizes, int n_in,
                              void* d_out, int out_size, void* d_ws, size_t ws_size,
                              hipStream_t stream) {
  (void)in_sizes; (void)n_in; (void)out_size;
  const float* x    = (const float*)d_in[0];
  const float* A1   = (const float*)d_in[1];
  const float* A2   = (const float*)d_in[2];
  const float* E1   = (const float*)d_in[3];
  const float* E2   = (const float*)d_in[4];
  const float* Wz   = (const float*)d_in[5];
  const float* bz   = (const float*)d_in[6];
  const float* Wr   = (const float*)d_in[7];
  const float* br   = (const float*)d_in[8];
  const float* Wc   = (const float*)d_in[9];
  const float* bc   = (const float*)d_in[10];
  const float* wpre = (const float*)d_in[11];
  const float* wadp = (const float*)d_in[12];
  float* out = (float*)d_out;

  char* ws = (char*)d_ws;
  const size_t NN2 = (size_t)NNODE * NNODE;  // 4,194,304
  const size_t NN2B = NN2 * 2;               // bytes per bf16 slice
  unsigned char* ADJ8  = (unsigned char*)(ws + 6 * NN2B);           // 6 fp8
  unsigned char* ADJT8 = (unsigned char*)(ws + 6 * NN2B + 6 * NN2); // 6 fp8
  __bf16* SC   = (__bf16*)(ws + 12 * NN2B);     // scores (4 slices), then:
  __bf16* M2p  = (__bf16*)(ws + 12 * NN2B);     // bf16 partials x2 = [12,14)
  unsigned char* M18 = (unsigned char*)(ws + 18 * NN2B);        // fp8
  unsigned char* M28 = (unsigned char*)(ws + 18 * NN2B + NN2);  // fp8
  unsigned char* XT8 = (unsigned char*)(ws + 20 * NN2B);        // fp8
  __bf16* xbf  = (__bf16*)(ws + 21 * NN2B);
  __bf16* rx   = (__bf16*)(ws + 22 * NN2B);
  __bf16* S1   = (__bf16*)(ws + 2 * NN2B);
  __bf16* S2   = (__bf16*)(ws + 3 * NN2B);
  float*  zbuf = (float*)(ws + 4 * NN2B);
  __bf16* E1p  = (__bf16*)(ws + 23 * NN2B);
  __bf16* E2p  = E1p + 4 * NNODE * 32;
  __bf16* Wzrt = E2p + 4 * NNODE * 32;
  __bf16* Wct  = Wzrt + 128 * 192;
  if (ws_size < 23 * NN2B + 2 * 4 * NNODE * 32 * 2 + 2 * 128 * 192 * 2) return;

  // --- adjacency construction (fused)
  prep_ew<<<224, 256, 0, stream>>>(E1, E2, Wz, Wr, Wc, wpre, wadp,
                                   E1p, E2p, Wzrt, Wct);
  score_gemm<<<dim3(16, 16, 4), 256, 0, stream>>>(E1p, E2p, SC);
  soft_tx<<<3072, 256, 0, stream>>>(SC, ADJ8, x, XT8, xbf);
  prep_adj<<<dim3(32, 32), 256, 0, stream>>>(A1, A2, ADJ8, ADJT8, M18,
                                             wpre, wadp);

  // --- M2 = sum_z w_z A_z^2 (MX fp8 K=128; 512 blocks = 2/CU full machine)
  gemm_sq<<<dim3(16, 16, 2), 256, 65536, stream>>>(ADJ8, ADJT8, M2p);
  combine_m2<<<2048, 256, 0, stream>>>(M2p, M28);

  // --- stage 1: S1 = M1 x, S2 = M2 x (MX fp8 K=128, fused transposed epilogue)
  gemm_hop1sx<<<dim3(16, 16, 2), 256, 65536, stream>>>(XT8, M18, M28, S1, S2);
  gemm_lin<0><<<512, 256, 0, stream>>>(xbf, S1, S2, Wzrt, bz, br, wpre, wadp,
                                       x, zbuf, rx, XT8, nullptr);

  // --- stage 2: hops on r*x (XT8 holds fp8(16*rx)^T from gemm_lin<0>)
  gemm_hop1sx<<<dim3(16, 16, 2), 256, 65536, stream>>>(XT8, M18, M28, S1, S2);
  gemm_lin<1><<<512, 256, 0, stream>>>(rx, S1, S2, Wct, bc, nullptr, wpre, wadp,
                                       x, zbuf, nullptr, nullptr, out);
}

// Round 20
// 163.424 us; speedup vs baseline: 1.3114x; 1.0014x over previous
//
#include <hip/hip_runtime.h>

#define NNODE 2048
#define NBATCH 32

typedef __attribute__((ext_vector_type(4))) float f32x4;
typedef __attribute__((ext_vector_type(8))) __bf16 bf16x8;
typedef __attribute__((ext_vector_type(4))) __bf16 bf16x4;
typedef __attribute__((ext_vector_type(4))) int i32x4;
typedef __attribute__((ext_vector_type(8))) int i32x8;

__device__ __forceinline__ void gload16(const void* g, void* lds) {
  __builtin_amdgcn_global_load_lds(
      (const __attribute__((address_space(1))) unsigned int*)g,
      (__attribute__((address_space(3))) unsigned int*)lds, 16, 0, 0);
}

// ---------------------------------------------------------------------------
// Merged: prep_e (blocks 0..127) + prep_w (blocks 128..223)
__global__ __launch_bounds__(256) void prep_ew(const float* __restrict__ E1,
                                               const float* __restrict__ E2,
                                               const float* __restrict__ Wz,
                                               const float* __restrict__ Wr,
                                               const float* __restrict__ Wc,
                                               const float* __restrict__ wpre,
                                               const float* __restrict__ wadp,
                                               __bf16* __restrict__ E1p,
                                               __bf16* __restrict__ E2p,
                                               __bf16* __restrict__ Wzrt,
                                               __bf16* __restrict__ Wct) {
  if (blockIdx.x < 128) {
    int idx = blockIdx.x * 256 + threadIdx.x;  // 0..32767
    int cq = idx & 3;
    int n = (idx >> 2) & 2047;
    int h = idx >> 13;
    const float4 q1 = *(const float4*)(E1 + (size_t)(n * 4 + h) * 16 + cq * 4);
    const float4 q2 = *(const float4*)(E2 + (size_t)(n * 4 + h) * 16 + cq * 4);
    size_t o = ((size_t)h * NNODE + n) * 32 + cq * 4;
    E1p[o + 0] = (__bf16)q1.x; E1p[o + 1] = (__bf16)q1.y;
    E1p[o + 2] = (__bf16)q1.z; E1p[o + 3] = (__bf16)q1.w;
    E2p[o + 0] = (__bf16)q2.x; E2p[o + 1] = (__bf16)q2.y;
    E2p[o + 2] = (__bf16)q2.z; E2p[o + 3] = (__bf16)q2.w;
    size_t oz = o + 16;
    E1p[oz + 0] = (__bf16)0.f; E1p[oz + 1] = (__bf16)0.f;
    E1p[oz + 2] = (__bf16)0.f; E1p[oz + 3] = (__bf16)0.f;
    E2p[oz + 0] = (__bf16)0.f; E2p[oz + 1] = (__bf16)0.f;
    E2p[oz + 2] = (__bf16)0.f; E2p[oz + 3] = (__bf16)0.f;
  } else {
    int idx = (blockIdx.x - 128) * 256 + threadIdx.x;  // 0 .. 128*192-1
    int rr = idx / 192, k = idx % 192;
    float s = 2.f * (*wpre) + (*wadp);
    float sc = (k < 64) ? s : 1.f;
    float vz = (rr < 64) ? Wz[(size_t)k * 64 + rr] : Wr[(size_t)k * 64 + rr - 64];
    Wzrt[idx] = (__bf16)(vz * sc);
    float vc = (rr < 64) ? Wc[(size_t)k * 64 + rr] * sc : 0.f;
    Wct[idx] = (__bf16)vc;
  }
}

// ---------------------------------------------------------------------------
// SC8[h][w][v] = fp8(16 * relu(E1p_h @ E2p_h^T)/4). Single K=32 MFMA step.
__global__ __launch_bounds__(256) void score_gemm(const __bf16* __restrict__ E1p,
                                                  const __bf16* __restrict__ E2p,
                                                  unsigned char* __restrict__ SC8) {
  __shared__ __bf16 As[128 * 32];
  __shared__ __bf16 Bs[128 * 32];
  const int tid = threadIdx.x;
  const int wave = tid >> 6, lane = tid & 63;
  const int wr = wave >> 1, wc = wave & 1;
  const int h = blockIdx.z;
  const int m0 = blockIdx.x * 128, n0 = blockIdx.y * 128;
  const __bf16* A = E1p + (size_t)h * NNODE * 32;
  const __bf16* Bt = E2p + (size_t)h * NNODE * 32;
  const int rowA = tid >> 2;
  const int colb = (tid & 3) * 16;
  gload16((const char*)(A + (size_t)(m0 + rowA) * 32) + colb, (char*)As + wave * 1024);
  gload16((const char*)(A + (size_t)(m0 + rowA + 64) * 32) + colb, (char*)As + 4096 + wave * 1024);
  gload16((const char*)(Bt + (size_t)(n0 + rowA) * 32) + colb, (char*)Bs + wave * 1024);
  gload16((const char*)(Bt + (size_t)(n0 + rowA + 64) * 32) + colb, (char*)Bs + 4096 + wave * 1024);
  __syncthreads();

  f32x4 acc[4][4] = {};
  bf16x8 af[4], bfr[4];
#pragma unroll
  for (int mi = 0; mi < 4; ++mi)
    af[mi] = *(const bf16x8*)((const char*)As +
             ((wr * 64 + mi * 16 + (lane & 15)) * 64 + (lane >> 4) * 16));
#pragma unroll
  for (int ni = 0; ni < 4; ++ni)
    bfr[ni] = *(const bf16x8*)((const char*)Bs +
             ((wc * 64 + ni * 16 + (lane & 15)) * 64 + (lane >> 4) * 16));
#pragma unroll
  for (int mi = 0; mi < 4; ++mi)
#pragma unroll
    for (int ni = 0; ni < 4; ++ni)
      acc[mi][ni] = __builtin_amdgcn_mfma_f32_16x16x32_bf16(af[mi], bfr[ni],
                                                            acc[mi][ni], 0, 0, 0);

  const int crow = (lane >> 4) * 4;
  const int ccol = lane & 15;
#pragma unroll
  for (int mi = 0; mi < 4; ++mi)
#pragma unroll
    for (int ni = 0; ni < 4; ++ni) {
      int r0 = m0 + wr * 64 + mi * 16 + crow;
      int cc = n0 + wc * 64 + ni * 16 + ccol;
#pragma unroll
      for (int r = 0; r < 4; ++r) {
        float val = fmaxf(acc[mi][ni][r], 0.f) * 4.0f;  // (1/4 relu-scale)*16 fp8
        int w0 = __builtin_amdgcn_cvt_pk_fp8_f32(val, val, 0, false);
        SC8[((size_t)h * NNODE + r0 + r) * NNODE + cc] = (unsigned char)(w0 & 0xFF);
      }
    }
}

// ---------------------------------------------------------------------------
// Merged: blocks 0..2047 -> row softmax (fp8 SC8 -> fp8 ADJ8 slices 2..5,
// scaled x128); blocks 2048..3071 -> transpose_x: x f32 -> XT8 fp8(16x) and
// xbf bf16 [B*N,64].
__global__ __launch_bounds__(256) void soft_tx(const unsigned char* __restrict__ SC8,
                                               unsigned char* __restrict__ ADJ8,
                                               const float* __restrict__ x,
                                               unsigned char* __restrict__ XT8,
                                               __bf16* __restrict__ xbf) {
  const int tid = threadIdx.x;
  const size_t NN2 = (size_t)NNODE * NNODE;
  if (blockIdx.x < 2048) {
    const int wave = tid >> 6, lane = tid & 63;
    const size_t row = (size_t)blockIdx.x * 4 + wave;
    const unsigned char* src = SC8 + row * NNODE;
    unsigned char* dst = ADJ8 + 2 * NN2 + row * NNODE;  // slices 2..5
    float v[32];
    float mx = 0.f;
    const float DSC = 0.0625f;  // 1/16 score descale
#pragma unroll
    for (int j = 0; j < 4; ++j) {
      int2 q = *(const int2*)(src + j * 512 + lane * 8);
      // selector must be a literal constant -> explicit unroll
      v[j * 8 + 0] = __builtin_amdgcn_cvt_f32_fp8(q.x, 0) * DSC;
      v[j * 8 + 1] = __builtin_amdgcn_cvt_f32_fp8(q.x, 1) * DSC;
      v[j * 8 + 2] = __builtin_amdgcn_cvt_f32_fp8(q.x, 2) * DSC;
      v[j * 8 + 3] = __builtin_amdgcn_cvt_f32_fp8(q.x, 3) * DSC;
      v[j * 8 + 4] = __builtin_amdgcn_cvt_f32_fp8(q.y, 0) * DSC;
      v[j * 8 + 5] = __builtin_amdgcn_cvt_f32_fp8(q.y, 1) * DSC;
      v[j * 8 + 6] = __builtin_amdgcn_cvt_f32_fp8(q.y, 2) * DSC;
      v[j * 8 + 7] = __builtin_amdgcn_cvt_f32_fp8(q.y, 3) * DSC;
#pragma unroll
      for (int i = 0; i < 8; ++i) mx = fmaxf(mx, v[j * 8 + i]);
    }
#pragma unroll
    for (int o = 32; o > 0; o >>= 1) mx = fmaxf(mx, __shfl_xor(mx, o));
    float s = 0.f;
#pragma unroll
    for (int i = 0; i < 32; ++i) {
      v[i] = __expf(v[i] - mx);
      s += v[i];
    }
#pragma unroll
    for (int o = 32; o > 0; o >>= 1) s += __shfl_xor(s, o);
    float inv = 128.f / s;  // x128 fp8 scale folded in
#pragma unroll
    for (int j = 0; j < 4; ++j) {
      int w0 = __builtin_amdgcn_cvt_pk_fp8_f32(v[j * 8 + 0] * inv, v[j * 8 + 1] * inv, 0, false);
      w0 = __builtin_amdgcn_cvt_pk_fp8_f32(v[j * 8 + 2] * inv, v[j * 8 + 3] * inv, w0, true);
      int w1 = __builtin_amdgcn_cvt_pk_fp8_f32(v[j * 8 + 4] * inv, v[j * 8 + 5] * inv, 0, false);
      w1 = __builtin_amdgcn_cvt_pk_fp8_f32(v[j * 8 + 6] * inv, v[j * 8 + 7] * inv, w1, true);
      int2 pk; pk.x = w0; pk.y = w1;
      *(int2*)(dst + j * 512 + lane * 8) = pk;
    }
  } else {
    const int idx = blockIdx.x - 2048;
    const int b = idx >> 5, v0 = (idx & 31) * 64;
    __shared__ float t[64][65];
    const int vr = tid >> 2, c0 = (tid & 3) * 16;
    const float* src = x + ((size_t)b * NNODE + v0 + vr) * 64 + c0;
    __bf16* xb = xbf + ((size_t)b * NNODE + v0 + vr) * 64 + c0;
#pragma unroll
    for (int j = 0; j < 4; ++j) {
      float4 q = ((const float4*)src)[j];
      t[vr][c0 + j * 4 + 0] = q.x;
      t[vr][c0 + j * 4 + 1] = q.y;
      t[vr][c0 + j * 4 + 2] = q.z;
      t[vr][c0 + j * 4 + 3] = q.w;
      xb[j * 4 + 0] = (__bf16)q.x;
      xb[j * 4 + 1] = (__bf16)q.y;
      xb[j * 4 + 2] = (__bf16)q.z;
      xb[j * 4 + 3] = (__bf16)q.w;
    }
    __syncthreads();
    const float SX = 16.f;
#pragma unroll
    for (int jr = 0; jr < 4; ++jr) {
      int c = jr * 16 + (tid >> 4);
      int vq = (tid & 15) * 4;
      int w0 = __builtin_amdgcn_cvt_pk_fp8_f32(t[vq][c] * SX, t[vq + 1][c] * SX, 0, false);
      w0 = __builtin_amdgcn_cvt_pk_fp8_f32(t[vq + 2][c] * SX, t[vq + 3][c] * SX, w0, true);
      *(int*)(XT8 + ((size_t)(b * 64 + c)) * NNODE + v0 + vq) = w0;
    }
  }
}

// ---------------------------------------------------------------------------
// Fused adjacency prep (x128 domain): z<2 reads A1/A2 f32, writes ADJ8;
// z>=2 reads fp8 ADJ8 (written by soft_tx). All z: ADJT8 = fp8(wz * v128),
// M18 = fp8(sum wz * v128).
__global__ __launch_bounds__(256) void prep_adj(const float* __restrict__ A1,
                                                const float* __restrict__ A2,
                                                unsigned char* __restrict__ ADJ8,
                                                unsigned char* __restrict__ ADJT8,
                                                unsigned char* __restrict__ M18,
                                                const float* __restrict__ wpre,
                                                const float* __restrict__ wadp) {
  const int r0 = blockIdx.x * 64, c0 = blockIdx.y * 64;
  const int tid = threadIdx.x;
  const size_t NN2 = (size_t)NNODE * NNODE;
  const float wp = *wpre, wa = *wadp * 0.25f;
  const float SA = 128.f;
  __shared__ float t[64][65];
  const int vr = tid >> 2, cg = (tid & 3) * 16;
  float m1acc[16] = {};

  for (int z = 0; z < 6; ++z) {
    const float wz = (z < 2) ? wp : wa;
    float vv[16];  // values in x128 domain
    if (z < 2) {
      const float* src = (z == 0 ? A1 : A2) + (size_t)(r0 + vr) * NNODE + c0 + cg;
#pragma unroll
      for (int j = 0; j < 4; ++j) {
        float4 q = ((const float4*)src)[j];
        vv[j * 4 + 0] = q.x * SA; vv[j * 4 + 1] = q.y * SA;
        vv[j * 4 + 2] = q.z * SA; vv[j * 4 + 3] = q.w * SA;
      }
      int4 pk;
#pragma unroll
      for (int q = 0; q < 4; ++q) {
        int w0 = __builtin_amdgcn_cvt_pk_fp8_f32(vv[4 * q], vv[4 * q + 1], 0, false);
        w0 = __builtin_amdgcn_cvt_pk_fp8_f32(vv[4 * q + 2], vv[4 * q + 3], w0, true);
        (&pk.x)[q] = w0;
      }
      *(int4*)(ADJ8 + (size_t)z * NN2 + (size_t)(r0 + vr) * NNODE + c0 + cg) = pk;
    } else {
      int4 pk = *(const int4*)(ADJ8 + (size_t)z * NN2 + (size_t)(r0 + vr) * NNODE + c0 + cg);
#pragma unroll
      for (int q = 0; q < 4; ++q) {
        int w0 = (&pk.x)[q];
        vv[4 * q + 0] = __builtin_amdgcn_cvt_f32_fp8(w0, 0);
        vv[4 * q + 1] = __builtin_amdgcn_cvt_f32_fp8(w0, 1);
        vv[4 * q + 2] = __builtin_amdgcn_cvt_f32_fp8(w0, 2);
        vv[4 * q + 3] = __builtin_amdgcn_cvt_f32_fp8(w0, 3);
      }
    }
#pragma unroll
    for (int i = 0; i < 16; ++i) {
      m1acc[i] += wz * vv[i];
      t[vr][cg + i] = vv[i];
    }
    __syncthreads();
    {
#pragma unroll
      for (int jr = 0; jr < 4; ++jr) {
        int c = jr * 16 + (tid >> 4);
        int vq = (tid & 15) * 4;
        int w0 = __builtin_amdgcn_cvt_pk_fp8_f32(t[vq][c] * wz, t[vq + 1][c] * wz, 0, false);
        w0 = __builtin_amdgcn_cvt_pk_fp8_f32(t[vq + 2][c] * wz, t[vq + 3][c] * wz, w0, true);
        *(int*)(ADJT8 + (size_t)z * NN2 + (size_t)(c0 + c) * NNODE + r0 + vq) = w0;
      }
    }
    __syncthreads();
  }
  {
    int4 pk;
#pragma unroll
    for (int q = 0; q < 4; ++q) {
      int w0 = __builtin_amdgcn_cvt_pk_fp8_f32(m1acc[4 * q], m1acc[4 * q + 1], 0, false);
      w0 = __builtin_amdgcn_cvt_pk_fp8_f32(m1acc[4 * q + 2], m1acc[4 * q + 3], w0, true);
      (&pk.x)[q] = w0;
    }
    *(int4*)(M18 + (size_t)(r0 + vr) * NNODE + c0 + cg) = pk;
  }
}

// ---------------------------------------------------------------------------
#define VMCNT0() asm volatile("s_waitcnt vmcnt(0)" ::: "memory")
#define VMCNT8() asm volatile("s_waitcnt vmcnt(8)" ::: "memory")
#define LGKMCNT0() asm volatile("s_waitcnt lgkmcnt(0)" ::: "memory")
#define BARRIER() asm volatile("s_barrier" ::: "memory")

// ---------------------------------------------------------------------------
// Shared MX K=128 fp8 GEMM machinery (R17-verified): 128x128 tile, BK=128,
// 16 KiB regions ([128 rows][128 B], 3-bit XOR swizzle), LDS 64 KiB ->
// 2 blocks/CU, R11 register-pipelined schedule with vmcnt(8), scales = 1.0.
#define MX_GEOM()                                                             \
  int aoff[4][2], boff[4][2];                                                 \
  _Pragma("unroll")                                                           \
  for (int mi = 0; mi < 4; ++mi)                                              \
    _Pragma("unroll")                                                         \
    for (int part = 0; part < 2; ++part) {                                    \
      int rh = mi * 32 + wr * 16 + (l & 15);                                  \
      int lo = rh * 128 + (l >> 4) * 32 + part * 16;                          \
      aoff[mi][part] = lo ^ ((rh & 7) << 4);                                  \
    }                                                                         \
  _Pragma("unroll")                                                           \
  for (int j = 0; j < 4; ++j)                                                 \
    _Pragma("unroll")                                                         \
    for (int part = 0; part < 2; ++part) {                                    \
      int rh = j * 32 + wc * 16 + (l & 15);                                   \
      int lo = rh * 128 + (l >> 4) * 32 + part * 16;                          \
      boff[j][part] = lo ^ ((rh & 7) << 4);                                   \
    }                                                                         \
  const int sg_row = w * 8 + (l >> 3);                                        \
  const int sg_col = (((l & 7) ^ ((l >> 3) & 7)) << 4);                       \
  unsigned aLoff[4], bLoff[4];                                                \
  _Pragma("unroll")                                                           \
  for (int p = 0; p < 4; ++p) {                                               \
    aLoff[p] = (unsigned)((m0 + p * 32 + sg_row) * 2048 + sg_col);            \
    bLoff[p] = (unsigned)((n0 + p * 32 + sg_row) * 2048 + sg_col);            \
  }

#define RDFRAG(region, o0, o1)                                                \
  __builtin_shufflevector(*(const i32x4*)((region) + (o0)),                   \
                          *(const i32x4*)((region) + (o1)),                   \
                          0, 1, 2, 3, 4, 5, 6, 7)

#define READFRAGSX(d, AF, BF)                                                 \
  do {                                                                        \
    _Pragma("unroll")                                                         \
    for (int mi = 0; mi < 4; ++mi)                                            \
      AF[mi] = RDFRAG(AREG(d), aoff[mi][0], aoff[mi][1]);                     \
    _Pragma("unroll")                                                         \
    for (int j = 0; j < 4; ++j)                                               \
      BF[j] = RDFRAG(BREG(d), boff[j][0], boff[j][1]);                        \
  } while (0)

#define MFMAX(AF, BF)                                                         \
  do {                                                                        \
    __builtin_amdgcn_s_setprio(1);                                            \
    _Pragma("unroll")                                                         \
    for (int mi = 0; mi < 4; ++mi)                                            \
      _Pragma("unroll")                                                       \
      for (int j = 0; j < 4; ++j)                                             \
        acc[mi][j] = __builtin_amdgcn_mfma_scale_f32_16x16x128_f8f6f4(        \
            AF[mi], BF[j], acc[mi][j], 0, 0, 0, 0x7F7F7F7F, 0, 0x7F7F7F7F);   \
    __builtin_amdgcn_s_setprio(0);                                            \
  } while (0)

// ---------------------------------------------------------------------------
// Fused-squares (MX K=128): M2part[zh] = (1/16384) sum_{z in half} ADJ8_z @
// ADJT8_z^T. 512 blocks = 2/CU; bf16 partials x2. R20: z-uniform 8x8 XCD
// chunks (XCDs 0-3 zh=0, 4-7 zh=1; each XCD an 8x8 m,n square).
__global__ __launch_bounds__(256, 2) void gemm_sq(const unsigned char* __restrict__ ADJ8,
                                                  const unsigned char* __restrict__ ADJT8,
                                                  __bf16* __restrict__ M2part) {
  extern __shared__ char smem[];  // 65536 B
  const int tid = threadIdx.x;
  const int w = tid >> 6, l = tid & 63;
  const int wr = w >> 1, wc = w & 1;
  const size_t NN2 = (size_t)NNODE * NNODE;
  int lin = blockIdx.x + 16 * blockIdx.y + 256 * blockIdx.z;  // [0,512)
  int xcd = lin & 7;
  int s = lin >> 3;              // [0,64)
  const int zh = xcd >> 2;       // [0,2)
  const int q = xcd & 3;         // quadrant within zh
  const int m0 = ((q & 1) * 8 + (s & 7)) * 128;
  const int n0 = ((q >> 1) * 8 + (s >> 3)) * 128;
  const int zb = zh * 3;
  __bf16* Cp = M2part + (size_t)zh * NN2;
  const int NTT = 48;            // 3 z * 16 K-tiles (BK=128)

#define AREG(d) (smem + (d) * 16384)
#define BREG(d) (smem + 32768 + (d) * 16384)

  MX_GEOM();

#define STAGEXA(toff, region)                                                 \
  do {                                                                        \
    _Pragma("unroll")                                                         \
    for (int p = 0; p < 4; ++p)                                               \
      gload16((const char*)ADJ8 + (toff) + aLoff[p],                          \
              (region) + p * 4096 + w * 1024);                                \
  } while (0)
#define STAGEXB(toff, region)                                                 \
  do {                                                                        \
    _Pragma("unroll")                                                         \
    for (int p = 0; p < 4; ++p)                                               \
      gload16((const char*)ADJT8 + (toff) + bLoff[p],                         \
              (region) + p * 4096 + w * 1024);                                \
  } while (0)

  f32x4 acc[4][4] = {};
  i32x8 afA[4], bfA[4], afB[4], bfB[4];

  size_t tOff = (size_t)zb * NN2;
  STAGEXA(tOff, AREG(0));
  STAGEXB(tOff, BREG(0));
  STAGEXA(tOff + 128, AREG(1));
  STAGEXB(tOff + 128, BREG(1));
  tOff += 256;
  VMCNT8();   // tile0 landed (tile1's 8 in flight)
  BARRIER();
  READFRAGSX(0, afA, bfA);
  LGKMCNT0();
  BARRIER();

  for (int t = 0; t <= NTT - 4; t += 2) {
    STAGEXA(tOff, AREG(0));
    STAGEXB(tOff, BREG(0));
    tOff += (((t + 2) & 15) == 15) ? (NN2 - (size_t)15 * 128) : (size_t)128;
    VMCNT8();
    BARRIER();
    READFRAGSX(1, afB, bfB);
    MFMAX(afA, bfA);
    LGKMCNT0();
    BARRIER();
    STAGEXA(tOff, AREG(1));
    STAGEXB(tOff, BREG(1));
    tOff += (((t + 3) & 15) == 15) ? (NN2 - (size_t)15 * 128) : (size_t)128;
    VMCNT8();
    BARRIER();
    READFRAGSX(0, afA, bfA);
    MFMAX(afB, bfB);
    LGKMCNT0();
    BARRIER();
  }
  VMCNT0();
  BARRIER();
  READFRAGSX(1, afB, bfB);
  MFMAX(afA, bfA);
  LGKMCNT0();
  MFMAX(afB, bfB);

  const float DS = 1.f / 16384.f;
  const int crow = (l >> 4) * 4;
  const int ccol = l & 15;
#pragma unroll
  for (int mi = 0; mi < 4; ++mi)
#pragma unroll
    for (int j = 0; j < 4; ++j) {
      int r0 = m0 + mi * 32 + wr * 16 + crow;
      int cc = n0 + j * 32 + wc * 16 + ccol;
#pragma unroll
      for (int r = 0; r < 4; ++r)
        Cp[(size_t)(r0 + r) * NNODE + cc] = (__bf16)(acc[mi][j][r] * DS);
    }
#undef STAGEXA
#undef STAGEXB
#undef AREG
#undef BREG
}

// ---------------------------------------------------------------------------
// Stage GEMM (MX K=128, R17/R18-verified) with fused transposed epilogue:
//   S_z[(b,n),c] = (1/2048) sum_v XT8[(b,c)][v] * M_z8[n][v].
__global__ __launch_bounds__(256, 2) void gemm_hop1sx(const unsigned char* __restrict__ XT8,
                                                      const unsigned char* __restrict__ M18,
                                                      const unsigned char* __restrict__ M28,
                                                      __bf16* __restrict__ S1,
                                                      __bf16* __restrict__ S2) {
  extern __shared__ char smem[];  // 65536 B
  const int tid = threadIdx.x;
  const int w = tid >> 6, l = tid & 63;
  const int wr = w >> 1, wc = w & 1;
  int lin = blockIdx.x + 16 * blockIdx.y + 256 * blockIdx.z;  // [0,512)
  int nlin = (lin & 7) * 64 + (lin >> 3);
  const int m0 = (nlin & 15) * 128, n0 = ((nlin >> 4) & 15) * 128;
  const int z = nlin >> 8;
  const unsigned char* Bbase = z ? M28 : M18;
  const int NT = NNODE / 128;  // 16 K-tiles

#define AREG(d) (smem + (d) * 16384)
#define BREG(d) (smem + 32768 + (d) * 16384)

  MX_GEOM();

#define STAGEXA(koff, region)                                                 \
  do {                                                                        \
    _Pragma("unroll")                                                         \
    for (int p = 0; p < 4; ++p)                                               \
      gload16((const char*)XT8 + (koff) + aLoff[p],                           \
              (region) + p * 4096 + w * 1024);                                \
  } while (0)
#define STAGEXB(koff, region)                                                 \
  do {                                                                        \
    _Pragma("unroll")                                                         \
    for (int p = 0; p < 4; ++p)                                               \
      gload16((const char*)Bbase + (koff) + bLoff[p],                         \
              (region) + p * 4096 + w * 1024);                                \
  } while (0)

  f32x4 acc[4][4] = {};
  i32x8 afA[4], bfA[4], afB[4], bfB[4];

  size_t kOff = 0;
  STAGEXA(kOff, AREG(0));
  STAGEXB(kOff, BREG(0));
  STAGEXA(kOff + 128, AREG(1));
  STAGEXB(kOff + 128, BREG(1));
  kOff += 256;
  VMCNT8();
  BARRIER();
  READFRAGSX(0, afA, bfA);
  LGKMCNT0();
  BARRIER();

  for (int t = 0; t <= NT - 4; t += 2) {
    STAGEXA(kOff, AREG(0));
    STAGEXB(kOff, BREG(0));
    kOff += 128;
    VMCNT8();
    BARRIER();
    READFRAGSX(1, afB, bfB);
    MFMAX(afA, bfA);
    LGKMCNT0();
    BARRIER();
    STAGEXA(kOff, AREG(1));
    STAGEXB(kOff, BREG(1));
    kOff += 128;
    VMCNT8();
    BARRIER();
    READFRAGSX(0, afA, bfA);
    MFMAX(afB, bfB);
    LGKMCNT0();
    BARRIER();
  }
  VMCNT0();
  BARRIER();
  READFRAGSX(1, afB, bfB);
  MFMAX(afA, bfA);
  LGKMCNT0();
  MFMAX(afB, bfB);

  // ---- epilogue (R14-verified): descale, LDS transpose T[n][m] (slot-XOR),
  // coalesced write S_z[(b, n0+n)*64 + c].
  {
    __syncthreads();
    const float DS = 1.f / 2048.f;  // 1/(16*128)
    const int crow = (l >> 4) * 4;
    const int ccol = l & 15;
    char* T = smem;  // 128 x 256 B = 32768
#pragma unroll
    for (int mi = 0; mi < 4; ++mi)
#pragma unroll
      for (int j = 0; j < 4; ++j) {
        int ml = mi * 32 + wr * 16 + crow;
        int nl = j * 32 + wc * 16 + ccol;
        bf16x4 v;
#pragma unroll
        for (int r = 0; r < 4; ++r) v[r] = (__bf16)(acc[mi][j][r] * DS);
        *(bf16x4*)(T + nl * 256 + ((ml * 2) ^ ((nl & 7) << 4))) = v;
      }
    __syncthreads();
    __bf16* dst = z ? S2 : S1;
    const int bA = m0 >> 6;
#pragma unroll
    for (int it = 0; it < 4; ++it) {
      int nl = (tid >> 3) + it * 32;
      int seg = tid & 7;
      int xorv = (nl & 7) << 4;
      const char* src = T + nl * 256;
      bf16x8 v0 = *(const bf16x8*)(src + ((seg * 32) ^ xorv));
      bf16x8 v1 = *(const bf16x8*)(src + ((seg * 32 + 16) ^ xorv));
      int b = bA + (seg >> 2);
      size_t o = ((size_t)b * NNODE + n0 + nl) * 64 + (seg & 3) * 16;
      *(bf16x8*)(dst + o) = v0;
      *(bf16x8*)(dst + o + 8) = v1;
    }
  }
#undef STAGEXA
#undef STAGEXB
#undef AREG
#undef BREG
}

// ---------------------------------------------------------------------------
// M28[i] = fp8(128 * (M2a[i] + M2b[i])), bf16 partials in
__global__ __launch_bounds__(256) void combine_m2(const __bf16* __restrict__ M2p,
                                                  unsigned char* __restrict__ M28) {
  const size_t NN2 = (size_t)NNODE * NNODE;
  size_t i = ((size_t)blockIdx.x * 256 + threadIdx.x) * 8;
  bf16x8 a = *(const bf16x8*)(M2p + i);
  bf16x8 b = *(const bf16x8*)(M2p + NN2 + i);
  const float SA = 128.f;
  float sv[8];
#pragma unroll
  for (int k = 0; k < 8; ++k)
    sv[k] = ((float)a[k] + (float)b[k]) * SA;
  int w0 = __builtin_amdgcn_cvt_pk_fp8_f32(sv[0], sv[1], 0, false);
  w0 = __builtin_amdgcn_cvt_pk_fp8_f32(sv[2], sv[3], w0, true);
  int w1 = __builtin_amdgcn_cvt_pk_fp8_f32(sv[4], sv[5], 0, false);
  w1 = __builtin_amdgcn_cvt_pk_fp8_f32(sv[6], sv[7], w1, true);
  int2 pk; pk.x = w0; pk.y = w1;
  *(int2*)(M28 + i) = pk;
}

// ---------------------------------------------------------------------------
// Gate linear GEMM: [65536 x 192] @ Wt^T, K=192, N=128, fused epilogues.
// MODE 0: cols 0-63 -> z=sigmoid -> zbuf(f32); cols 64-127 -> r ->
//         rx=(bf16)(r*hid) row-major AND fp8(16*rx)^T -> XT8out.
// MODE 1: cols 0-63 -> c=tanh -> out=(1-z)*hid+z*c (f32)
template <int MODE>
__global__ __launch_bounds__(256) void gemm_lin(const __bf16* __restrict__ Xp,
                                                const __bf16* __restrict__ S1,
                                                const __bf16* __restrict__ S2,
                                                const __bf16* __restrict__ Wt,
                                                const float* __restrict__ b0,
                                                const float* __restrict__ b1,
                                                const float* __restrict__ wpre,
                                                const float* __restrict__ wadp,
                                                const float* __restrict__ hid,
                                                float* __restrict__ zbuf,
                                                __bf16* __restrict__ rxout,
                                                unsigned char* __restrict__ XT8out,
                                                float* __restrict__ outp) {
  __shared__ __bf16 As[128 * 32];
  __shared__ __bf16 Bs[128 * 32];
  __shared__ char T[64 * 256];  // rx transpose staging (MODE 0)
  const int tid = threadIdx.x;
  const int wave = tid >> 6, lane = tid & 63;
  const int wr = wave >> 1, wc = wave & 1;
  const int m0 = blockIdx.x * 128;
  const int rowA = tid >> 2;
  const int colb = (tid & 3) * 16;
  const __bf16* srcs[3] = {Xp, S1, S2};
  char* asD0 = (char*)As + wave * 1024;
  char* asD1 = (char*)As + 4096 + wave * 1024;
  char* bsD0 = (char*)Bs + wave * 1024;
  char* bsD1 = (char*)Bs + 4096 + wave * 1024;

  f32x4 acc[4][4] = {};

#pragma unroll
  for (int kt = 0; kt < 6; ++kt) {
    const __bf16* Ab = srcs[kt >> 1];
    const char* aS0 = (const char*)(Ab + (size_t)(m0 + rowA) * 64) + (kt & 1) * 64 + colb;
    const char* aS1 = (const char*)(Ab + (size_t)(m0 + rowA + 64) * 64) + (kt & 1) * 64 + colb;
    const char* bS0 = (const char*)(Wt + (size_t)rowA * 192) + kt * 64 + colb;
    const char* bS1 = (const char*)(Wt + (size_t)(rowA + 64) * 192) + kt * 64 + colb;
    gload16(aS0, asD0);
    gload16(aS1, asD1);
    gload16(bS0, bsD0);
    gload16(bS1, bsD1);
    __syncthreads();
    bf16x8 af[4], bfr[4];
#pragma unroll
    for (int mi = 0; mi < 4; ++mi)
      af[mi] = *(const bf16x8*)((const char*)As +
               ((wr * 64 + mi * 16 + (lane & 15)) * 64 + (lane >> 4) * 16));
#pragma unroll
    for (int ni = 0; ni < 4; ++ni)
      bfr[ni] = *(const bf16x8*)((const char*)Bs +
               ((wc * 64 + ni * 16 + (lane & 15)) * 64 + (lane >> 4) * 16));
#pragma unroll
    for (int mi = 0; mi < 4; ++mi)
#pragma unroll
      for (int ni = 0; ni < 4; ++ni)
        acc[mi][ni] = __builtin_amdgcn_mfma_f32_16x16x32_bf16(af[mi], bfr[ni],
                                                              acc[mi][ni], 0, 0, 0);
    __syncthreads();
  }

  const float wp = *wpre, wa = *wadp;
  const float s = 2.f * wp + wa;
  const int crow = (lane >> 4) * 4;
  const int ccol = lane & 15;
#pragma unroll
  for (int mi = 0; mi < 4; ++mi)
#pragma unroll
    for (int ni = 0; ni < 4; ++ni) {
      int r0 = m0 + wr * 64 + mi * 16 + crow;
      int col = wc * 64 + ni * 16 + ccol;
      int cf = col & 63;
      if (MODE == 0) {
        if (col < 64) {
#pragma unroll
          for (int r = 0; r < 4; ++r) {
            int row = r0 + r;
            float g = acc[mi][ni][r] + s * b0[cf];
            zbuf[(size_t)row * 64 + cf] = 1.f / (1.f + __expf(-g));
          }
        } else {
          bf16x4 tv;
#pragma unroll
          for (int r = 0; r < 4; ++r) {
            int row = r0 + r;
            float g = acc[mi][ni][r] + s * b1[cf];
            float rv = 1.f / (1.f + __expf(-g));
            __bf16 rxv = (__bf16)(rv * hid[(size_t)row * 64 + cf]);
            rxout[(size_t)row * 64 + cf] = rxv;
            tv[r] = rxv;
          }
          int vl0 = wr * 64 + mi * 16 + crow;
          *(bf16x4*)(T + cf * 256 + ((vl0 * 2) ^ ((cf & 7) << 4))) = tv;
        }
      } else {
        if (col < 64) {
#pragma unroll
          for (int r = 0; r < 4; ++r) {
            int row = r0 + r;
            float g = acc[mi][ni][r] + s * b0[cf];
            float cv = 1.f - 2.f / (1.f + __expf(2.f * g));
            float zv = zbuf[(size_t)row * 64 + cf];
            float hv = hid[(size_t)row * 64 + cf];
            outp[(size_t)row * 64 + cf] = (1.f - zv) * hv + zv * cv;
          }
        }
      }
    }

  if (MODE == 0) {
    __syncthreads();
    const int b = m0 >> 11;
    const int v0 = m0 & 2047;
    const float SX = 16.f;
#pragma unroll
    for (int it = 0; it < 4; ++it) {
      int rr = it * 16 + (tid >> 4);
      int seg = tid & 15;
      bf16x8 v = *(const bf16x8*)(T + rr * 256 + ((seg * 16) ^ ((rr & 7) << 4)));
      int w0 = __builtin_amdgcn_cvt_pk_fp8_f32((float)v[0] * SX, (float)v[1] * SX, 0, false);
      w0 = __builtin_amdgcn_cvt_pk_fp8_f32((float)v[2] * SX, (float)v[3] * SX, w0, true);
      int w1 = __builtin_amdgcn_cvt_pk_fp8_f32((float)v[4] * SX, (float)v[5] * SX, 0, false);
      w1 = __builtin_amdgcn_cvt_pk_fp8_f32((float)v[6] * SX, (float)v[7] * SX, w1, true);
      int2 pk; pk.x = w0; pk.y = w1;
      *(int2*)(XT8out + ((size_t)(b * 64 + rr)) * NNODE + v0 + seg * 8) = pk;
    }
  }
}

// ---------------------------------------------------------------------------
extern "C" void kernel_launch(void* const* d_in, const int* in_sizes, int n_in,
                              void* d_out, int out_size, void* d_ws, size_t ws_size,
                              hipStream_t stream) {
  (void)in_sizes; (void)n_in; (void)out_size;
  const float* x    = (const float*)d_in[0];
  const float* A1   = (const float*)d_in[1];
  const float* A2   = (const float*)d_in[2];
  const float* E1   = (const float*)d_in[3];
  const float* E2   = (const float*)d_in[4];
  const float* Wz   = (const float*)d_in[5];
  const float* bz   = (const float*)d_in[6];
  const float* Wr   = (const float*)d_in[7];
  const float* br   = (const float*)d_in[8];
  const float* Wc   = (const float*)d_in[9];
  const float* bc   = (const float*)d_in[10];
  const float* wpre = (const float*)d_in[11];
  const float* wadp = (const float*)d_in[12];
  float* out = (float*)d_out;

  char* ws = (char*)d_ws;
  const size_t NN2 = (size_t)NNODE * NNODE;  // 4,194,304
  const size_t NN2B = NN2 * 2;               // bytes per bf16 slice
  unsigned char* ADJ8  = (unsigned char*)(ws + 6 * NN2B);           // 6 fp8
  unsigned char* ADJT8 = (unsigned char*)(ws + 6 * NN2B + 6 * NN2); // 6 fp8
  unsigned char* SC8 = (unsigned char*)(ws + 12 * NN2B);  // fp8 scores (4 slices)
  __bf16* M2p  = (__bf16*)(ws + 12 * NN2B);     // bf16 partials x2 (post-SC8)
  unsigned char* M18 = (unsigned char*)(ws + 18 * NN2B);        // fp8
  unsigned char* M28 = (unsigned char*)(ws + 18 * NN2B + NN2);  // fp8
  unsigned char* XT8 = (unsigned char*)(ws + 20 * NN2B);        // fp8
  __bf16* xbf  = (__bf16*)(ws + 21 * NN2B);
  __bf16* rx   = (__bf16*)(ws + 22 * NN2B);
  __bf16* S1   = (__bf16*)(ws + 2 * NN2B);
  __bf16* S2   = (__bf16*)(ws + 3 * NN2B);
  float*  zbuf = (float*)(ws + 4 * NN2B);
  __bf16* E1p  = (__bf16*)(ws + 23 * NN2B);
  __bf16* E2p  = E1p + 4 * NNODE * 32;
  __bf16* Wzrt = E2p + 4 * NNODE * 32;
  __bf16* Wct  = Wzrt + 128 * 192;
  if (ws_size < 23 * NN2B + 2 * 4 * NNODE * 32 * 2 + 2 * 128 * 192 * 2) return;

  // --- adjacency construction (fused)
  prep_ew<<<224, 256, 0, stream>>>(E1, E2, Wz, Wr, Wc, wpre, wadp,
                                   E1p, E2p, Wzrt, Wct);
  score_gemm<<<dim3(16, 16, 4), 256, 0, stream>>>(E1p, E2p, SC8);
  soft_tx<<<3072, 256, 0, stream>>>(SC8, ADJ8, x, XT8, xbf);
  prep_adj<<<dim3(32, 32), 256, 0, stream>>>(A1, A2, ADJ8, ADJT8, M18,
                                             wpre, wadp);

  // --- M2 = sum_z w_z A_z^2 (MX fp8 K=128; 512 blocks = 2/CU full machine)
  gemm_sq<<<dim3(16, 16, 2), 256, 65536, stream>>>(ADJ8, ADJT8, M2p);
  combine_m2<<<2048, 256, 0, stream>>>(M2p, M28);

  // --- stage 1: S1 = M1 x, S2 = M2 x (MX fp8 K=128, fused transposed epilogue)
  gemm_hop1sx<<<dim3(16, 16, 2), 256, 65536, stream>>>(XT8, M18, M28, S1, S2);
  gemm_lin<0><<<512, 256, 0, stream>>>(xbf, S1, S2, Wzrt, bz, br, wpre, wadp,
                                       x, zbuf, rx, XT8, nullptr);

  // --- stage 2: hops on r*x (XT8 holds fp8(16*rx)^T from gemm_lin<0>)
  gemm_hop1sx<<<dim3(16, 16, 2), 256, 65536, stream>>>(XT8, M18, M28, S1, S2);
  gemm_lin<1><<<512, 256, 0, stream>>>(rx, S1, S2, Wct, bc, nullptr, wpre, wadp,
                                       x, zbuf, nullptr, nullptr, out);
}

// Round 22
// 160.669 us; speedup vs baseline: 1.3339x; 1.0171x over previous
//
#include <hip/hip_runtime.h>

#define NNODE 2048
#define NBATCH 32

typedef __attribute__((ext_vector_type(4))) float f32x4;
typedef __attribute__((ext_vector_type(8))) __bf16 bf16x8;
typedef __attribute__((ext_vector_type(4))) __bf16 bf16x4;
typedef __attribute__((ext_vector_type(4))) int i32x4;
typedef __attribute__((ext_vector_type(8))) int i32x8;

__device__ __forceinline__ void gload16(const void* g, void* lds) {
  __builtin_amdgcn_global_load_lds(
      (const __attribute__((address_space(1))) unsigned int*)g,
      (__attribute__((address_space(3))) unsigned int*)lds, 16, 0, 0);
}

// ---------------------------------------------------------------------------
// Merged: prep_e (blocks 0..127) + prep_w bf16 (blocks 128..223)
__global__ __launch_bounds__(256) void prep_ew(const float* __restrict__ E1,
                                               const float* __restrict__ E2,
                                               const float* __restrict__ Wz,
                                               const float* __restrict__ Wr,
                                               const float* __restrict__ Wc,
                                               const float* __restrict__ wpre,
                                               const float* __restrict__ wadp,
                                               __bf16* __restrict__ E1p,
                                               __bf16* __restrict__ E2p,
                                               __bf16* __restrict__ Wzrt,
                                               __bf16* __restrict__ Wct) {
  if (blockIdx.x < 128) {
    int idx = blockIdx.x * 256 + threadIdx.x;  // 0..32767
    int cq = idx & 3;
    int n = (idx >> 2) & 2047;
    int h = idx >> 13;
    const float4 q1 = *(const float4*)(E1 + (size_t)(n * 4 + h) * 16 + cq * 4);
    const float4 q2 = *(const float4*)(E2 + (size_t)(n * 4 + h) * 16 + cq * 4);
    size_t o = ((size_t)h * NNODE + n) * 32 + cq * 4;
    E1p[o + 0] = (__bf16)q1.x; E1p[o + 1] = (__bf16)q1.y;
    E1p[o + 2] = (__bf16)q1.z; E1p[o + 3] = (__bf16)q1.w;
    E2p[o + 0] = (__bf16)q2.x; E2p[o + 1] = (__bf16)q2.y;
    E2p[o + 2] = (__bf16)q2.z; E2p[o + 3] = (__bf16)q2.w;
    size_t oz = o + 16;
    E1p[oz + 0] = (__bf16)0.f; E1p[oz + 1] = (__bf16)0.f;
    E1p[oz + 2] = (__bf16)0.f; E1p[oz + 3] = (__bf16)0.f;
    E2p[oz + 0] = (__bf16)0.f; E2p[oz + 1] = (__bf16)0.f;
    E2p[oz + 2] = (__bf16)0.f; E2p[oz + 3] = (__bf16)0.f;
  } else {
    int idx = (blockIdx.x - 128) * 256 + threadIdx.x;  // 0 .. 128*192-1
    int rr = idx / 192, k = idx % 192;
    float s = 2.f * (*wpre) + (*wadp);
    float sc = (k < 64) ? s : 1.f;
    float vz = (rr < 64) ? Wz[(size_t)k * 64 + rr] : Wr[(size_t)k * 64 + rr - 64];
    Wzrt[idx] = (__bf16)(vz * sc);
    float vc = (rr < 64) ? Wc[(size_t)k * 64 + rr] * sc : 0.f;
    Wct[idx] = (__bf16)vc;
  }
}

// ---------------------------------------------------------------------------
// SC8[h][w][v] = fp8(16 * relu(E1p_h @ E2p_h^T)/4). Single K=32 MFMA step.
__global__ __launch_bounds__(256) void score_gemm(const __bf16* __restrict__ E1p,
                                                  const __bf16* __restrict__ E2p,
                                                  unsigned char* __restrict__ SC8) {
  __shared__ __bf16 As[128 * 32];
  __shared__ __bf16 Bs[128 * 32];
  const int tid = threadIdx.x;
  const int wave = tid >> 6, lane = tid & 63;
  const int wr = wave >> 1, wc = wave & 1;
  const int h = blockIdx.z;
  const int m0 = blockIdx.x * 128, n0 = blockIdx.y * 128;
  const __bf16* A = E1p + (size_t)h * NNODE * 32;
  const __bf16* Bt = E2p + (size_t)h * NNODE * 32;
  const int rowA = tid >> 2;
  const int colb = (tid & 3) * 16;
  gload16((const char*)(A + (size_t)(m0 + rowA) * 32) + colb, (char*)As + wave * 1024);
  gload16((const char*)(A + (size_t)(m0 + rowA + 64) * 32) + colb, (char*)As + 4096 + wave * 1024);
  gload16((const char*)(Bt + (size_t)(n0 + rowA) * 32) + colb, (char*)Bs + wave * 1024);
  gload16((const char*)(Bt + (size_t)(n0 + rowA + 64) * 32) + colb, (char*)Bs + 4096 + wave * 1024);
  __syncthreads();

  f32x4 acc[4][4] = {};
  bf16x8 af[4], bfr[4];
#pragma unroll
  for (int mi = 0; mi < 4; ++mi)
    af[mi] = *(const bf16x8*)((const char*)As +
             ((wr * 64 + mi * 16 + (lane & 15)) * 64 + (lane >> 4) * 16));
#pragma unroll
  for (int ni = 0; ni < 4; ++ni)
    bfr[ni] = *(const bf16x8*)((const char*)Bs +
             ((wc * 64 + ni * 16 + (lane & 15)) * 64 + (lane >> 4) * 16));
#pragma unroll
  for (int mi = 0; mi < 4; ++mi)
#pragma unroll
    for (int ni = 0; ni < 4; ++ni)
      acc[mi][ni] = __builtin_amdgcn_mfma_f32_16x16x32_bf16(af[mi], bfr[ni],
                                                            acc[mi][ni], 0, 0, 0);

  const int crow = (lane >> 4) * 4;
  const int ccol = lane & 15;
#pragma unroll
  for (int mi = 0; mi < 4; ++mi)
#pragma unroll
    for (int ni = 0; ni < 4; ++ni) {
      int r0 = m0 + wr * 64 + mi * 16 + crow;
      int cc = n0 + wc * 64 + ni * 16 + ccol;
#pragma unroll
      for (int r = 0; r < 4; ++r) {
        float val = fmaxf(acc[mi][ni][r], 0.f) * 4.0f;  // (1/4 relu-scale)*16 fp8
        int w0 = __builtin_amdgcn_cvt_pk_fp8_f32(val, val, 0, false);
        SC8[((size_t)h * NNODE + r0 + r) * NNODE + cc] = (unsigned char)(w0 & 0xFF);
      }
    }
}

// ---------------------------------------------------------------------------
// Merged: blocks 0..2047 -> row softmax (fp8 SC8 -> fp8 ADJ8 slices 2..5,
// scaled x128); blocks 2048..3071 -> transpose_x: x f32 -> XT8 fp8(16x) and
// xbf bf16 [B*N,64].
__global__ __launch_bounds__(256) void soft_tx(const unsigned char* __restrict__ SC8,
                                               unsigned char* __restrict__ ADJ8,
                                               const float* __restrict__ x,
                                               unsigned char* __restrict__ XT8,
                                               __bf16* __restrict__ xbf) {
  const int tid = threadIdx.x;
  const size_t NN2 = (size_t)NNODE * NNODE;
  if (blockIdx.x < 2048) {
    const int wave = tid >> 6, lane = tid & 63;
    const size_t row = (size_t)blockIdx.x * 4 + wave;
    const unsigned char* src = SC8 + row * NNODE;
    unsigned char* dst = ADJ8 + 2 * NN2 + row * NNODE;  // slices 2..5
    float v[32];
    float mx = 0.f;
    const float DSC = 0.0625f;  // 1/16 score descale
#pragma unroll
    for (int j = 0; j < 4; ++j) {
      int2 q = *(const int2*)(src + j * 512 + lane * 8);
      v[j * 8 + 0] = __builtin_amdgcn_cvt_f32_fp8(q.x, 0) * DSC;
      v[j * 8 + 1] = __builtin_amdgcn_cvt_f32_fp8(q.x, 1) * DSC;
      v[j * 8 + 2] = __builtin_amdgcn_cvt_f32_fp8(q.x, 2) * DSC;
      v[j * 8 + 3] = __builtin_amdgcn_cvt_f32_fp8(q.x, 3) * DSC;
      v[j * 8 + 4] = __builtin_amdgcn_cvt_f32_fp8(q.y, 0) * DSC;
      v[j * 8 + 5] = __builtin_amdgcn_cvt_f32_fp8(q.y, 1) * DSC;
      v[j * 8 + 6] = __builtin_amdgcn_cvt_f32_fp8(q.y, 2) * DSC;
      v[j * 8 + 7] = __builtin_amdgcn_cvt_f32_fp8(q.y, 3) * DSC;
#pragma unroll
      for (int i = 0; i < 8; ++i) mx = fmaxf(mx, v[j * 8 + i]);
    }
#pragma unroll
    for (int o = 32; o > 0; o >>= 1) mx = fmaxf(mx, __shfl_xor(mx, o));
    float s = 0.f;
#pragma unroll
    for (int i = 0; i < 32; ++i) {
      v[i] = __expf(v[i] - mx);
      s += v[i];
    }
#pragma unroll
    for (int o = 32; o > 0; o >>= 1) s += __shfl_xor(s, o);
    float inv = 128.f / s;  // x128 fp8 scale folded in
#pragma unroll
    for (int j = 0; j < 4; ++j) {
      int w0 = __builtin_amdgcn_cvt_pk_fp8_f32(v[j * 8 + 0] * inv, v[j * 8 + 1] * inv, 0, false);
      w0 = __builtin_amdgcn_cvt_pk_fp8_f32(v[j * 8 + 2] * inv, v[j * 8 + 3] * inv, w0, true);
      int w1 = __builtin_amdgcn_cvt_pk_fp8_f32(v[j * 8 + 4] * inv, v[j * 8 + 5] * inv, 0, false);
      w1 = __builtin_amdgcn_cvt_pk_fp8_f32(v[j * 8 + 6] * inv, v[j * 8 + 7] * inv, w1, true);
      int2 pk; pk.x = w0; pk.y = w1;
      *(int2*)(dst + j * 512 + lane * 8) = pk;
    }
  } else {
    const int idx = blockIdx.x - 2048;
    const int b = idx >> 5, v0 = (idx & 31) * 64;
    __shared__ float t[64][65];
    const int vr = tid >> 2, c0 = (tid & 3) * 16;
    const float* src = x + ((size_t)b * NNODE + v0 + vr) * 64 + c0;
    __bf16* xb = xbf + ((size_t)b * NNODE + v0 + vr) * 64 + c0;
#pragma unroll
    for (int j = 0; j < 4; ++j) {
      float4 q = ((const float4*)src)[j];
      t[vr][c0 + j * 4 + 0] = q.x;
      t[vr][c0 + j * 4 + 1] = q.y;
      t[vr][c0 + j * 4 + 2] = q.z;
      t[vr][c0 + j * 4 + 3] = q.w;
      xb[j * 4 + 0] = (__bf16)q.x;
      xb[j * 4 + 1] = (__bf16)q.y;
      xb[j * 4 + 2] = (__bf16)q.z;
      xb[j * 4 + 3] = (__bf16)q.w;
    }
    __syncthreads();
    const float SX = 16.f;
#pragma unroll
    for (int jr = 0; jr < 4; ++jr) {
      int c = jr * 16 + (tid >> 4);
      int vq = (tid & 15) * 4;
      int w0 = __builtin_amdgcn_cvt_pk_fp8_f32(t[vq][c] * SX, t[vq + 1][c] * SX, 0, false);
      w0 = __builtin_amdgcn_cvt_pk_fp8_f32(t[vq + 2][c] * SX, t[vq + 3][c] * SX, w0, true);
      *(int*)(XT8 + ((size_t)(b * 64 + c)) * NNODE + v0 + vq) = w0;
    }
  }
}

// ---------------------------------------------------------------------------
// Fused adjacency prep (x128 domain, R20-verified).
__global__ __launch_bounds__(256) void prep_adj(const float* __restrict__ A1,
                                                const float* __restrict__ A2,
                                                unsigned char* __restrict__ ADJ8,
                                                unsigned char* __restrict__ ADJT8,
                                                unsigned char* __restrict__ M18,
                                                const float* __restrict__ wpre,
                                                const float* __restrict__ wadp) {
  const int r0 = blockIdx.x * 64, c0 = blockIdx.y * 64;
  const int tid = threadIdx.x;
  const size_t NN2 = (size_t)NNODE * NNODE;
  const float wp = *wpre, wa = *wadp * 0.25f;
  const float SA = 128.f;
  __shared__ float t[64][65];
  const int vr = tid >> 2, cg = (tid & 3) * 16;
  float m1acc[16] = {};

  for (int z = 0; z < 6; ++z) {
    const float wz = (z < 2) ? wp : wa;
    float vv[16];  // values in x128 domain
    if (z < 2) {
      const float* src = (z == 0 ? A1 : A2) + (size_t)(r0 + vr) * NNODE + c0 + cg;
#pragma unroll
      for (int j = 0; j < 4; ++j) {
        float4 q = ((const float4*)src)[j];
        vv[j * 4 + 0] = q.x * SA; vv[j * 4 + 1] = q.y * SA;
        vv[j * 4 + 2] = q.z * SA; vv[j * 4 + 3] = q.w * SA;
      }
      int4 pk;
#pragma unroll
      for (int q = 0; q < 4; ++q) {
        int w0 = __builtin_amdgcn_cvt_pk_fp8_f32(vv[4 * q], vv[4 * q + 1], 0, false);
        w0 = __builtin_amdgcn_cvt_pk_fp8_f32(vv[4 * q + 2], vv[4 * q + 3], w0, true);
        (&pk.x)[q] = w0;
      }
      *(int4*)(ADJ8 + (size_t)z * NN2 + (size_t)(r0 + vr) * NNODE + c0 + cg) = pk;
    } else {
      int4 pk = *(const int4*)(ADJ8 + (size_t)z * NN2 + (size_t)(r0 + vr) * NNODE + c0 + cg);
#pragma unroll
      for (int q = 0; q < 4; ++q) {
        int w0 = (&pk.x)[q];
        vv[4 * q + 0] = __builtin_amdgcn_cvt_f32_fp8(w0, 0);
        vv[4 * q + 1] = __builtin_amdgcn_cvt_f32_fp8(w0, 1);
        vv[4 * q + 2] = __builtin_amdgcn_cvt_f32_fp8(w0, 2);
        vv[4 * q + 3] = __builtin_amdgcn_cvt_f32_fp8(w0, 3);
      }
    }
#pragma unroll
    for (int i = 0; i < 16; ++i) {
      m1acc[i] += wz * vv[i];
      t[vr][cg + i] = vv[i];
    }
    __syncthreads();
    {
#pragma unroll
      for (int jr = 0; jr < 4; ++jr) {
        int c = jr * 16 + (tid >> 4);
        int vq = (tid & 15) * 4;
        int w0 = __builtin_amdgcn_cvt_pk_fp8_f32(t[vq][c] * wz, t[vq + 1][c] * wz, 0, false);
        w0 = __builtin_amdgcn_cvt_pk_fp8_f32(t[vq + 2][c] * wz, t[vq + 3][c] * wz, w0, true);
        *(int*)(ADJT8 + (size_t)z * NN2 + (size_t)(c0 + c) * NNODE + r0 + vq) = w0;
      }
    }
    __syncthreads();
  }
  {
    int4 pk;
#pragma unroll
    for (int q = 0; q < 4; ++q) {
      int w0 = __builtin_amdgcn_cvt_pk_fp8_f32(m1acc[4 * q], m1acc[4 * q + 1], 0, false);
      w0 = __builtin_amdgcn_cvt_pk_fp8_f32(m1acc[4 * q + 2], m1acc[4 * q + 3], w0, true);
      (&pk.x)[q] = w0;
    }
    *(int4*)(M18 + (size_t)(r0 + vr) * NNODE + c0 + cg) = pk;
  }
}

// ---------------------------------------------------------------------------
#define VMCNT0() asm volatile("s_waitcnt vmcnt(0)" ::: "memory")
#define VMCNT8() asm volatile("s_waitcnt vmcnt(8)" ::: "memory")
#define LGKMCNT0() asm volatile("s_waitcnt lgkmcnt(0)" ::: "memory")
#define BARRIER() asm volatile("s_barrier" ::: "memory")

// ---------------------------------------------------------------------------
// Shared MX K=128 fp8 GEMM machinery (R17-verified).
#define MX_GEOM()                                                             \
  int aoff[4][2], boff[4][2];                                                 \
  _Pragma("unroll")                                                           \
  for (int mi = 0; mi < 4; ++mi)                                              \
    _Pragma("unroll")                                                         \
    for (int part = 0; part < 2; ++part) {                                    \
      int rh = mi * 32 + wr * 16 + (l & 15);                                  \
      int lo = rh * 128 + (l >> 4) * 32 + part * 16;                          \
      aoff[mi][part] = lo ^ ((rh & 7) << 4);                                  \
    }                                                                         \
  _Pragma("unroll")                                                           \
  for (int j = 0; j < 4; ++j)                                                 \
    _Pragma("unroll")                                                         \
    for (int part = 0; part < 2; ++part) {                                    \
      int rh = j * 32 + wc * 16 + (l & 15);                                   \
      int lo = rh * 128 + (l >> 4) * 32 + part * 16;                          \
      boff[j][part] = lo ^ ((rh & 7) << 4);                                   \
    }                                                                         \
  const int sg_row = w * 8 + (l >> 3);                                        \
  const int sg_col = (((l & 7) ^ ((l >> 3) & 7)) << 4);                       \
  unsigned aLoff[4], bLoff[4];                                                \
  _Pragma("unroll")                                                           \
  for (int p = 0; p < 4; ++p) {                                               \
    aLoff[p] = (unsigned)((m0 + p * 32 + sg_row) * 2048 + sg_col);            \
    bLoff[p] = (unsigned)((n0 + p * 32 + sg_row) * 2048 + sg_col);            \
  }

#define RDFRAG(region, o0, o1)                                                \
  __builtin_shufflevector(*(const i32x4*)((region) + (o0)),                   \
                          *(const i32x4*)((region) + (o1)),                   \
                          0, 1, 2, 3, 4, 5, 6, 7)

#define READFRAGSX(d, AF, BF)                                                 \
  do {                                                                        \
    _Pragma("unroll")                                                         \
    for (int mi = 0; mi < 4; ++mi)                                            \
      AF[mi] = RDFRAG(AREG(d), aoff[mi][0], aoff[mi][1]);                     \
    _Pragma("unroll")                                                         \
    for (int j = 0; j < 4; ++j)                                               \
      BF[j] = RDFRAG(BREG(d), boff[j][0], boff[j][1]);                        \
  } while (0)

#define MFMAX(AF, BF)                                                         \
  do {                                                                        \
    __builtin_amdgcn_s_setprio(1);                                            \
    _Pragma("unroll")                                                         \
    for (int mi = 0; mi < 4; ++mi)                                            \
      _Pragma("unroll")                                                       \
      for (int j = 0; j < 4; ++j)                                             \
        acc[mi][j] = __builtin_amdgcn_mfma_scale_f32_16x16x128_f8f6f4(        \
            AF[mi], BF[j], acc[mi][j], 0, 0, 0, 0x7F7F7F7F, 0, 0x7F7F7F7F);   \
    __builtin_amdgcn_s_setprio(0);                                            \
  } while (0)

// ---------------------------------------------------------------------------
// Fused-squares (MX K=128, R20-verified loop): fp8 partials out (x128).
__global__ __launch_bounds__(256, 2) void gemm_sq(const unsigned char* __restrict__ ADJ8,
                                                  const unsigned char* __restrict__ ADJT8,
                                                  unsigned char* __restrict__ M2p8) {
  extern __shared__ char smem[];  // 65536 B
  const int tid = threadIdx.x;
  const int w = tid >> 6, l = tid & 63;
  const int wr = w >> 1, wc = w & 1;
  const size_t NN2 = (size_t)NNODE * NNODE;
  int lin = blockIdx.x + 16 * blockIdx.y + 256 * blockIdx.z;  // [0,512)
  int xcd = lin & 7;
  int s = lin >> 3;              // [0,64)
  const int zh = xcd >> 2;       // [0,2)
  const int q = xcd & 3;         // quadrant within zh
  const int m0 = ((q & 1) * 8 + (s & 7)) * 128;
  const int n0 = ((q >> 1) * 8 + (s >> 3)) * 128;
  const int zb = zh * 3;
  unsigned char* Cp = M2p8 + (size_t)zh * NN2;
  const int NTT = 48;            // 3 z * 16 K-tiles (BK=128)

#define AREG(d) (smem + (d) * 16384)
#define BREG(d) (smem + 32768 + (d) * 16384)

  MX_GEOM();

#define STAGEXA(toff, region)                                                 \
  do {                                                                        \
    _Pragma("unroll")                                                         \
    for (int p = 0; p < 4; ++p)                                               \
      gload16((const char*)ADJ8 + (toff) + aLoff[p],                          \
              (region) + p * 4096 + w * 1024);                                \
  } while (0)
#define STAGEXB(toff, region)                                                 \
  do {                                                                        \
    _Pragma("unroll")                                                         \
    for (int p = 0; p < 4; ++p)                                               \
      gload16((const char*)ADJT8 + (toff) + bLoff[p],                         \
              (region) + p * 4096 + w * 1024);                                \
  } while (0)

  f32x4 acc[4][4] = {};
  i32x8 afA[4], bfA[4], afB[4], bfB[4];

  size_t tOff = (size_t)zb * NN2;
  STAGEXA(tOff, AREG(0));
  STAGEXB(tOff, BREG(0));
  STAGEXA(tOff + 128, AREG(1));
  STAGEXB(tOff + 128, BREG(1));
  tOff += 256;
  VMCNT8();
  BARRIER();
  READFRAGSX(0, afA, bfA);
  LGKMCNT0();
  BARRIER();

  for (int t = 0; t <= NTT - 4; t += 2) {
    STAGEXA(tOff, AREG(0));
    STAGEXB(tOff, BREG(0));
    tOff += (((t + 2) & 15) == 15) ? (NN2 - (size_t)15 * 128) : (size_t)128;
    VMCNT8();
    BARRIER();
    READFRAGSX(1, afB, bfB);
    MFMAX(afA, bfA);
    LGKMCNT0();
    BARRIER();
    STAGEXA(tOff, AREG(1));
    STAGEXB(tOff, BREG(1));
    tOff += (((t + 3) & 15) == 15) ? (NN2 - (size_t)15 * 128) : (size_t)128;
    VMCNT8();
    BARRIER();
    READFRAGSX(0, afA, bfA);
    MFMAX(afB, bfB);
    LGKMCNT0();
    BARRIER();
  }
  VMCNT0();
  BARRIER();
  READFRAGSX(1, afB, bfB);
  MFMAX(afA, bfA);
  LGKMCNT0();
  MFMAX(afB, bfB);

  const float DS = 1.f / 128.f;  // (1/16384)*128: fp8 partials in x128 domain
  const int crow = (l >> 4) * 4;
  const int ccol = l & 15;
#pragma unroll
  for (int mi = 0; mi < 4; ++mi)
#pragma unroll
    for (int j = 0; j < 4; ++j) {
      int r0 = m0 + mi * 32 + wr * 16 + crow;
      int cc = n0 + j * 32 + wc * 16 + ccol;
#pragma unroll
      for (int r = 0; r < 4; ++r) {
        float v = acc[mi][j][r] * DS;
        int w0 = __builtin_amdgcn_cvt_pk_fp8_f32(v, v, 0, false);
        Cp[(size_t)(r0 + r) * NNODE + cc] = (unsigned char)(w0 & 0xFF);
      }
    }
#undef STAGEXA
#undef STAGEXB
#undef AREG
#undef BREG
}

// ---------------------------------------------------------------------------
// Stage GEMM (MX K=128, R18/R20-verified) with fused transposed epilogue:
//   S_z[(b,n),c] = (1/2048) sum_v XT8[(b,c)][v] * M_z8[n][v]  (bf16 out).
__global__ __launch_bounds__(256, 2) void gemm_hop1sx(const unsigned char* __restrict__ XT8,
                                                      const unsigned char* __restrict__ M18,
                                                      const unsigned char* __restrict__ M28,
                                                      __bf16* __restrict__ S1,
                                                      __bf16* __restrict__ S2) {
  extern __shared__ char smem[];  // 65536 B
  const int tid = threadIdx.x;
  const int w = tid >> 6, l = tid & 63;
  const int wr = w >> 1, wc = w & 1;
  int lin = blockIdx.x + 16 * blockIdx.y + 256 * blockIdx.z;  // [0,512)
  int nlin = (lin & 7) * 64 + (lin >> 3);
  const int m0 = (nlin & 15) * 128, n0 = ((nlin >> 4) & 15) * 128;
  const int z = nlin >> 8;
  const unsigned char* Bbase = z ? M28 : M18;
  const int NT = NNODE / 128;  // 16 K-tiles

#define AREG(d) (smem + (d) * 16384)
#define BREG(d) (smem + 32768 + (d) * 16384)

  MX_GEOM();

#define STAGEXA(koff, region)                                                 \
  do {                                                                        \
    _Pragma("unroll")                                                         \
    for (int p = 0; p < 4; ++p)                                               \
      gload16((const char*)XT8 + (koff) + aLoff[p],                           \
              (region) + p * 4096 + w * 1024);                                \
  } while (0)
#define STAGEXB(koff, region)                                                 \
  do {                                                                        \
    _Pragma("unroll")                                                         \
    for (int p = 0; p < 4; ++p)                                               \
      gload16((const char*)Bbase + (koff) + bLoff[p],                         \
              (region) + p * 4096 + w * 1024);                                \
  } while (0)

  f32x4 acc[4][4] = {};
  i32x8 afA[4], bfA[4], afB[4], bfB[4];

  size_t kOff = 0;
  STAGEXA(kOff, AREG(0));
  STAGEXB(kOff, BREG(0));
  STAGEXA(kOff + 128, AREG(1));
  STAGEXB(kOff + 128, BREG(1));
  kOff += 256;
  VMCNT8();
  BARRIER();
  READFRAGSX(0, afA, bfA);
  LGKMCNT0();
  BARRIER();

  for (int t = 0; t <= NT - 4; t += 2) {
    STAGEXA(kOff, AREG(0));
    STAGEXB(kOff, BREG(0));
    kOff += 128;
    VMCNT8();
    BARRIER();
    READFRAGSX(1, afB, bfB);
    MFMAX(afA, bfA);
    LGKMCNT0();
    BARRIER();
    STAGEXA(kOff, AREG(1));
    STAGEXB(kOff, BREG(1));
    kOff += 128;
    VMCNT8();
    BARRIER();
    READFRAGSX(0, afA, bfA);
    MFMAX(afB, bfB);
    LGKMCNT0();
    BARRIER();
  }
  VMCNT0();
  BARRIER();
  READFRAGSX(1, afB, bfB);
  MFMAX(afA, bfA);
  LGKMCNT0();
  MFMAX(afB, bfB);

  // ---- epilogue (R14-verified): descale, LDS transpose T[n][m] (slot-XOR),
  // coalesced write S_z[(b, n0+n)*64 + c].
  {
    __syncthreads();
    const float DS = 1.f / 2048.f;  // 1/(16*128)
    const int crow = (l >> 4) * 4;
    const int ccol = l & 15;
    char* T = smem;  // 128 x 256 B = 32768
#pragma unroll
    for (int mi = 0; mi < 4; ++mi)
#pragma unroll
      for (int j = 0; j < 4; ++j) {
        int ml = mi * 32 + wr * 16 + crow;
        int nl = j * 32 + wc * 16 + ccol;
        bf16x4 v;
#pragma unroll
        for (int r = 0; r < 4; ++r) v[r] = (__bf16)(acc[mi][j][r] * DS);
        *(bf16x4*)(T + nl * 256 + ((ml * 2) ^ ((nl & 7) << 4))) = v;
      }
    __syncthreads();
    __bf16* dst = z ? S2 : S1;
    const int bA = m0 >> 6;
#pragma unroll
    for (int it = 0; it < 4; ++it) {
      int nl = (tid >> 3) + it * 32;
      int seg = tid & 7;
      int xorv = (nl & 7) << 4;
      const char* src = T + nl * 256;
      bf16x8 v0 = *(const bf16x8*)(src + ((seg * 32) ^ xorv));
      bf16x8 v1 = *(const bf16x8*)(src + ((seg * 32 + 16) ^ xorv));
      int b = bA + (seg >> 2);
      size_t o = ((size_t)b * NNODE + n0 + nl) * 64 + (seg & 3) * 16;
      *(bf16x8*)(dst + o) = v0;
      *(bf16x8*)(dst + o + 8) = v1;
    }
  }
#undef STAGEXA
#undef STAGEXB
#undef AREG
#undef BREG
}

// ---------------------------------------------------------------------------
// M28[i] = fp8(M2a[i] + M2b[i]), fp8 partials in (x128 domain)
__global__ __launch_bounds__(256) void combine_m2(const unsigned char* __restrict__ M2p8,
                                                  unsigned char* __restrict__ M28) {
  const size_t NN2 = (size_t)NNODE * NNODE;
  size_t i = ((size_t)blockIdx.x * 256 + threadIdx.x) * 8;
  int2 a = *(const int2*)(M2p8 + i);
  int2 b = *(const int2*)(M2p8 + NN2 + i);
  float sv[8];
  sv[0] = __builtin_amdgcn_cvt_f32_fp8(a.x, 0) + __builtin_amdgcn_cvt_f32_fp8(b.x, 0);
  sv[1] = __builtin_amdgcn_cvt_f32_fp8(a.x, 1) + __builtin_amdgcn_cvt_f32_fp8(b.x, 1);
  sv[2] = __builtin_amdgcn_cvt_f32_fp8(a.x, 2) + __builtin_amdgcn_cvt_f32_fp8(b.x, 2);
  sv[3] = __builtin_amdgcn_cvt_f32_fp8(a.x, 3) + __builtin_amdgcn_cvt_f32_fp8(b.x, 3);
  sv[4] = __builtin_amdgcn_cvt_f32_fp8(a.y, 0) + __builtin_amdgcn_cvt_f32_fp8(b.y, 0);
  sv[5] = __builtin_amdgcn_cvt_f32_fp8(a.y, 1) + __builtin_amdgcn_cvt_f32_fp8(b.y, 1);
  sv[6] = __builtin_amdgcn_cvt_f32_fp8(a.y, 2) + __builtin_amdgcn_cvt_f32_fp8(b.y, 2);
  sv[7] = __builtin_amdgcn_cvt_f32_fp8(a.y, 3) + __builtin_amdgcn_cvt_f32_fp8(b.y, 3);
  int w0 = __builtin_amdgcn_cvt_pk_fp8_f32(sv[0], sv[1], 0, false);
  w0 = __builtin_amdgcn_cvt_pk_fp8_f32(sv[2], sv[3], w0, true);
  int w1 = __builtin_amdgcn_cvt_pk_fp8_f32(sv[4], sv[5], 0, false);
  w1 = __builtin_amdgcn_cvt_pk_fp8_f32(sv[6], sv[7], w1, true);
  int2 pk; pk.x = w0; pk.y = w1;
  *(int2*)(M28 + i) = pk;
}

// ---------------------------------------------------------------------------
// Gate linear GEMM (R20-verified bf16): [65536 x 192] @ Wt^T, fused epilogues.
// MODE 0: cols 0-63 -> z=sigmoid -> zbuf(f32); cols 64-127 -> r ->
//         rx=(bf16)(r*hid) row-major AND fp8(16*rx)^T -> XT8out.
// MODE 1: cols 0-63 -> c=tanh -> out=(1-z)*hid+z*c (f32)
template <int MODE>
__global__ __launch_bounds__(256) void gemm_lin(const __bf16* __restrict__ Xp,
                                                const __bf16* __restrict__ S1,
                                                const __bf16* __restrict__ S2,
                                                const __bf16* __restrict__ Wt,
                                                const float* __restrict__ b0,
                                                const float* __restrict__ b1,
                                                const float* __restrict__ wpre,
                                                const float* __restrict__ wadp,
                                                const float* __restrict__ hid,
                                                float* __restrict__ zbuf,
                                                __bf16* __restrict__ rxout,
                                                unsigned char* __restrict__ XT8out,
                                                float* __restrict__ outp) {
  __shared__ __bf16 As[128 * 32];
  __shared__ __bf16 Bs[128 * 32];
  __shared__ char T[64 * 256];  // rx transpose staging (MODE 0)
  const int tid = threadIdx.x;
  const int wave = tid >> 6, lane = tid & 63;
  const int wr = wave >> 1, wc = wave & 1;
  const int m0 = blockIdx.x * 128;
  const int rowA = tid >> 2;
  const int colb = (tid & 3) * 16;
  const __bf16* srcs[3] = {Xp, S1, S2};
  char* asD0 = (char*)As + wave * 1024;
  char* asD1 = (char*)As + 4096 + wave * 1024;
  char* bsD0 = (char*)Bs + wave * 1024;
  char* bsD1 = (char*)Bs + 4096 + wave * 1024;

  f32x4 acc[4][4] = {};

#pragma unroll
  for (int kt = 0; kt < 6; ++kt) {
    const __bf16* Ab = srcs[kt >> 1];
    const char* aS0 = (const char*)(Ab + (size_t)(m0 + rowA) * 64) + (kt & 1) * 64 + colb;
    const char* aS1 = (const char*)(Ab + (size_t)(m0 + rowA + 64) * 64) + (kt & 1) * 64 + colb;
    const char* bS0 = (const char*)(Wt + (size_t)rowA * 192) + kt * 64 + colb;
    const char* bS1 = (const char*)(Wt + (size_t)(rowA + 64) * 192) + kt * 64 + colb;
    gload16(aS0, asD0);
    gload16(aS1, asD1);
    gload16(bS0, bsD0);
    gload16(bS1, bsD1);
    __syncthreads();
    bf16x8 af[4], bfr[4];
#pragma unroll
    for (int mi = 0; mi < 4; ++mi)
      af[mi] = *(const bf16x8*)((const char*)As +
               ((wr * 64 + mi * 16 + (lane & 15)) * 64 + (lane >> 4) * 16));
#pragma unroll
    for (int ni = 0; ni < 4; ++ni)
      bfr[ni] = *(const bf16x8*)((const char*)Bs +
               ((wc * 64 + ni * 16 + (lane & 15)) * 64 + (lane >> 4) * 16));
#pragma unroll
    for (int mi = 0; mi < 4; ++mi)
#pragma unroll
      for (int ni = 0; ni < 4; ++ni)
        acc[mi][ni] = __builtin_amdgcn_mfma_f32_16x16x32_bf16(af[mi], bfr[ni],
                                                              acc[mi][ni], 0, 0, 0);
    __syncthreads();
  }

  const float wp = *wpre, wa = *wadp;
  const float s = 2.f * wp + wa;
  const int crow = (lane >> 4) * 4;
  const int ccol = lane & 15;
#pragma unroll
  for (int mi = 0; mi < 4; ++mi)
#pragma unroll
    for (int ni = 0; ni < 4; ++ni) {
      int r0 = m0 + wr * 64 + mi * 16 + crow;
      int col = wc * 64 + ni * 16 + ccol;
      int cf = col & 63;
      if (MODE == 0) {
        if (col < 64) {
#pragma unroll
          for (int r = 0; r < 4; ++r) {
            int row = r0 + r;
            float g = acc[mi][ni][r] + s * b0[cf];
            zbuf[(size_t)row * 64 + cf] = 1.f / (1.f + __expf(-g));
          }
        } else {
          bf16x4 tv;
#pragma unroll
          for (int r = 0; r < 4; ++r) {
            int row = r0 + r;
            float g = acc[mi][ni][r] + s * b1[cf];
            float rv = 1.f / (1.f + __expf(-g));
            __bf16 rxv = (__bf16)(rv * hid[(size_t)row * 64 + cf]);
            rxout[(size_t)row * 64 + cf] = rxv;
            tv[r] = rxv;
          }
          int vl0 = wr * 64 + mi * 16 + crow;
          *(bf16x4*)(T + cf * 256 + ((vl0 * 2) ^ ((cf & 7) << 4))) = tv;
        }
      } else {
        if (col < 64) {
#pragma unroll
          for (int r = 0; r < 4; ++r) {
            int row = r0 + r;
            float g = acc[mi][ni][r] + s * b0[cf];
            float cv = 1.f - 2.f / (1.f + __expf(2.f * g));
            float zv = zbuf[(size_t)row * 64 + cf];
            float hv = hid[(size_t)row * 64 + cf];
            outp[(size_t)row * 64 + cf] = (1.f - zv) * hv + zv * cv;
          }
        }
      }
    }

  if (MODE == 0) {
    __syncthreads();
    const int b = m0 >> 11;
    const int v0 = m0 & 2047;
    const float SX = 16.f;
#pragma unroll
    for (int it = 0; it < 4; ++it) {
      int rr = it * 16 + (tid >> 4);
      int seg = tid & 15;
      bf16x8 v = *(const bf16x8*)(T + rr * 256 + ((seg * 16) ^ ((rr & 7) << 4)));
      int w0 = __builtin_amdgcn_cvt_pk_fp8_f32((float)v[0] * SX, (float)v[1] * SX, 0, false);
      w0 = __builtin_amdgcn_cvt_pk_fp8_f32((float)v[2] * SX, (float)v[3] * SX, w0, true);
      int w1 = __builtin_amdgcn_cvt_pk_fp8_f32((float)v[4] * SX, (float)v[5] * SX, 0, false);
      w1 = __builtin_amdgcn_cvt_pk_fp8_f32((float)v[6] * SX, (float)v[7] * SX, w1, true);
      int2 pk; pk.x = w0; pk.y = w1;
      *(int2*)(XT8out + ((size_t)(b * 64 + rr)) * NNODE + v0 + seg * 8) = pk;
    }
  }
}

// ---------------------------------------------------------------------------
extern "C" void kernel_launch(void* const* d_in, const int* in_sizes, int n_in,
                              void* d_out, int out_size, void* d_ws, size_t ws_size,
                              hipStream_t stream) {
  (void)in_sizes; (void)n_in; (void)out_size;
  const float* x    = (const float*)d_in[0];
  const float* A1   = (const float*)d_in[1];
  const float* A2   = (const float*)d_in[2];
  const float* E1   = (const float*)d_in[3];
  const float* E2   = (const float*)d_in[4];
  const float* Wz   = (const float*)d_in[5];
  const float* bz   = (const float*)d_in[6];
  const float* Wr   = (const float*)d_in[7];
  const float* br   = (const float*)d_in[8];
  const float* Wc   = (const float*)d_in[9];
  const float* bc   = (const float*)d_in[10];
  const float* wpre = (const float*)d_in[11];
  const float* wadp = (const float*)d_in[12];
  float* out = (float*)d_out;

  char* ws = (char*)d_ws;
  const size_t NN2 = (size_t)NNODE * NNODE;  // 4,194,304
  const size_t NN2B = NN2 * 2;               // bytes per bf16 slice
  unsigned char* ADJ8  = (unsigned char*)(ws + 6 * NN2B);           // 6 fp8
  unsigned char* ADJT8 = (unsigned char*)(ws + 6 * NN2B + 6 * NN2); // 6 fp8
  unsigned char* SC8 = (unsigned char*)(ws + 12 * NN2B);  // fp8 scores (4 slices)
  unsigned char* M2p8 = (unsigned char*)(ws + 12 * NN2B); // fp8 partials x2 (post-SC8)
  unsigned char* M18 = (unsigned char*)(ws + 18 * NN2B);        // fp8
  unsigned char* M28 = (unsigned char*)(ws + 18 * NN2B + NN2);  // fp8
  unsigned char* XT8 = (unsigned char*)(ws + 20 * NN2B);        // fp8
  __bf16* xbf  = (__bf16*)(ws + 21 * NN2B);
  __bf16* rx   = (__bf16*)(ws + 22 * NN2B);
  __bf16* S1   = (__bf16*)(ws + 2 * NN2B);
  __bf16* S2   = (__bf16*)(ws + 3 * NN2B);
  float*  zbuf = (float*)(ws + 4 * NN2B);
  __bf16* E1p  = (__bf16*)(ws + 23 * NN2B);
  __bf16* E2p  = E1p + 4 * NNODE * 32;
  __bf16* Wzrt = E2p + 4 * NNODE * 32;
  __bf16* Wct  = Wzrt + 128 * 192;
  if (ws_size < 23 * NN2B + 2 * 4 * NNODE * 32 * 2 + 2 * 128 * 192 * 2) return;

  // --- adjacency construction (fused)
  prep_ew<<<224, 256, 0, stream>>>(E1, E2, Wz, Wr, Wc, wpre, wadp,
                                   E1p, E2p, Wzrt, Wct);
  score_gemm<<<dim3(16, 16, 4), 256, 0, stream>>>(E1p, E2p, SC8);
  soft_tx<<<3072, 256, 0, stream>>>(SC8, ADJ8, x, XT8, xbf);
  prep_adj<<<dim3(32, 32), 256, 0, stream>>>(A1, A2, ADJ8, ADJT8, M18,
                                             wpre, wadp);

  // --- M2 = sum_z w_z A_z^2 (MX fp8 K=128; fp8 split-K partials)
  gemm_sq<<<dim3(16, 16, 2), 256, 65536, stream>>>(ADJ8, ADJT8, M2p8);
  combine_m2<<<2048, 256, 0, stream>>>(M2p8, M28);

  // --- stage 1: S1 = M1 x, S2 = M2 x (MX fp8 K=128, bf16 S out)
  gemm_hop1sx<<<dim3(16, 16, 2), 256, 65536, stream>>>(XT8, M18, M28, S1, S2);
  gemm_lin<0><<<512, 256, 0, stream>>>(xbf, S1, S2, Wzrt, bz, br, wpre, wadp,
                                       x, zbuf, rx, XT8, nullptr);

  // --- stage 2: hops on r*x (XT8 holds fp8(16*rx)^T from gemm_lin<0>)
  gemm_hop1sx<<<dim3(16, 16, 2), 256, 65536, stream>>>(XT8, M18, M28, S1, S2);
  gemm_lin<1><<<512, 256, 0, stream>>>(rx, S1, S2, Wct, bc, nullptr, wpre, wadp,
                                       x, zbuf, nullptr, nullptr, out);
}